// Round 4
// baseline (21536.682 us; speedup 1.0000x reference)
//
#include <hip/hip_runtime.h>
#include <cstdint>
#include <cstddef>

#define BB 8
#define CC 64
#define NN 4096
#define OO 64
#define KK 20
#define KC 58
#define KSKIP 6
#define NSPLIT 8
#define JS 512            // j's per split
#define CAPS 10           // per-(query,split) direct candidate slots
#define GCAP 20           // per-query overflow pool slots
#define BN_EPS 1e-5f
#define NEG 0.2f
#define NEGINF (-3.402823466e38f)
#define M_TOTAL 655360.0f   // B*N*K

#define MED3F(a, b, c) __builtin_amdgcn_fmed3f((a), (b), (c))

// LAUNCH_BOUNDS LESSON (rounds 1-3): hipcc VGPR cap = 256/min_waves_arg
// (arg2->128, arg3->84, arg4->64). The scan kernels' live set (xi[58] +
// pipelined staging) exceeds 128 -> ANY bound spills to scratch
// (FETCH 31MB -> 24-46GB, VALUBusy ~2%). No bounds -> 256 VGPR, no spill.
// Do not re-add launch_bounds to k_knnA/k_collect.

// ---------------- K0: h = 0.5*||x_{6:}||^2 per point ----------------
__global__ void k_sq(const float* __restrict__ x, float* __restrict__ h) {
  int n = blockIdx.x * 256 + threadIdx.x;  // 0 .. BB*NN-1
  int b = n >> 12;
  int nn = n & (NN - 1);
  const float* xp = x + ((size_t)b * CC + KSKIP) * NN + nn;
  float s = 0.f;
#pragma unroll
  for (int c = 0; c < KC; ++c) {
    float v = xp[(size_t)c * NN];
    s = fmaf(v, v, s);
  }
  h[n] = 0.5f * s;
}

// med3 ripple: insert e into descending top-20 value list. 20 independent ops.
#define RIP(tv, e)                                   \
  do {                                               \
    float _e = (e);                                  \
    tv[19] = MED3F(tv[18], tv[19], _e);              \
    tv[18] = MED3F(tv[17], tv[18], _e);              \
    tv[17] = MED3F(tv[16], tv[17], _e);              \
    tv[16] = MED3F(tv[15], tv[16], _e);              \
    tv[15] = MED3F(tv[14], tv[15], _e);              \
    tv[14] = MED3F(tv[13], tv[14], _e);              \
    tv[13] = MED3F(tv[12], tv[13], _e);              \
    tv[12] = MED3F(tv[11], tv[12], _e);              \
    tv[11] = MED3F(tv[10], tv[11], _e);              \
    tv[10] = MED3F(tv[9],  tv[10], _e);              \
    tv[9]  = MED3F(tv[8],  tv[9],  _e);              \
    tv[8]  = MED3F(tv[7],  tv[8],  _e);              \
    tv[7]  = MED3F(tv[6],  tv[7],  _e);              \
    tv[6]  = MED3F(tv[5],  tv[6],  _e);              \
    tv[5]  = MED3F(tv[4],  tv[5],  _e);              \
    tv[4]  = MED3F(tv[3],  tv[4],  _e);              \
    tv[3]  = MED3F(tv[2],  tv[3],  _e);              \
    tv[2]  = MED3F(tv[1],  tv[2],  _e);              \
    tv[1]  = MED3F(tv[0],  tv[1],  _e);              \
    tv[0]  = fmaxf(tv[0], _e);                       \
  } while (0)

// distance batch: 8 j's per group; MUST be textually identical in pass A and B
// (bit-exact fp32 required for threshold re-scan).
#define DIST8(jq)                                                     \
  float a0 = 0.f, a1 = 0.f, a2 = 0.f, a3 = 0.f;                       \
  float a4 = 0.f, a5 = 0.f, a6 = 0.f, a7 = 0.f;                       \
  _Pragma("unroll")                                                   \
  for (int c = 0; c < KC; ++c) {                                      \
    float4 xA = *(const float4*)(ltile + c * 64 + (jq) * 8);          \
    float4 xB = *(const float4*)(ltile + c * 64 + (jq) * 8 + 4);      \
    float xic = xi[c];                                                \
    a0 = fmaf(xic, xA.x, a0);                                         \
    a1 = fmaf(xic, xA.y, a1);                                         \
    a2 = fmaf(xic, xA.z, a2);                                         \
    a3 = fmaf(xic, xA.w, a3);                                         \
    a4 = fmaf(xic, xB.x, a4);                                         \
    a5 = fmaf(xic, xB.y, a5);                                         \
    a6 = fmaf(xic, xB.z, a6);                                         \
    a7 = fmaf(xic, xB.w, a7);                                         \
  }                                                                   \
  float4 hA = *(const float4*)(lh + (jq) * 8);                        \
  float4 hB = *(const float4*)(lh + (jq) * 8 + 4);                    \
  float d0 = a0 - hA.x;                                               \
  float d1 = a1 - hA.y;                                               \
  float d2 = a2 - hA.z;                                               \
  float d3 = a3 - hA.w;                                               \
  float d4 = a4 - hB.x;                                               \
  float d5 = a5 - hB.y;                                               \
  float d6 = a6 - hB.z;                                               \
  float d7 = a7 - hB.w;

#define STAGE_TILE(jbase)                                             \
  __syncthreads();                                                    \
  for (int f = t; f < KC * 16; f += 256) {                            \
    int c = f >> 4, q = f & 15;                                       \
    float4 v = *(const float4*)(xb + c * NN + (jbase) + q * 4);       \
    *(float4*)(ltile + c * 64 + q * 4) = v;                           \
  }                                                                   \
  if (t < 64) lh[t] = hg[b * NN + (jbase) + t];                       \
  __syncthreads();

// ---------------- Pass A: per-(query, split) top-20 VALUES only ----------------
// grid: BB(8) x itile(16) x split(8) = 1024 blocks of 256 threads.
__global__ void k_knnA(const float* __restrict__ x,
                       const float* __restrict__ hg,
                       float* __restrict__ candv) {
  __shared__ float ltile[KC * 64];
  __shared__ float lh[64];
  int t = threadIdx.x;
  int lane = t & 63;
  int w = t >> 6;
  int bidx = blockIdx.x;
  int b = bidx >> 7;
  int itile = (bidx >> 3) & 15;
  int split = bidx & 7;
  int i = itile * 256 + w * 64 + lane;
  const float* xb = x + ((size_t)b * CC + KSKIP) * NN;

  float xi[KC];
#pragma unroll
  for (int c = 0; c < KC; ++c) xi[c] = xb[c * NN + i];

  float tv[KK];
#pragma unroll
  for (int s = 0; s < KK; ++s) tv[s] = NEGINF;

#pragma unroll 1
  for (int jt = 0; jt < JS / 64; ++jt) {
    int jbase = split * JS + jt * 64;
    STAGE_TILE(jbase)
#pragma unroll 1
    for (int jq = 0; jq < 8; ++jq) {
      DIST8(jq)
      RIP(tv, d0); RIP(tv, d1); RIP(tv, d2); RIP(tv, d3);
      RIP(tv, d4); RIP(tv, d5); RIP(tv, d6); RIP(tv, d7);
    }
  }

  float* cv = candv + (((size_t)(b * NN + i)) * NSPLIT + split) * KK;
#pragma unroll
  for (int s = 0; s < KK; ++s) cv[s] = tv[s];
}

// ---------------- merge split value-lists -> exact 20th-largest threshold ----------------
__global__ void k_thresh(const float* __restrict__ candv, float* __restrict__ thr) {
  int qi = blockIdx.x * 256 + threadIdx.x;  // 0..BB*NN-1
  const float* cv = candv + (size_t)qi * NSPLIT * KK;
  float tv[KK];
#pragma unroll
  for (int s = 0; s < KK; ++s) tv[s] = NEGINF;
#pragma unroll 1
  for (int s = 0; s < NSPLIT * KK; ++s) {
    RIP(tv, cv[s]);
  }
  thr[qi] = tv[19];
}

// ---------------- Pass B: re-scan, collect j with d >= thr ----------------
// Per-(query,split) private segment + register-local counter: no atomic-return
// dependency in the hot path. Rare overflow (>CAPS hits in one split) spills
// to a per-query atomic pool. NO launch_bounds (see lesson above).
__global__ void k_collect(const float* __restrict__ x,
                          const float* __restrict__ hg,
                          const float* __restrict__ thr,
                          int* __restrict__ cnt8,
                          int* __restrict__ gcnt,
                          float* __restrict__ segs,
                          float* __restrict__ pool) {
  __shared__ float ltile[KC * 64];
  __shared__ float lh[64];
  int t = threadIdx.x;
  int lane = t & 63;
  int w = t >> 6;
  int bidx = blockIdx.x;
  int b = bidx >> 7;
  int itile = (bidx >> 3) & 15;
  int split = bidx & 7;
  int i = itile * 256 + w * 64 + lane;
  int qi = b * NN + i;
  const float* xb = x + ((size_t)b * CC + KSKIP) * NN;

  float xi[KC];
#pragma unroll
  for (int c = 0; c < KC; ++c) xi[c] = xb[c * NN + i];
  float ti_ = thr[qi];
  float* seg = segs + (((size_t)qi * NSPLIT) + split) * CAPS * 2;
  int p = 0;

#define EMIT(dv, jj)                                                  \
  if ((dv) >= ti_) {                                                  \
    float2 pr;                                                        \
    pr.x = (dv);                                                      \
    pr.y = __int_as_float(jj);                                        \
    if (p < CAPS) {                                                   \
      *(float2*)(seg + p * 2) = pr;                                   \
    } else {                                                          \
      int g = atomicAdd(&gcnt[qi], 1);                                \
      if (g < GCAP) *(float2*)(pool + ((size_t)qi * GCAP + g) * 2) = pr; \
    }                                                                 \
    ++p;                                                              \
  }

#pragma unroll 1
  for (int jt = 0; jt < JS / 64; ++jt) {
    int jbase = split * JS + jt * 64;
    STAGE_TILE(jbase)
#pragma unroll 1
    for (int jq = 0; jq < 8; ++jq) {
      DIST8(jq)
      int j0 = jbase + jq * 8;
      EMIT(d0, j0 + 0) EMIT(d1, j0 + 1) EMIT(d2, j0 + 2) EMIT(d3, j0 + 3)
      EMIT(d4, j0 + 4) EMIT(d5, j0 + 5) EMIT(d6, j0 + 6) EMIT(d7, j0 + 7)
    }
  }
#undef EMIT
  cnt8[qi * NSPLIT + split] = p;
}

// ---------------- final: lexicographic top-20 over segments + pool ----------------
// tie at equal d -> smaller j wins (matches jax.lax.top_k). Output order
// irrelevant downstream (sum/max over k).
__global__ void k_final(const float* __restrict__ segs, const int* __restrict__ cnt8,
                        const float* __restrict__ pool, const int* __restrict__ gcnt,
                        int* __restrict__ idxk) {
  int qi = blockIdx.x * 256 + threadIdx.x;
  float tv[KK];
  int ti[KK];
#pragma unroll
  for (int s = 0; s < KK; ++s) { tv[s] = NEGINF; ti[s] = 0; }

#define INSERT(pr)                                                            \
  {                                                                           \
    float d = pr.x;                                                           \
    int j = __float_as_int(pr.y);                                             \
    bool acc = (d > tv[KK - 1]) || (d == tv[KK - 1] && j < ti[KK - 1]);       \
    if (acc) {                                                                \
      tv[KK - 1] = d;                                                         \
      ti[KK - 1] = j;                                                         \
      _Pragma("unroll")                                                       \
      for (int s = KK - 1; s > 0; --s) {                                      \
        bool gt_ = (tv[s] > tv[s - 1]) || (tv[s] == tv[s - 1] && ti[s] < ti[s - 1]); \
        float vh_ = gt_ ? tv[s] : tv[s - 1];                                  \
        float vl_ = gt_ ? tv[s - 1] : tv[s];                                  \
        int ih_ = gt_ ? ti[s] : ti[s - 1];                                    \
        int il_ = gt_ ? ti[s - 1] : ti[s];                                    \
        tv[s - 1] = vh_; tv[s] = vl_;                                         \
        ti[s - 1] = ih_; ti[s] = il_;                                         \
      }                                                                       \
    }                                                                         \
  }

#pragma unroll 1
  for (int sp = 0; sp < NSPLIT; ++sp) {
    int c = cnt8[qi * NSPLIT + sp];
    if (c > CAPS) c = CAPS;
    const float* cp = segs + (((size_t)qi * NSPLIT) + sp) * CAPS * 2;
#pragma unroll 1
    for (int e = 0; e < c; ++e) {
      float2 pr = *(const float2*)(cp + e * 2);
      INSERT(pr)
    }
  }
  int g = gcnt[qi];
  if (g > GCAP) g = GCAP;
  const float* pp = pool + (size_t)qi * GCAP * 2;
#pragma unroll 1
  for (int e = 0; e < g; ++e) {
    float2 pr = *(const float2*)(pp + e * 2);
    INSERT(pr)
  }
#undef INSERT

  int* op = idxk + (size_t)qi * KK;
#pragma unroll
  for (int s = 0; s < KK; ++s) op[s] = ti[s];
}

// ---------------- K2: u = W1^T x, v = (W2-W1)^T x, stored (b, n, o) ----------------
__global__ void k_uv(const float* __restrict__ x, const float* __restrict__ W,
                     float* __restrict__ ut, float* __restrict__ vt) {
  __shared__ float w1[64 * 65];
  __shared__ float wd[64 * 65];
  __shared__ float xs[64 * 72];
  int t = threadIdx.x;
  int b = blockIdx.x >> 6;
  int nbase = (blockIdx.x & 63) * 64;

  for (int f = t; f < 4096; f += 256) {
    int o = f >> 6, c = f & 63;
    float a = W[o * 128 + c];
    float b2 = W[o * 128 + 64 + c];
    w1[c * 65 + o] = a;
    wd[c * 65 + o] = b2 - a;
  }
  for (int f = t; f < 1024; f += 256) {
    int c = f >> 4, q = f & 15;
    float4 v = *(const float4*)(x + ((size_t)b * CC + c) * NN + nbase + q * 4);
    *(float4*)(xs + c * 72 + q * 4) = v;
  }
  __syncthreads();

  int o = t & 63, w = t >> 6;
  float4 au[4], av[4];
#pragma unroll
  for (int nq = 0; nq < 4; ++nq) {
    au[nq] = make_float4(0.f, 0.f, 0.f, 0.f);
    av[nq] = make_float4(0.f, 0.f, 0.f, 0.f);
  }
#pragma unroll 4
  for (int c = 0; c < 64; ++c) {
    float w1v = w1[c * 65 + o];
    float wdv = wd[c * 65 + o];
#pragma unroll
    for (int nq = 0; nq < 4; ++nq) {
      float4 xv = *(const float4*)(xs + c * 72 + w * 16 + nq * 4);
      au[nq].x = fmaf(w1v, xv.x, au[nq].x);
      au[nq].y = fmaf(w1v, xv.y, au[nq].y);
      au[nq].z = fmaf(w1v, xv.z, au[nq].z);
      au[nq].w = fmaf(w1v, xv.w, au[nq].w);
      av[nq].x = fmaf(wdv, xv.x, av[nq].x);
      av[nq].y = fmaf(wdv, xv.y, av[nq].y);
      av[nq].z = fmaf(wdv, xv.z, av[nq].z);
      av[nq].w = fmaf(wdv, xv.w, av[nq].w);
    }
  }
#pragma unroll
  for (int nq = 0; nq < 4; ++nq) {
    int n = nbase + w * 16 + nq * 4;
    size_t base = ((size_t)b * NN + n) * OO + o;
    ut[base + 0 * OO] = au[nq].x;
    ut[base + 1 * OO] = au[nq].y;
    ut[base + 2 * OO] = au[nq].z;
    ut[base + 3 * OO] = au[nq].w;
    vt[base + 0 * OO] = av[nq].x;
    vt[base + 1 * OO] = av[nq].y;
    vt[base + 2 * OO] = av[nq].z;
    vt[base + 3 * OO] = av[nq].w;
  }
}

// ---------------- K3: BN sum / sumsq over all (b,n,k) per channel ----------------
__global__ void k_stats(const float* __restrict__ ut, const float* __restrict__ vt,
                        const int* __restrict__ idxk, float* __restrict__ gsum,
                        float* __restrict__ gsqs) {
  __shared__ float red[2][4][64];
  int t = threadIdx.x;
  int o = t & 63, w = t >> 6;
  int b = blockIdx.x >> 6;
  int nbase = (blockIdx.x & 63) * 64 + w * 16;
  const float* up = ut + (size_t)b * NN * OO;
  float s = 0.f, s2 = 0.f;
#pragma unroll 1
  for (int nn2 = 0; nn2 < 16; ++nn2) {
    int n = nbase + nn2;
    float vv = vt[((size_t)b * NN + n) * OO + o];
    const int* ip = idxk + ((size_t)b * NN + n) * KK;
    int4 q0 = *(const int4*)(ip + 0);
    int4 q1 = *(const int4*)(ip + 4);
    int4 q2 = *(const int4*)(ip + 8);
    int4 q3 = *(const int4*)(ip + 12);
    int4 q4 = *(const int4*)(ip + 16);
#define ACC(j)                                  \
    {                                           \
      float u = up[(size_t)(j) * OO + o];       \
      float yy = u + vv;                        \
      s += yy;                                  \
      s2 = fmaf(yy, yy, s2);                    \
    }
    ACC(q0.x) ACC(q0.y) ACC(q0.z) ACC(q0.w)
    ACC(q1.x) ACC(q1.y) ACC(q1.z) ACC(q1.w)
    ACC(q2.x) ACC(q2.y) ACC(q2.z) ACC(q2.w)
    ACC(q3.x) ACC(q3.y) ACC(q3.z) ACC(q3.w)
    ACC(q4.x) ACC(q4.y) ACC(q4.z) ACC(q4.w)
#undef ACC
  }
  red[0][w][o] = s;
  red[1][w][o] = s2;
  __syncthreads();
  if (w == 0) {
    float ts = red[0][0][o] + red[0][1][o] + red[0][2][o] + red[0][3][o];
    float t2 = red[1][0][o] + red[1][1][o] + red[1][2][o] + red[1][3][o];
    atomicAdd(&gsum[o], ts);
    atomicAdd(&gsqs[o], t2);
  }
}

// ---------------- K4: finalize BN affine ----------------
__global__ void k_bn(const float* __restrict__ gsum, const float* __restrict__ gsqs,
                     const float* __restrict__ gamma, const float* __restrict__ beta,
                     float* __restrict__ AB) {
  int o = threadIdx.x;
  float mean = gsum[o] * (1.f / M_TOTAL);
  float var = gsqs[o] * (1.f / M_TOTAL) - mean * mean;
  float A = gamma[o] / sqrtf(var + BN_EPS);
  AB[o] = A;
  AB[64 + o] = beta[o] - mean * A;
}

// ---------------- K5: normalized + leakyrelu + max over k, transposed store ----------------
__global__ void k_out(const float* __restrict__ ut, const float* __restrict__ vt,
                      const int* __restrict__ idxk, const float* __restrict__ AB,
                      float* __restrict__ outp) {
  __shared__ float lt[64 * 65];
  int t = threadIdx.x;
  int o = t & 63, w = t >> 6;
  int b = blockIdx.x >> 6;
  int nb = (blockIdx.x & 63) * 64;
  float A = AB[o], Bs = AB[64 + o];
  const float* up = ut + (size_t)b * NN * OO;
#pragma unroll 1
  for (int nn2 = 0; nn2 < 16; ++nn2) {
    int nl = w * 16 + nn2;
    int n = nb + nl;
    float vv = vt[((size_t)b * NN + n) * OO + o];
    const int* ip = idxk + ((size_t)b * NN + n) * KK;
    int4 q0 = *(const int4*)(ip + 0);
    int4 q1 = *(const int4*)(ip + 4);
    int4 q2 = *(const int4*)(ip + 8);
    int4 q3 = *(const int4*)(ip + 12);
    int4 q4 = *(const int4*)(ip + 16);
    float m = NEGINF;
#define STEP(j)                                   \
    {                                             \
      float u = up[(size_t)(j) * OO + o];         \
      float y = fmaf(A, u + vv, Bs);              \
      y = fmaxf(y, NEG * y);                      \
      m = fmaxf(m, y);                            \
    }
    STEP(q0.x) STEP(q0.y) STEP(q0.z) STEP(q0.w)
    STEP(q1.x) STEP(q1.y) STEP(q1.z) STEP(q1.w)
    STEP(q2.x) STEP(q2.y) STEP(q2.z) STEP(q2.w)
    STEP(q3.x) STEP(q3.y) STEP(q3.z) STEP(q3.w)
    STEP(q4.x) STEP(q4.y) STEP(q4.z) STEP(q4.w)
#undef STEP
    lt[nl * 65 + o] = m;
  }
  __syncthreads();
  int oo = t >> 2, part = t & 3;
#pragma unroll
  for (int mq = 0; mq < 4; ++mq) {
    int n0 = part * 16 + mq * 4;
    float4 vvv;
    vvv.x = lt[(n0 + 0) * 65 + oo];
    vvv.y = lt[(n0 + 1) * 65 + oo];
    vvv.z = lt[(n0 + 2) * 65 + oo];
    vvv.w = lt[(n0 + 3) * 65 + oo];
    *(float4*)(outp + ((size_t)b * OO + oo) * NN + nb + n0) = vvv;
  }
}

extern "C" void kernel_launch(void* const* d_in, const int* in_sizes, int n_in,
                              void* d_out, int out_size, void* d_ws, size_t ws_size,
                              hipStream_t stream) {
  const float* x = (const float*)d_in[0];
  const float* W = (const float*)d_in[1];
  const float* gamma = (const float*)d_in[2];
  const float* beta = (const float*)d_in[3];
  float* outp = (float*)d_out;
  char* ws = (char*)d_ws;

  const size_t NQ = (size_t)BB * NN;  // 32768 queries
  size_t off = 0;
  float* hg = (float*)(ws + off); off += NQ * 4;                      // 128 KB
  float* thr = (float*)(ws + off); off += NQ * 4;                     // 128 KB
  int* cnt8 = (int*)(ws + off); off += NQ * NSPLIT * 4;               // 1 MB
  int* gcnt = (int*)(ws + off); off += NQ * 4;                        // 128 KB
  int* idxk = (int*)(ws + off); off += NQ * KK * 4;                   // 2.6 MB
  float* gsum = (float*)(ws + off); off += 256;
  float* gsqs = (float*)(ws + off); off += 256;
  float* AB = (float*)(ws + off); off += 512;
  // overlapped region:
  //  phase 1 (knnA/thresh): candv                 = 20 MB
  //  phase 2 (collect/final): segs (20MB) + pool  = 25.2 MB
  //  phase 3 (uv/stats/out): ut (8MB) + vt (8MB)  = 16 MB
  char* region = ws + off;
  float* candv = (float*)region;                                      // 20 MB
  float* segs = (float*)region;                                       // 20 MB
  float* pool = (float*)(region + NQ * NSPLIT * CAPS * 2 * 4);        // 5.2 MB
  float* ut = (float*)region;                                         // 8 MB
  float* vt = (float*)(region + NQ * OO * 4);                         // 8 MB

  k_sq<<<BB * NN / 256, 256, 0, stream>>>(x, hg);
  k_knnA<<<BB * 16 * NSPLIT, 256, 0, stream>>>(x, hg, candv);
  k_thresh<<<BB * NN / 256, 256, 0, stream>>>(candv, thr);
  hipMemsetAsync(gcnt, 0, NQ * 4, stream);
  k_collect<<<BB * 16 * NSPLIT, 256, 0, stream>>>(x, hg, thr, cnt8, gcnt, segs, pool);
  k_final<<<BB * NN / 256, 256, 0, stream>>>(segs, cnt8, pool, gcnt, idxk);
  k_uv<<<BB * 64, 256, 0, stream>>>(x, W, ut, vt);
  hipMemsetAsync(gsum, 0, 512, stream);
  k_stats<<<BB * 64, 256, 0, stream>>>(ut, vt, idxk, gsum, gsqs);
  k_bn<<<1, 64, 0, stream>>>(gsum, gsqs, gamma, beta, AB);
  k_out<<<BB * 64, 256, 0, stream>>>(ut, vt, idxk, AB, outp);
}

// Round 5
// 1798.048 us; speedup vs baseline: 11.9778x; 11.9778x over previous
//
#include <hip/hip_runtime.h>
#include <cstdint>
#include <cstddef>

#define BB 8
#define CC 64
#define NN 4096
#define OO 64
#define KK 20
#define KC 58
#define KSKIP 6
#define NSPLIT 8
#define JS 512            // j's per split
#define CAPS 10           // per-(query,split) direct candidate slots
#define GCAP 20           // per-query overflow pool slots
#define BN_EPS 1e-5f
#define NEG 0.2f
#define NEGINF (-3.402823466e38f)
#define M_TOTAL 655360.0f   // B*N*K

#define MED3F(a, b, c) __builtin_amdgcn_fmed3f((a), (b), (c))

// VGPR-CAP MODEL (measured r0-r4): hipcc cap = 256 / max(min_waves_arg,
// derived_min), where derived_min comes from flat workgroup size:
//   no launch_bounds      -> flat wg 1024 -> 16 waves -> min 4 waves/EU -> cap 64 (SPILLS)
//   __launch_bounds__(256)        -> min 1 -> cap 256  (round-0 known-good)
//   __launch_bounds__(256,2/3/4)  -> cap 128/84/64     (all spill for scan kernels)
// Scan kernels' live set is >128: ONLY single-arg (256) avoids spill.
// ALWAYS use single-arg __launch_bounds__(256) on 256-thread kernels here.

// ---------------- K0: h = 0.5*||x_{6:}||^2 per point ----------------
__global__ __launch_bounds__(256) void k_sq(const float* __restrict__ x, float* __restrict__ h) {
  int n = blockIdx.x * 256 + threadIdx.x;  // 0 .. BB*NN-1
  int b = n >> 12;
  int nn = n & (NN - 1);
  const float* xp = x + ((size_t)b * CC + KSKIP) * NN + nn;
  float s = 0.f;
#pragma unroll
  for (int c = 0; c < KC; ++c) {
    float v = xp[(size_t)c * NN];
    s = fmaf(v, v, s);
  }
  h[n] = 0.5f * s;
}

// med3 ripple: insert e into descending top-20 value list. 20 independent ops.
#define RIP(tv, e)                                   \
  do {                                               \
    float _e = (e);                                  \
    tv[19] = MED3F(tv[18], tv[19], _e);              \
    tv[18] = MED3F(tv[17], tv[18], _e);              \
    tv[17] = MED3F(tv[16], tv[17], _e);              \
    tv[16] = MED3F(tv[15], tv[16], _e);              \
    tv[15] = MED3F(tv[14], tv[15], _e);              \
    tv[14] = MED3F(tv[13], tv[14], _e);              \
    tv[13] = MED3F(tv[12], tv[13], _e);              \
    tv[12] = MED3F(tv[11], tv[12], _e);              \
    tv[11] = MED3F(tv[10], tv[11], _e);              \
    tv[10] = MED3F(tv[9],  tv[10], _e);              \
    tv[9]  = MED3F(tv[8],  tv[9],  _e);              \
    tv[8]  = MED3F(tv[7],  tv[8],  _e);              \
    tv[7]  = MED3F(tv[6],  tv[7],  _e);              \
    tv[6]  = MED3F(tv[5],  tv[6],  _e);              \
    tv[5]  = MED3F(tv[4],  tv[5],  _e);              \
    tv[4]  = MED3F(tv[3],  tv[4],  _e);              \
    tv[3]  = MED3F(tv[2],  tv[3],  _e);              \
    tv[2]  = MED3F(tv[1],  tv[2],  _e);              \
    tv[1]  = MED3F(tv[0],  tv[1],  _e);              \
    tv[0]  = fmaxf(tv[0], _e);                       \
  } while (0)

// distance batch: 8 j's per group; MUST be textually identical in pass A and B
// (bit-exact fp32 required for threshold re-scan).
#define DIST8(jq)                                                     \
  float a0 = 0.f, a1 = 0.f, a2 = 0.f, a3 = 0.f;                       \
  float a4 = 0.f, a5 = 0.f, a6 = 0.f, a7 = 0.f;                       \
  _Pragma("unroll")                                                   \
  for (int c = 0; c < KC; ++c) {                                      \
    float4 xA = *(const float4*)(ltile + c * 64 + (jq) * 8);          \
    float4 xB = *(const float4*)(ltile + c * 64 + (jq) * 8 + 4);      \
    float xic = xi[c];                                                \
    a0 = fmaf(xic, xA.x, a0);                                         \
    a1 = fmaf(xic, xA.y, a1);                                         \
    a2 = fmaf(xic, xA.z, a2);                                         \
    a3 = fmaf(xic, xA.w, a3);                                         \
    a4 = fmaf(xic, xB.x, a4);                                         \
    a5 = fmaf(xic, xB.y, a5);                                         \
    a6 = fmaf(xic, xB.z, a6);                                         \
    a7 = fmaf(xic, xB.w, a7);                                         \
  }                                                                   \
  float4 hA = *(const float4*)(lh + (jq) * 8);                        \
  float4 hB = *(const float4*)(lh + (jq) * 8 + 4);                    \
  float d0 = a0 - hA.x;                                               \
  float d1 = a1 - hA.y;                                               \
  float d2 = a2 - hA.z;                                               \
  float d3 = a3 - hA.w;                                               \
  float d4 = a4 - hB.x;                                               \
  float d5 = a5 - hB.y;                                               \
  float d6 = a6 - hB.z;                                               \
  float d7 = a7 - hB.w;

#define STAGE_TILE(jbase)                                             \
  __syncthreads();                                                    \
  for (int f = t; f < KC * 16; f += 256) {                            \
    int c = f >> 4, q = f & 15;                                       \
    float4 v = *(const float4*)(xb + c * NN + (jbase) + q * 4);       \
    *(float4*)(ltile + c * 64 + q * 4) = v;                           \
  }                                                                   \
  if (t < 64) lh[t] = hg[b * NN + (jbase) + t];                       \
  __syncthreads();

// ---------------- Pass A: per-(query, split) top-20 VALUES only ----------------
// grid: BB(8) x itile(16) x split(8) = 1024 blocks of 256 threads.
__global__ __launch_bounds__(256) void k_knnA(const float* __restrict__ x,
                                              const float* __restrict__ hg,
                                              float* __restrict__ candv) {
  __shared__ float ltile[KC * 64];
  __shared__ float lh[64];
  int t = threadIdx.x;
  int lane = t & 63;
  int w = t >> 6;
  int bidx = blockIdx.x;
  int b = bidx >> 7;
  int itile = (bidx >> 3) & 15;
  int split = bidx & 7;
  int i = itile * 256 + w * 64 + lane;
  const float* xb = x + ((size_t)b * CC + KSKIP) * NN;

  float xi[KC];
#pragma unroll
  for (int c = 0; c < KC; ++c) xi[c] = xb[c * NN + i];

  float tv[KK];
#pragma unroll
  for (int s = 0; s < KK; ++s) tv[s] = NEGINF;

#pragma unroll 1
  for (int jt = 0; jt < JS / 64; ++jt) {
    int jbase = split * JS + jt * 64;
    STAGE_TILE(jbase)
#pragma unroll 1
    for (int jq = 0; jq < 8; ++jq) {
      DIST8(jq)
      RIP(tv, d0); RIP(tv, d1); RIP(tv, d2); RIP(tv, d3);
      RIP(tv, d4); RIP(tv, d5); RIP(tv, d6); RIP(tv, d7);
    }
  }

  float* cv = candv + (((size_t)(b * NN + i)) * NSPLIT + split) * KK;
#pragma unroll
  for (int s = 0; s < KK; ++s) cv[s] = tv[s];
}

// ---------------- merge split value-lists -> exact 20th-largest threshold ----------------
__global__ __launch_bounds__(256) void k_thresh(const float* __restrict__ candv,
                                                float* __restrict__ thr) {
  int qi = blockIdx.x * 256 + threadIdx.x;  // 0..BB*NN-1
  const float* cv = candv + (size_t)qi * NSPLIT * KK;
  float tv[KK];
#pragma unroll
  for (int s = 0; s < KK; ++s) tv[s] = NEGINF;
#pragma unroll 1
  for (int s = 0; s < NSPLIT * KK; ++s) {
    RIP(tv, cv[s]);
  }
  thr[qi] = tv[19];
}

// ---------------- Pass B: re-scan, collect j with d >= thr ----------------
// Per-(query,split) private segment + register-local counter: no atomic-return
// dependency in the hot path. Rare overflow (>CAPS hits in one split) spills
// to a per-query atomic pool.
__global__ __launch_bounds__(256) void k_collect(const float* __restrict__ x,
                                                 const float* __restrict__ hg,
                                                 const float* __restrict__ thr,
                                                 int* __restrict__ cnt8,
                                                 int* __restrict__ gcnt,
                                                 float* __restrict__ segs,
                                                 float* __restrict__ pool) {
  __shared__ float ltile[KC * 64];
  __shared__ float lh[64];
  int t = threadIdx.x;
  int lane = t & 63;
  int w = t >> 6;
  int bidx = blockIdx.x;
  int b = bidx >> 7;
  int itile = (bidx >> 3) & 15;
  int split = bidx & 7;
  int i = itile * 256 + w * 64 + lane;
  int qi = b * NN + i;
  const float* xb = x + ((size_t)b * CC + KSKIP) * NN;

  float xi[KC];
#pragma unroll
  for (int c = 0; c < KC; ++c) xi[c] = xb[c * NN + i];
  float ti_ = thr[qi];
  float* seg = segs + (((size_t)qi * NSPLIT) + split) * CAPS * 2;
  int p = 0;

#define EMIT(dv, jj)                                                  \
  if ((dv) >= ti_) {                                                  \
    float2 pr;                                                        \
    pr.x = (dv);                                                      \
    pr.y = __int_as_float(jj);                                        \
    if (p < CAPS) {                                                   \
      *(float2*)(seg + p * 2) = pr;                                   \
    } else {                                                          \
      int g = atomicAdd(&gcnt[qi], 1);                                \
      if (g < GCAP) *(float2*)(pool + ((size_t)qi * GCAP + g) * 2) = pr; \
    }                                                                 \
    ++p;                                                              \
  }

#pragma unroll 1
  for (int jt = 0; jt < JS / 64; ++jt) {
    int jbase = split * JS + jt * 64;
    STAGE_TILE(jbase)
#pragma unroll 1
    for (int jq = 0; jq < 8; ++jq) {
      DIST8(jq)
      int j0 = jbase + jq * 8;
      EMIT(d0, j0 + 0) EMIT(d1, j0 + 1) EMIT(d2, j0 + 2) EMIT(d3, j0 + 3)
      EMIT(d4, j0 + 4) EMIT(d5, j0 + 5) EMIT(d6, j0 + 6) EMIT(d7, j0 + 7)
    }
  }
#undef EMIT
  cnt8[qi * NSPLIT + split] = p;
}

// ---------------- final: lexicographic top-20 over segments + pool ----------------
// tie at equal d -> smaller j wins (matches jax.lax.top_k). Output order
// irrelevant downstream (sum/max over k).
__global__ __launch_bounds__(256) void k_final(const float* __restrict__ segs,
                                               const int* __restrict__ cnt8,
                                               const float* __restrict__ pool,
                                               const int* __restrict__ gcnt,
                                               int* __restrict__ idxk) {
  int qi = blockIdx.x * 256 + threadIdx.x;
  float tv[KK];
  int ti[KK];
#pragma unroll
  for (int s = 0; s < KK; ++s) { tv[s] = NEGINF; ti[s] = 0; }

#define INSERT(pr)                                                            \
  {                                                                           \
    float d = pr.x;                                                           \
    int j = __float_as_int(pr.y);                                             \
    bool acc = (d > tv[KK - 1]) || (d == tv[KK - 1] && j < ti[KK - 1]);       \
    if (acc) {                                                                \
      tv[KK - 1] = d;                                                         \
      ti[KK - 1] = j;                                                         \
      _Pragma("unroll")                                                       \
      for (int s = KK - 1; s > 0; --s) {                                      \
        bool gt_ = (tv[s] > tv[s - 1]) || (tv[s] == tv[s - 1] && ti[s] < ti[s - 1]); \
        float vh_ = gt_ ? tv[s] : tv[s - 1];                                  \
        float vl_ = gt_ ? tv[s - 1] : tv[s];                                  \
        int ih_ = gt_ ? ti[s] : ti[s - 1];                                    \
        int il_ = gt_ ? ti[s - 1] : ti[s];                                    \
        tv[s - 1] = vh_; tv[s] = vl_;                                         \
        ti[s - 1] = ih_; ti[s] = il_;                                         \
      }                                                                       \
    }                                                                         \
  }

#pragma unroll 1
  for (int sp = 0; sp < NSPLIT; ++sp) {
    int c = cnt8[qi * NSPLIT + sp];
    if (c > CAPS) c = CAPS;
    const float* cp = segs + (((size_t)qi * NSPLIT) + sp) * CAPS * 2;
#pragma unroll 1
    for (int e = 0; e < c; ++e) {
      float2 pr = *(const float2*)(cp + e * 2);
      INSERT(pr)
    }
  }
  int g = gcnt[qi];
  if (g > GCAP) g = GCAP;
  const float* pp = pool + (size_t)qi * GCAP * 2;
#pragma unroll 1
  for (int e = 0; e < g; ++e) {
    float2 pr = *(const float2*)(pp + e * 2);
    INSERT(pr)
  }
#undef INSERT

  int* op = idxk + (size_t)qi * KK;
#pragma unroll
  for (int s = 0; s < KK; ++s) op[s] = ti[s];
}

// ---------------- K2: u = W1^T x, v = (W2-W1)^T x, stored (b, n, o) ----------------
__global__ __launch_bounds__(256) void k_uv(const float* __restrict__ x,
                                            const float* __restrict__ W,
                                            float* __restrict__ ut, float* __restrict__ vt) {
  __shared__ float w1[64 * 65];
  __shared__ float wd[64 * 65];
  __shared__ float xs[64 * 72];
  int t = threadIdx.x;
  int b = blockIdx.x >> 6;
  int nbase = (blockIdx.x & 63) * 64;

  for (int f = t; f < 4096; f += 256) {
    int o = f >> 6, c = f & 63;
    float a = W[o * 128 + c];
    float b2 = W[o * 128 + 64 + c];
    w1[c * 65 + o] = a;
    wd[c * 65 + o] = b2 - a;
  }
  for (int f = t; f < 1024; f += 256) {
    int c = f >> 4, q = f & 15;
    float4 v = *(const float4*)(x + ((size_t)b * CC + c) * NN + nbase + q * 4);
    *(float4*)(xs + c * 72 + q * 4) = v;
  }
  __syncthreads();

  int o = t & 63, w = t >> 6;
  float4 au[4], av[4];
#pragma unroll
  for (int nq = 0; nq < 4; ++nq) {
    au[nq] = make_float4(0.f, 0.f, 0.f, 0.f);
    av[nq] = make_float4(0.f, 0.f, 0.f, 0.f);
  }
#pragma unroll 4
  for (int c = 0; c < 64; ++c) {
    float w1v = w1[c * 65 + o];
    float wdv = wd[c * 65 + o];
#pragma unroll
    for (int nq = 0; nq < 4; ++nq) {
      float4 xv = *(const float4*)(xs + c * 72 + w * 16 + nq * 4);
      au[nq].x = fmaf(w1v, xv.x, au[nq].x);
      au[nq].y = fmaf(w1v, xv.y, au[nq].y);
      au[nq].z = fmaf(w1v, xv.z, au[nq].z);
      au[nq].w = fmaf(w1v, xv.w, au[nq].w);
      av[nq].x = fmaf(wdv, xv.x, av[nq].x);
      av[nq].y = fmaf(wdv, xv.y, av[nq].y);
      av[nq].z = fmaf(wdv, xv.z, av[nq].z);
      av[nq].w = fmaf(wdv, xv.w, av[nq].w);
    }
  }
#pragma unroll
  for (int nq = 0; nq < 4; ++nq) {
    int n = nbase + w * 16 + nq * 4;
    size_t base = ((size_t)b * NN + n) * OO + o;
    ut[base + 0 * OO] = au[nq].x;
    ut[base + 1 * OO] = au[nq].y;
    ut[base + 2 * OO] = au[nq].z;
    ut[base + 3 * OO] = au[nq].w;
    vt[base + 0 * OO] = av[nq].x;
    vt[base + 1 * OO] = av[nq].y;
    vt[base + 2 * OO] = av[nq].z;
    vt[base + 3 * OO] = av[nq].w;
  }
}

// ---------------- K3: BN sum / sumsq over all (b,n,k) per channel ----------------
__global__ __launch_bounds__(256) void k_stats(const float* __restrict__ ut,
                                               const float* __restrict__ vt,
                                               const int* __restrict__ idxk,
                                               float* __restrict__ gsum,
                                               float* __restrict__ gsqs) {
  __shared__ float red[2][4][64];
  int t = threadIdx.x;
  int o = t & 63, w = t >> 6;
  int b = blockIdx.x >> 6;
  int nbase = (blockIdx.x & 63) * 64 + w * 16;
  const float* up = ut + (size_t)b * NN * OO;
  float s = 0.f, s2 = 0.f;
#pragma unroll 1
  for (int nn2 = 0; nn2 < 16; ++nn2) {
    int n = nbase + nn2;
    float vv = vt[((size_t)b * NN + n) * OO + o];
    const int* ip = idxk + ((size_t)b * NN + n) * KK;
    int4 q0 = *(const int4*)(ip + 0);
    int4 q1 = *(const int4*)(ip + 4);
    int4 q2 = *(const int4*)(ip + 8);
    int4 q3 = *(const int4*)(ip + 12);
    int4 q4 = *(const int4*)(ip + 16);
#define ACC(j)                                  \
    {                                           \
      float u = up[(size_t)(j) * OO + o];       \
      float yy = u + vv;                        \
      s += yy;                                  \
      s2 = fmaf(yy, yy, s2);                    \
    }
    ACC(q0.x) ACC(q0.y) ACC(q0.z) ACC(q0.w)
    ACC(q1.x) ACC(q1.y) ACC(q1.z) ACC(q1.w)
    ACC(q2.x) ACC(q2.y) ACC(q2.z) ACC(q2.w)
    ACC(q3.x) ACC(q3.y) ACC(q3.z) ACC(q3.w)
    ACC(q4.x) ACC(q4.y) ACC(q4.z) ACC(q4.w)
#undef ACC
  }
  red[0][w][o] = s;
  red[1][w][o] = s2;
  __syncthreads();
  if (w == 0) {
    float ts = red[0][0][o] + red[0][1][o] + red[0][2][o] + red[0][3][o];
    float t2 = red[1][0][o] + red[1][1][o] + red[1][2][o] + red[1][3][o];
    atomicAdd(&gsum[o], ts);
    atomicAdd(&gsqs[o], t2);
  }
}

// ---------------- K4: finalize BN affine ----------------
__global__ void k_bn(const float* __restrict__ gsum, const float* __restrict__ gsqs,
                     const float* __restrict__ gamma, const float* __restrict__ beta,
                     float* __restrict__ AB) {
  int o = threadIdx.x;
  float mean = gsum[o] * (1.f / M_TOTAL);
  float var = gsqs[o] * (1.f / M_TOTAL) - mean * mean;
  float A = gamma[o] / sqrtf(var + BN_EPS);
  AB[o] = A;
  AB[64 + o] = beta[o] - mean * A;
}

// ---------------- K5: normalized + leakyrelu + max over k, transposed store ----------------
__global__ __launch_bounds__(256) void k_out(const float* __restrict__ ut,
                                             const float* __restrict__ vt,
                                             const int* __restrict__ idxk,
                                             const float* __restrict__ AB,
                                             float* __restrict__ outp) {
  __shared__ float lt[64 * 65];
  int t = threadIdx.x;
  int o = t & 63, w = t >> 6;
  int b = blockIdx.x >> 6;
  int nb = (blockIdx.x & 63) * 64;
  float A = AB[o], Bs = AB[64 + o];
  const float* up = ut + (size_t)b * NN * OO;
#pragma unroll 1
  for (int nn2 = 0; nn2 < 16; ++nn2) {
    int nl = w * 16 + nn2;
    int n = nb + nl;
    float vv = vt[((size_t)b * NN + n) * OO + o];
    const int* ip = idxk + ((size_t)b * NN + n) * KK;
    int4 q0 = *(const int4*)(ip + 0);
    int4 q1 = *(const int4*)(ip + 4);
    int4 q2 = *(const int4*)(ip + 8);
    int4 q3 = *(const int4*)(ip + 12);
    int4 q4 = *(const int4*)(ip + 16);
    float m = NEGINF;
#define STEP(j)                                   \
    {                                             \
      float u = up[(size_t)(j) * OO + o];         \
      float y = fmaf(A, u + vv, Bs);              \
      y = fmaxf(y, NEG * y);                      \
      m = fmaxf(m, y);                            \
    }
    STEP(q0.x) STEP(q0.y) STEP(q0.z) STEP(q0.w)
    STEP(q1.x) STEP(q1.y) STEP(q1.z) STEP(q1.w)
    STEP(q2.x) STEP(q2.y) STEP(q2.z) STEP(q2.w)
    STEP(q3.x) STEP(q3.y) STEP(q3.z) STEP(q3.w)
    STEP(q4.x) STEP(q4.y) STEP(q4.z) STEP(q4.w)
#undef STEP
    lt[nl * 65 + o] = m;
  }
  __syncthreads();
  int oo = t >> 2, part = t & 3;
#pragma unroll
  for (int mq = 0; mq < 4; ++mq) {
    int n0 = part * 16 + mq * 4;
    float4 vvv;
    vvv.x = lt[(n0 + 0) * 65 + oo];
    vvv.y = lt[(n0 + 1) * 65 + oo];
    vvv.z = lt[(n0 + 2) * 65 + oo];
    vvv.w = lt[(n0 + 3) * 65 + oo];
    *(float4*)(outp + ((size_t)b * OO + oo) * NN + nb + n0) = vvv;
  }
}

extern "C" void kernel_launch(void* const* d_in, const int* in_sizes, int n_in,
                              void* d_out, int out_size, void* d_ws, size_t ws_size,
                              hipStream_t stream) {
  const float* x = (const float*)d_in[0];
  const float* W = (const float*)d_in[1];
  const float* gamma = (const float*)d_in[2];
  const float* beta = (const float*)d_in[3];
  float* outp = (float*)d_out;
  char* ws = (char*)d_ws;

  const size_t NQ = (size_t)BB * NN;  // 32768 queries
  size_t off = 0;
  float* hg = (float*)(ws + off); off += NQ * 4;                      // 128 KB
  float* thr = (float*)(ws + off); off += NQ * 4;                     // 128 KB
  int* cnt8 = (int*)(ws + off); off += NQ * NSPLIT * 4;               // 1 MB
  int* gcnt = (int*)(ws + off); off += NQ * 4;                        // 128 KB
  int* idxk = (int*)(ws + off); off += NQ * KK * 4;                   // 2.6 MB
  float* gsum = (float*)(ws + off); off += 256;
  float* gsqs = (float*)(ws + off); off += 256;
  float* AB = (float*)(ws + off); off += 512;
  // overlapped region:
  //  phase 1 (knnA/thresh): candv                 = 20 MB
  //  phase 2 (collect/final): segs (20MB) + pool  = 25.2 MB
  //  phase 3 (uv/stats/out): ut (8MB) + vt (8MB)  = 16 MB
  char* region = ws + off;
  float* candv = (float*)region;                                      // 20 MB
  float* segs = (float*)region;                                       // 20 MB
  float* pool = (float*)(region + NQ * NSPLIT * CAPS * 2 * 4);        // 5.2 MB
  float* ut = (float*)region;                                         // 8 MB
  float* vt = (float*)(region + NQ * OO * 4);                         // 8 MB

  k_sq<<<BB * NN / 256, 256, 0, stream>>>(x, hg);
  k_knnA<<<BB * 16 * NSPLIT, 256, 0, stream>>>(x, hg, candv);
  k_thresh<<<BB * NN / 256, 256, 0, stream>>>(candv, thr);
  hipMemsetAsync(gcnt, 0, NQ * 4, stream);
  k_collect<<<BB * 16 * NSPLIT, 256, 0, stream>>>(x, hg, thr, cnt8, gcnt, segs, pool);
  k_final<<<BB * NN / 256, 256, 0, stream>>>(segs, cnt8, pool, gcnt, idxk);
  k_uv<<<BB * 64, 256, 0, stream>>>(x, W, ut, vt);
  hipMemsetAsync(gsum, 0, 512, stream);
  k_stats<<<BB * 64, 256, 0, stream>>>(ut, vt, idxk, gsum, gsqs);
  k_bn<<<1, 64, 0, stream>>>(gsum, gsqs, gamma, beta, AB);
  k_out<<<BB * 64, 256, 0, stream>>>(ut, vt, idxk, AB, outp);
}

// Round 6
// 1778.694 us; speedup vs baseline: 12.1081x; 1.0109x over previous
//
#include <hip/hip_runtime.h>
#include <cstdint>
#include <cstddef>

#define BB 8
#define CC 64
#define NN 4096
#define OO 64
#define KK 20
#define KC 58
#define KSKIP 6
#define NSPLIT 8
#define JS 512            // j's per split
#define CAPS 10           // per-(query,split) direct candidate slots
#define GCAP 20           // per-query overflow pool slots
#define BN_EPS 1e-5f
#define NEG 0.2f
#define NEGINF (-3.402823466e38f)
#define M_TOTAL 655360.0f   // B*N*K

#define MED3F(a, b, c) __builtin_amdgcn_fmed3f((a), (b), (c))

// VGPR-CAP MODEL (measured r0-r5): hipcc cap = 256 / waves_per_EU_bound.
//   no launch_bounds              -> flat-wg default 1024 -> cap 64
//   __launch_bounds__(256)        -> cap 256
//   __launch_bounds__(256,2/3/4)  -> cap 128/84/64
// TWO-SIDED LESSON:
//  - scan kernels (k_knnA/k_collect, live set >128): need single-arg (256)
//    or they spill (r1-r4: FETCH 31MB -> 24-46GB, VALUBusy ~2%).
//  - low-pressure gather kernels (k_uv/k_stats/k_out, live set <64): LEAVE
//    UNBOUNDED. The default 64-cap is a free occupancy floor; giving them
//    (256) let the compiler stretch live ranges and cost ~320us (r5).

// ---------------- K0: h = 0.5*||x_{6:}||^2 per point ----------------
__global__ void k_sq(const float* __restrict__ x, float* __restrict__ h) {
  int n = blockIdx.x * 256 + threadIdx.x;  // 0 .. BB*NN-1
  int b = n >> 12;
  int nn = n & (NN - 1);
  const float* xp = x + ((size_t)b * CC + KSKIP) * NN + nn;
  float s = 0.f;
#pragma unroll
  for (int c = 0; c < KC; ++c) {
    float v = xp[(size_t)c * NN];
    s = fmaf(v, v, s);
  }
  h[n] = 0.5f * s;
}

// med3 ripple: insert e into descending top-20 value list. 20 independent ops.
#define RIP(tv, e)                                   \
  do {                                               \
    float _e = (e);                                  \
    tv[19] = MED3F(tv[18], tv[19], _e);              \
    tv[18] = MED3F(tv[17], tv[18], _e);              \
    tv[17] = MED3F(tv[16], tv[17], _e);              \
    tv[16] = MED3F(tv[15], tv[16], _e);              \
    tv[15] = MED3F(tv[14], tv[15], _e);              \
    tv[14] = MED3F(tv[13], tv[14], _e);              \
    tv[13] = MED3F(tv[12], tv[13], _e);              \
    tv[12] = MED3F(tv[11], tv[12], _e);              \
    tv[11] = MED3F(tv[10], tv[11], _e);              \
    tv[10] = MED3F(tv[9],  tv[10], _e);              \
    tv[9]  = MED3F(tv[8],  tv[9],  _e);              \
    tv[8]  = MED3F(tv[7],  tv[8],  _e);              \
    tv[7]  = MED3F(tv[6],  tv[7],  _e);              \
    tv[6]  = MED3F(tv[5],  tv[6],  _e);              \
    tv[5]  = MED3F(tv[4],  tv[5],  _e);              \
    tv[4]  = MED3F(tv[3],  tv[4],  _e);              \
    tv[3]  = MED3F(tv[2],  tv[3],  _e);              \
    tv[2]  = MED3F(tv[1],  tv[2],  _e);              \
    tv[1]  = MED3F(tv[0],  tv[1],  _e);              \
    tv[0]  = fmaxf(tv[0], _e);                       \
  } while (0)

// distance batch: 8 j's per group; MUST be textually identical in pass A and B
// (bit-exact fp32 required for threshold re-scan).
#define DIST8(jq)                                                     \
  float a0 = 0.f, a1 = 0.f, a2 = 0.f, a3 = 0.f;                       \
  float a4 = 0.f, a5 = 0.f, a6 = 0.f, a7 = 0.f;                       \
  _Pragma("unroll")                                                   \
  for (int c = 0; c < KC; ++c) {                                      \
    float4 xA = *(const float4*)(ltile + c * 64 + (jq) * 8);          \
    float4 xB = *(const float4*)(ltile + c * 64 + (jq) * 8 + 4);      \
    float xic = xi[c];                                                \
    a0 = fmaf(xic, xA.x, a0);                                         \
    a1 = fmaf(xic, xA.y, a1);                                         \
    a2 = fmaf(xic, xA.z, a2);                                         \
    a3 = fmaf(xic, xA.w, a3);                                         \
    a4 = fmaf(xic, xB.x, a4);                                         \
    a5 = fmaf(xic, xB.y, a5);                                         \
    a6 = fmaf(xic, xB.z, a6);                                         \
    a7 = fmaf(xic, xB.w, a7);                                         \
  }                                                                   \
  float4 hA = *(const float4*)(lh + (jq) * 8);                        \
  float4 hB = *(const float4*)(lh + (jq) * 8 + 4);                    \
  float d0 = a0 - hA.x;                                               \
  float d1 = a1 - hA.y;                                               \
  float d2 = a2 - hA.z;                                               \
  float d3 = a3 - hA.w;                                               \
  float d4 = a4 - hB.x;                                               \
  float d5 = a5 - hB.y;                                               \
  float d6 = a6 - hB.z;                                               \
  float d7 = a7 - hB.w;

#define STAGE_TILE(jbase)                                             \
  __syncthreads();                                                    \
  for (int f = t; f < KC * 16; f += 256) {                            \
    int c = f >> 4, q = f & 15;                                       \
    float4 v = *(const float4*)(xb + c * NN + (jbase) + q * 4);       \
    *(float4*)(ltile + c * 64 + q * 4) = v;                           \
  }                                                                   \
  if (t < 64) lh[t] = hg[b * NN + (jbase) + t];                       \
  __syncthreads();

// ---------------- Pass A: per-(query, split) top-20 VALUES only ----------------
// grid: BB(8) x itile(16) x split(8) = 1024 blocks of 256 threads.
__global__ __launch_bounds__(256) void k_knnA(const float* __restrict__ x,
                                              const float* __restrict__ hg,
                                              float* __restrict__ candv) {
  __shared__ float ltile[KC * 64];
  __shared__ float lh[64];
  int t = threadIdx.x;
  int lane = t & 63;
  int w = t >> 6;
  int bidx = blockIdx.x;
  int b = bidx >> 7;
  int itile = (bidx >> 3) & 15;
  int split = bidx & 7;
  int i = itile * 256 + w * 64 + lane;
  const float* xb = x + ((size_t)b * CC + KSKIP) * NN;

  float xi[KC];
#pragma unroll
  for (int c = 0; c < KC; ++c) xi[c] = xb[c * NN + i];

  float tv[KK];
#pragma unroll
  for (int s = 0; s < KK; ++s) tv[s] = NEGINF;

#pragma unroll 1
  for (int jt = 0; jt < JS / 64; ++jt) {
    int jbase = split * JS + jt * 64;
    STAGE_TILE(jbase)
#pragma unroll 1
    for (int jq = 0; jq < 8; ++jq) {
      DIST8(jq)
      RIP(tv, d0); RIP(tv, d1); RIP(tv, d2); RIP(tv, d3);
      RIP(tv, d4); RIP(tv, d5); RIP(tv, d6); RIP(tv, d7);
    }
  }

  float* cv = candv + (((size_t)(b * NN + i)) * NSPLIT + split) * KK;
#pragma unroll
  for (int s = 0; s < KK; ++s) cv[s] = tv[s];
}

// ---------------- merge split value-lists -> exact 20th-largest threshold ----------------
__global__ void k_thresh(const float* __restrict__ candv, float* __restrict__ thr) {
  int qi = blockIdx.x * 256 + threadIdx.x;  // 0..BB*NN-1
  const float* cv = candv + (size_t)qi * NSPLIT * KK;
  float tv[KK];
#pragma unroll
  for (int s = 0; s < KK; ++s) tv[s] = NEGINF;
#pragma unroll 1
  for (int s = 0; s < NSPLIT * KK; ++s) {
    RIP(tv, cv[s]);
  }
  thr[qi] = tv[19];
}

// ---------------- Pass B: re-scan, collect j with d >= thr ----------------
// Per-(query,split) private segment + register-local counter: no atomic-return
// dependency in the hot path (proven r5: 1225 -> 922us vs atomic r0 version).
__global__ __launch_bounds__(256) void k_collect(const float* __restrict__ x,
                                                 const float* __restrict__ hg,
                                                 const float* __restrict__ thr,
                                                 int* __restrict__ cnt8,
                                                 int* __restrict__ gcnt,
                                                 float* __restrict__ segs,
                                                 float* __restrict__ pool) {
  __shared__ float ltile[KC * 64];
  __shared__ float lh[64];
  int t = threadIdx.x;
  int lane = t & 63;
  int w = t >> 6;
  int bidx = blockIdx.x;
  int b = bidx >> 7;
  int itile = (bidx >> 3) & 15;
  int split = bidx & 7;
  int i = itile * 256 + w * 64 + lane;
  int qi = b * NN + i;
  const float* xb = x + ((size_t)b * CC + KSKIP) * NN;

  float xi[KC];
#pragma unroll
  for (int c = 0; c < KC; ++c) xi[c] = xb[c * NN + i];
  float ti_ = thr[qi];
  float* seg = segs + (((size_t)qi * NSPLIT) + split) * CAPS * 2;
  int p = 0;

#define EMIT(dv, jj)                                                  \
  if ((dv) >= ti_) {                                                  \
    float2 pr;                                                        \
    pr.x = (dv);                                                      \
    pr.y = __int_as_float(jj);                                        \
    if (p < CAPS) {                                                   \
      *(float2*)(seg + p * 2) = pr;                                   \
    } else {                                                          \
      int g = atomicAdd(&gcnt[qi], 1);                                \
      if (g < GCAP) *(float2*)(pool + ((size_t)qi * GCAP + g) * 2) = pr; \
    }                                                                 \
    ++p;                                                              \
  }

#pragma unroll 1
  for (int jt = 0; jt < JS / 64; ++jt) {
    int jbase = split * JS + jt * 64;
    STAGE_TILE(jbase)
#pragma unroll 1
    for (int jq = 0; jq < 8; ++jq) {
      DIST8(jq)
      int j0 = jbase + jq * 8;
      EMIT(d0, j0 + 0) EMIT(d1, j0 + 1) EMIT(d2, j0 + 2) EMIT(d3, j0 + 3)
      EMIT(d4, j0 + 4) EMIT(d5, j0 + 5) EMIT(d6, j0 + 6) EMIT(d7, j0 + 7)
    }
  }
#undef EMIT
  cnt8[qi * NSPLIT + split] = p;
}

// ---------------- final: lexicographic top-20 over segments + pool ----------------
// tie at equal d -> smaller j wins (matches jax.lax.top_k). Output order
// irrelevant downstream (sum/max over k).
__global__ void k_final(const float* __restrict__ segs, const int* __restrict__ cnt8,
                        const float* __restrict__ pool, const int* __restrict__ gcnt,
                        int* __restrict__ idxk) {
  int qi = blockIdx.x * 256 + threadIdx.x;
  float tv[KK];
  int ti[KK];
#pragma unroll
  for (int s = 0; s < KK; ++s) { tv[s] = NEGINF; ti[s] = 0; }

#define INSERT(pr)                                                            \
  {                                                                           \
    float d = pr.x;                                                           \
    int j = __float_as_int(pr.y);                                             \
    bool acc = (d > tv[KK - 1]) || (d == tv[KK - 1] && j < ti[KK - 1]);       \
    if (acc) {                                                                \
      tv[KK - 1] = d;                                                         \
      ti[KK - 1] = j;                                                         \
      _Pragma("unroll")                                                       \
      for (int s = KK - 1; s > 0; --s) {                                      \
        bool gt_ = (tv[s] > tv[s - 1]) || (tv[s] == tv[s - 1] && ti[s] < ti[s - 1]); \
        float vh_ = gt_ ? tv[s] : tv[s - 1];                                  \
        float vl_ = gt_ ? tv[s - 1] : tv[s];                                  \
        int ih_ = gt_ ? ti[s] : ti[s - 1];                                    \
        int il_ = gt_ ? ti[s - 1] : ti[s];                                    \
        tv[s - 1] = vh_; tv[s] = vl_;                                         \
        ti[s - 1] = ih_; ti[s] = il_;                                         \
      }                                                                       \
    }                                                                         \
  }

#pragma unroll 1
  for (int sp = 0; sp < NSPLIT; ++sp) {
    int c = cnt8[qi * NSPLIT + sp];
    if (c > CAPS) c = CAPS;
    const float* cp = segs + (((size_t)qi * NSPLIT) + sp) * CAPS * 2;
#pragma unroll 1
    for (int e = 0; e < c; ++e) {
      float2 pr = *(const float2*)(cp + e * 2);
      INSERT(pr)
    }
  }
  int g = gcnt[qi];
  if (g > GCAP) g = GCAP;
  const float* pp = pool + (size_t)qi * GCAP * 2;
#pragma unroll 1
  for (int e = 0; e < g; ++e) {
    float2 pr = *(const float2*)(pp + e * 2);
    INSERT(pr)
  }
#undef INSERT

  int* op = idxk + (size_t)qi * KK;
#pragma unroll
  for (int s = 0; s < KK; ++s) op[s] = ti[s];
}

// ---------------- K2: u = W1^T x, v = (W2-W1)^T x, stored (b, n, o) ----------------
__global__ void k_uv(const float* __restrict__ x, const float* __restrict__ W,
                     float* __restrict__ ut, float* __restrict__ vt) {
  __shared__ float w1[64 * 65];
  __shared__ float wd[64 * 65];
  __shared__ float xs[64 * 72];
  int t = threadIdx.x;
  int b = blockIdx.x >> 6;
  int nbase = (blockIdx.x & 63) * 64;

  for (int f = t; f < 4096; f += 256) {
    int o = f >> 6, c = f & 63;
    float a = W[o * 128 + c];
    float b2 = W[o * 128 + 64 + c];
    w1[c * 65 + o] = a;
    wd[c * 65 + o] = b2 - a;
  }
  for (int f = t; f < 1024; f += 256) {
    int c = f >> 4, q = f & 15;
    float4 v = *(const float4*)(x + ((size_t)b * CC + c) * NN + nbase + q * 4);
    *(float4*)(xs + c * 72 + q * 4) = v;
  }
  __syncthreads();

  int o = t & 63, w = t >> 6;
  float4 au[4], av[4];
#pragma unroll
  for (int nq = 0; nq < 4; ++nq) {
    au[nq] = make_float4(0.f, 0.f, 0.f, 0.f);
    av[nq] = make_float4(0.f, 0.f, 0.f, 0.f);
  }
#pragma unroll 4
  for (int c = 0; c < 64; ++c) {
    float w1v = w1[c * 65 + o];
    float wdv = wd[c * 65 + o];
#pragma unroll
    for (int nq = 0; nq < 4; ++nq) {
      float4 xv = *(const float4*)(xs + c * 72 + w * 16 + nq * 4);
      au[nq].x = fmaf(w1v, xv.x, au[nq].x);
      au[nq].y = fmaf(w1v, xv.y, au[nq].y);
      au[nq].z = fmaf(w1v, xv.z, au[nq].z);
      au[nq].w = fmaf(w1v, xv.w, au[nq].w);
      av[nq].x = fmaf(wdv, xv.x, av[nq].x);
      av[nq].y = fmaf(wdv, xv.y, av[nq].y);
      av[nq].z = fmaf(wdv, xv.z, av[nq].z);
      av[nq].w = fmaf(wdv, xv.w, av[nq].w);
    }
  }
#pragma unroll
  for (int nq = 0; nq < 4; ++nq) {
    int n = nbase + w * 16 + nq * 4;
    size_t base = ((size_t)b * NN + n) * OO + o;
    ut[base + 0 * OO] = au[nq].x;
    ut[base + 1 * OO] = au[nq].y;
    ut[base + 2 * OO] = au[nq].z;
    ut[base + 3 * OO] = au[nq].w;
    vt[base + 0 * OO] = av[nq].x;
    vt[base + 1 * OO] = av[nq].y;
    vt[base + 2 * OO] = av[nq].z;
    vt[base + 3 * OO] = av[nq].w;
  }
}

// ---------------- K3: BN sum / sumsq over all (b,n,k) per channel ----------------
__global__ void k_stats(const float* __restrict__ ut, const float* __restrict__ vt,
                        const int* __restrict__ idxk, float* __restrict__ gsum,
                        float* __restrict__ gsqs) {
  __shared__ float red[2][4][64];
  int t = threadIdx.x;
  int o = t & 63, w = t >> 6;
  int b = blockIdx.x >> 6;
  int nbase = (blockIdx.x & 63) * 64 + w * 16;
  const float* up = ut + (size_t)b * NN * OO;
  float s = 0.f, s2 = 0.f;
#pragma unroll 1
  for (int nn2 = 0; nn2 < 16; ++nn2) {
    int n = nbase + nn2;
    float vv = vt[((size_t)b * NN + n) * OO + o];
    const int* ip = idxk + ((size_t)b * NN + n) * KK;
    int4 q0 = *(const int4*)(ip + 0);
    int4 q1 = *(const int4*)(ip + 4);
    int4 q2 = *(const int4*)(ip + 8);
    int4 q3 = *(const int4*)(ip + 12);
    int4 q4 = *(const int4*)(ip + 16);
#define ACC(j)                                  \
    {                                           \
      float u = up[(size_t)(j) * OO + o];       \
      float yy = u + vv;                        \
      s += yy;                                  \
      s2 = fmaf(yy, yy, s2);                    \
    }
    ACC(q0.x) ACC(q0.y) ACC(q0.z) ACC(q0.w)
    ACC(q1.x) ACC(q1.y) ACC(q1.z) ACC(q1.w)
    ACC(q2.x) ACC(q2.y) ACC(q2.z) ACC(q2.w)
    ACC(q3.x) ACC(q3.y) ACC(q3.z) ACC(q3.w)
    ACC(q4.x) ACC(q4.y) ACC(q4.z) ACC(q4.w)
#undef ACC
  }
  red[0][w][o] = s;
  red[1][w][o] = s2;
  __syncthreads();
  if (w == 0) {
    float ts = red[0][0][o] + red[0][1][o] + red[0][2][o] + red[0][3][o];
    float t2 = red[1][0][o] + red[1][1][o] + red[1][2][o] + red[1][3][o];
    atomicAdd(&gsum[o], ts);
    atomicAdd(&gsqs[o], t2);
  }
}

// ---------------- K4: finalize BN affine ----------------
__global__ void k_bn(const float* __restrict__ gsum, const float* __restrict__ gsqs,
                     const float* __restrict__ gamma, const float* __restrict__ beta,
                     float* __restrict__ AB) {
  int o = threadIdx.x;
  float mean = gsum[o] * (1.f / M_TOTAL);
  float var = gsqs[o] * (1.f / M_TOTAL) - mean * mean;
  float A = gamma[o] / sqrtf(var + BN_EPS);
  AB[o] = A;
  AB[64 + o] = beta[o] - mean * A;
}

// ---------------- K5: normalized + leakyrelu + max over k, transposed store ----------------
__global__ void k_out(const float* __restrict__ ut, const float* __restrict__ vt,
                      const int* __restrict__ idxk, const float* __restrict__ AB,
                      float* __restrict__ outp) {
  __shared__ float lt[64 * 65];
  int t = threadIdx.x;
  int o = t & 63, w = t >> 6;
  int b = blockIdx.x >> 6;
  int nb = (blockIdx.x & 63) * 64;
  float A = AB[o], Bs = AB[64 + o];
  const float* up = ut + (size_t)b * NN * OO;
#pragma unroll 1
  for (int nn2 = 0; nn2 < 16; ++nn2) {
    int nl = w * 16 + nn2;
    int n = nb + nl;
    float vv = vt[((size_t)b * NN + n) * OO + o];
    const int* ip = idxk + ((size_t)b * NN + n) * KK;
    int4 q0 = *(const int4*)(ip + 0);
    int4 q1 = *(const int4*)(ip + 4);
    int4 q2 = *(const int4*)(ip + 8);
    int4 q3 = *(const int4*)(ip + 12);
    int4 q4 = *(const int4*)(ip + 16);
    float m = NEGINF;
#define STEP(j)                                   \
    {                                             \
      float u = up[(size_t)(j) * OO + o];         \
      float y = fmaf(A, u + vv, Bs);              \
      y = fmaxf(y, NEG * y);                      \
      m = fmaxf(m, y);                            \
    }
    STEP(q0.x) STEP(q0.y) STEP(q0.z) STEP(q0.w)
    STEP(q1.x) STEP(q1.y) STEP(q1.z) STEP(q1.w)
    STEP(q2.x) STEP(q2.y) STEP(q2.z) STEP(q2.w)
    STEP(q3.x) STEP(q3.y) STEP(q3.z) STEP(q3.w)
    STEP(q4.x) STEP(q4.y) STEP(q4.z) STEP(q4.w)
#undef STEP
    lt[nl * 65 + o] = m;
  }
  __syncthreads();
  int oo = t >> 2, part = t & 3;
#pragma unroll
  for (int mq = 0; mq < 4; ++mq) {
    int n0 = part * 16 + mq * 4;
    float4 vvv;
    vvv.x = lt[(n0 + 0) * 65 + oo];
    vvv.y = lt[(n0 + 1) * 65 + oo];
    vvv.z = lt[(n0 + 2) * 65 + oo];
    vvv.w = lt[(n0 + 3) * 65 + oo];
    *(float4*)(outp + ((size_t)b * OO + oo) * NN + nb + n0) = vvv;
  }
}

extern "C" void kernel_launch(void* const* d_in, const int* in_sizes, int n_in,
                              void* d_out, int out_size, void* d_ws, size_t ws_size,
                              hipStream_t stream) {
  const float* x = (const float*)d_in[0];
  const float* W = (const float*)d_in[1];
  const float* gamma = (const float*)d_in[2];
  const float* beta = (const float*)d_in[3];
  float* outp = (float*)d_out;
  char* ws = (char*)d_ws;

  const size_t NQ = (size_t)BB * NN;  // 32768 queries
  size_t off = 0;
  float* hg = (float*)(ws + off); off += NQ * 4;                      // 128 KB
  float* thr = (float*)(ws + off); off += NQ * 4;                     // 128 KB
  int* cnt8 = (int*)(ws + off); off += NQ * NSPLIT * 4;               // 1 MB
  int* gcnt = (int*)(ws + off); off += NQ * 4;                        // 128 KB
  int* idxk = (int*)(ws + off); off += NQ * KK * 4;                   // 2.6 MB
  float* gsum = (float*)(ws + off); off += 256;
  float* gsqs = (float*)(ws + off); off += 256;
  float* AB = (float*)(ws + off); off += 512;
  // overlapped region:
  //  phase 1 (knnA/thresh): candv                 = 20 MB
  //  phase 2 (collect/final): segs (20MB) + pool  = 25.2 MB
  //  phase 3 (uv/stats/out): ut (8MB) + vt (8MB)  = 16 MB
  char* region = ws + off;
  float* candv = (float*)region;                                      // 20 MB
  float* segs = (float*)region;                                       // 20 MB
  float* pool = (float*)(region + NQ * NSPLIT * CAPS * 2 * 4);        // 5.2 MB
  float* ut = (float*)region;                                         // 8 MB
  float* vt = (float*)(region + NQ * OO * 4);                         // 8 MB

  k_sq<<<BB * NN / 256, 256, 0, stream>>>(x, hg);
  k_knnA<<<BB * 16 * NSPLIT, 256, 0, stream>>>(x, hg, candv);
  k_thresh<<<BB * NN / 256, 256, 0, stream>>>(candv, thr);
  hipMemsetAsync(gcnt, 0, NQ * 4, stream);
  k_collect<<<BB * 16 * NSPLIT, 256, 0, stream>>>(x, hg, thr, cnt8, gcnt, segs, pool);
  k_final<<<BB * NN / 256, 256, 0, stream>>>(segs, cnt8, pool, gcnt, idxk);
  k_uv<<<BB * 64, 256, 0, stream>>>(x, W, ut, vt);
  hipMemsetAsync(gsum, 0, 512, stream);
  k_stats<<<BB * 64, 256, 0, stream>>>(ut, vt, idxk, gsum, gsqs);
  k_bn<<<1, 64, 0, stream>>>(gsum, gsqs, gamma, beta, AB);
  k_out<<<BB * 64, 256, 0, stream>>>(ut, vt, idxk, AB, outp);
}

// Round 7
// 1559.666 us; speedup vs baseline: 13.8085x; 1.1404x over previous
//
#include <hip/hip_runtime.h>
#include <cstdint>
#include <cstddef>

#define BB 8
#define CC 64
#define NN 4096
#define OO 64
#define KK 20
#define KC 58
#define HC 29             // channels per lane (lane-pair split: even 0-28, odd 29-57)
#define KSKIP 6
#define NSPLIT 8
#define JS 512            // j's per split
#define CAPS 10           // per-(query,split) segment slots: 5 even-lane + 5 odd-lane
#define HCAP 5
#define GCAP 20           // per-query overflow pool slots
#define BN_EPS 1e-5f
#define NEG 0.2f
#define NEGINF (-3.402823466e38f)
#define M_TOTAL 655360.0f   // B*N*K

#define MED3F(a, b, c) __builtin_amdgcn_fmed3f((a), (b), (c))

// VGPR-CAP MODEL (measured r0-r5): hipcc cap = 256/waves_per_EU_bound.
//   no bounds -> flat-wg 1024 default -> cap 64; (256)->256; (256,2)->128;
//   (256,3)->84; (256,4)->64. HW residency halves at alloc {64,128,256}
//   -> 8/4/2 waves per SIMD. Old scan structure (xi[58]) spilled at <=128.
//   NEW structure: lane-pair channel split -> xi[29], live ~70-100 -> target
//   (256,2)=128 cap = 4 waves/SIMD (2x the 256-VGPR residency).
// SPILL TRIPWIRE: scan-kernel FETCH_SIZE must stay in MBs. GBs = spill.

// ---------------- K0: h = 0.5*||x_{6:}||^2 per point ----------------
__global__ void k_sq(const float* __restrict__ x, float* __restrict__ h) {
  int n = blockIdx.x * 256 + threadIdx.x;  // 0 .. BB*NN-1
  int b = n >> 12;
  int nn = n & (NN - 1);
  const float* xp = x + ((size_t)b * CC + KSKIP) * NN + nn;
  float s = 0.f;
#pragma unroll
  for (int c = 0; c < KC; ++c) {
    float v = xp[(size_t)c * NN];
    s = fmaf(v, v, s);
  }
  h[n] = 0.5f * s;
}

// med3 ripple: insert e into descending top-20 value list.
#define RIP(tv, e)                                   \
  do {                                               \
    float _e = (e);                                  \
    tv[19] = MED3F(tv[18], tv[19], _e);              \
    tv[18] = MED3F(tv[17], tv[18], _e);              \
    tv[17] = MED3F(tv[16], tv[17], _e);              \
    tv[16] = MED3F(tv[15], tv[16], _e);              \
    tv[15] = MED3F(tv[14], tv[15], _e);              \
    tv[14] = MED3F(tv[13], tv[14], _e);              \
    tv[13] = MED3F(tv[12], tv[13], _e);              \
    tv[12] = MED3F(tv[11], tv[12], _e);              \
    tv[11] = MED3F(tv[10], tv[11], _e);              \
    tv[10] = MED3F(tv[9],  tv[10], _e);              \
    tv[9]  = MED3F(tv[8],  tv[9],  _e);              \
    tv[8]  = MED3F(tv[7],  tv[8],  _e);              \
    tv[7]  = MED3F(tv[6],  tv[7],  _e);              \
    tv[6]  = MED3F(tv[5],  tv[6],  _e);              \
    tv[5]  = MED3F(tv[4],  tv[5],  _e);              \
    tv[4]  = MED3F(tv[3],  tv[4],  _e);              \
    tv[3]  = MED3F(tv[2],  tv[3],  _e);              \
    tv[2]  = MED3F(tv[1],  tv[2],  _e);              \
    tv[1]  = MED3F(tv[0],  tv[1],  _e);              \
    tv[0]  = fmaxf(tv[0], _e);                       \
  } while (0)

// Pair-split distance batch: 16 j's per pair-iteration. Each lane accumulates
// its 29-channel partial for all 16 j's; shfl_xor(1)+add completes the dot
// (commutative add -> bit-identical in both lanes). Even lane then owns
// d for j+0..7, odd lane j+8..15 (via half8 select).
// MUST be textually identical in pass A and B (bit-exact fp32 re-scan).
#define DIST16(jq)                                                    \
  float a0 = 0.f, a1 = 0.f, a2 = 0.f, a3 = 0.f;                       \
  float a4 = 0.f, a5 = 0.f, a6 = 0.f, a7 = 0.f;                       \
  float a8 = 0.f, a9 = 0.f, a10 = 0.f, a11 = 0.f;                     \
  float a12 = 0.f, a13 = 0.f, a14 = 0.f, a15 = 0.f;                   \
  _Pragma("unroll")                                                   \
  for (int cc = 0; cc < HC; ++cc) {                                   \
    float4 x0 = *(const float4*)(ltp + cc * 64 + (jq) * 16);          \
    float4 x1 = *(const float4*)(ltp + cc * 64 + (jq) * 16 + 4);      \
    float4 x2 = *(const float4*)(ltp + cc * 64 + (jq) * 16 + 8);      \
    float4 x3 = *(const float4*)(ltp + cc * 64 + (jq) * 16 + 12);     \
    float xic = xi[cc];                                               \
    a0  = fmaf(xic, x0.x, a0);  a1  = fmaf(xic, x0.y, a1);            \
    a2  = fmaf(xic, x0.z, a2);  a3  = fmaf(xic, x0.w, a3);            \
    a4  = fmaf(xic, x1.x, a4);  a5  = fmaf(xic, x1.y, a5);            \
    a6  = fmaf(xic, x1.z, a6);  a7  = fmaf(xic, x1.w, a7);            \
    a8  = fmaf(xic, x2.x, a8);  a9  = fmaf(xic, x2.y, a9);            \
    a10 = fmaf(xic, x2.z, a10); a11 = fmaf(xic, x2.w, a11);           \
    a12 = fmaf(xic, x3.x, a12); a13 = fmaf(xic, x3.y, a13);           \
    a14 = fmaf(xic, x3.z, a14); a15 = fmaf(xic, x3.w, a15);           \
  }                                                                   \
  a0  += __shfl_xor(a0, 1);  a1  += __shfl_xor(a1, 1);                \
  a2  += __shfl_xor(a2, 1);  a3  += __shfl_xor(a3, 1);                \
  a4  += __shfl_xor(a4, 1);  a5  += __shfl_xor(a5, 1);                \
  a6  += __shfl_xor(a6, 1);  a7  += __shfl_xor(a7, 1);                \
  a8  += __shfl_xor(a8, 1);  a9  += __shfl_xor(a9, 1);                \
  a10 += __shfl_xor(a10, 1); a11 += __shfl_xor(a11, 1);               \
  a12 += __shfl_xor(a12, 1); a13 += __shfl_xor(a13, 1);               \
  a14 += __shfl_xor(a14, 1); a15 += __shfl_xor(a15, 1);               \
  float4 hA = *(const float4*)(lh + (jq) * 16 + half8);               \
  float4 hB = *(const float4*)(lh + (jq) * 16 + half8 + 4);           \
  float d0 = (half8 ? a8  : a0)  - hA.x;                              \
  float d1 = (half8 ? a9  : a1)  - hA.y;                              \
  float d2 = (half8 ? a10 : a2)  - hA.z;                              \
  float d3 = (half8 ? a11 : a3)  - hA.w;                              \
  float d4 = (half8 ? a12 : a4)  - hB.x;                              \
  float d5 = (half8 ? a13 : a5)  - hB.y;                              \
  float d6 = (half8 ? a14 : a6)  - hB.z;                              \
  float d7 = (half8 ? a15 : a7)  - hB.w;

#define STAGE_TILE(jbase)                                             \
  __syncthreads();                                                    \
  for (int f = t; f < KC * 16; f += 256) {                            \
    int c = f >> 4, q = f & 15;                                       \
    float4 v = *(const float4*)(xb + c * NN + (jbase) + q * 4);       \
    *(float4*)(ltile + c * 64 + q * 4) = v;                           \
  }                                                                   \
  if (t < 64) lh[t] = hg[b * NN + (jbase) + t];                       \
  __syncthreads();

// ---------------- Pass A: per-(query, split) top-20 VALUES only ----------------
// grid: BB(8) x itile(32) x split(8) = 2048 blocks of 256 threads.
// 128 queries per block (lane pairs), pair handles 16 j's per DIST16.
__global__ __launch_bounds__(256, 2) void k_knnA(const float* __restrict__ x,
                                                 const float* __restrict__ hg,
                                                 float* __restrict__ candv) {
  __shared__ float ltile[KC * 64];
  __shared__ float lh[64];
  int t = threadIdx.x;
  int l = t & 63;
  int w = t >> 6;
  int half = l & 1;
  int half8 = half * 8;
  int bidx = blockIdx.x;
  int b = bidx >> 8;
  int itile = (bidx >> 3) & 31;
  int split = bidx & 7;
  int i = itile * 128 + w * 32 + (l >> 1);
  const float* xb = x + ((size_t)b * CC + KSKIP) * NN;
  const float* ltp = ltile + half * (HC * 64);

  float xi[HC];
#pragma unroll
  for (int cc = 0; cc < HC; ++cc) xi[cc] = xb[(half * HC + cc) * NN + i];

  float tv[KK];
#pragma unroll
  for (int s = 0; s < KK; ++s) tv[s] = NEGINF;

#pragma unroll 1
  for (int jt = 0; jt < JS / 64; ++jt) {
    int jbase = split * JS + jt * 64;
    STAGE_TILE(jbase)
#pragma unroll 1
    for (int jq = 0; jq < 4; ++jq) {
      DIST16(jq)
      RIP(tv, d0); RIP(tv, d1); RIP(tv, d2); RIP(tv, d3);
      RIP(tv, d4); RIP(tv, d5); RIP(tv, d6); RIP(tv, d7);
    }
  }

  // merge partner lane's list (snapshot first: partner's tv mutates during merge)
  float ov[KK];
#pragma unroll
  for (int s = 0; s < KK; ++s) ov[s] = __shfl_xor(tv[s], 1);
#pragma unroll
  for (int s = 0; s < KK; ++s) { RIP(tv, ov[s]); }

  if (!half) {
    float* cv = candv + (((size_t)(b * NN + i)) * NSPLIT + split) * KK;
#pragma unroll
    for (int s = 0; s < KK; ++s) cv[s] = tv[s];
  }
}

// ---------------- merge split value-lists -> exact 20th-largest threshold ----------------
__global__ void k_thresh(const float* __restrict__ candv, float* __restrict__ thr) {
  int qi = blockIdx.x * 256 + threadIdx.x;  // 0..BB*NN-1
  const float* cv = candv + (size_t)qi * NSPLIT * KK;
  float tv[KK];
#pragma unroll
  for (int s = 0; s < KK; ++s) tv[s] = NEGINF;
#pragma unroll 1
  for (int s = 0; s < NSPLIT * KK; ++s) {
    RIP(tv, cv[s]);
  }
  thr[qi] = tv[19];
}

// ---------------- Pass B: re-scan, collect j with d >= thr ----------------
// Even lane emits j+0..7 into seg slots [0,5); odd lane j+8..15 into [5,10).
// Packed count: cnt8 = p_even | p_odd<<16. Overflow (>5 hits per lane-half,
// P~9e-4) -> per-query atomic pool.
__global__ __launch_bounds__(256, 2) void k_collect(const float* __restrict__ x,
                                                    const float* __restrict__ hg,
                                                    const float* __restrict__ thr,
                                                    int* __restrict__ cnt8,
                                                    int* __restrict__ gcnt,
                                                    float* __restrict__ segs,
                                                    float* __restrict__ pool) {
  __shared__ float ltile[KC * 64];
  __shared__ float lh[64];
  int t = threadIdx.x;
  int l = t & 63;
  int w = t >> 6;
  int half = l & 1;
  int half8 = half * 8;
  int bidx = blockIdx.x;
  int b = bidx >> 8;
  int itile = (bidx >> 3) & 31;
  int split = bidx & 7;
  int i = itile * 128 + w * 32 + (l >> 1);
  int qi = b * NN + i;
  const float* xb = x + ((size_t)b * CC + KSKIP) * NN;
  const float* ltp = ltile + half * (HC * 64);

  float xi[HC];
#pragma unroll
  for (int cc = 0; cc < HC; ++cc) xi[cc] = xb[(half * HC + cc) * NN + i];
  float ti_ = thr[qi];
  float* seg = segs + ((((size_t)qi * NSPLIT) + split) * CAPS + half * HCAP) * 2;
  int p = 0;

#define EMIT(dv, jj)                                                  \
  if ((dv) >= ti_) {                                                  \
    float2 pr;                                                        \
    pr.x = (dv);                                                      \
    pr.y = __int_as_float(jj);                                        \
    if (p < HCAP) {                                                   \
      *(float2*)(seg + p * 2) = pr;                                   \
    } else {                                                          \
      int g = atomicAdd(&gcnt[qi], 1);                                \
      if (g < GCAP) *(float2*)(pool + ((size_t)qi * GCAP + g) * 2) = pr; \
    }                                                                 \
    ++p;                                                              \
  }

#pragma unroll 1
  for (int jt = 0; jt < JS / 64; ++jt) {
    int jbase = split * JS + jt * 64;
    STAGE_TILE(jbase)
#pragma unroll 1
    for (int jq = 0; jq < 4; ++jq) {
      DIST16(jq)
      int j0 = jbase + jq * 16 + half8;
      EMIT(d0, j0 + 0) EMIT(d1, j0 + 1) EMIT(d2, j0 + 2) EMIT(d3, j0 + 3)
      EMIT(d4, j0 + 4) EMIT(d5, j0 + 5) EMIT(d6, j0 + 6) EMIT(d7, j0 + 7)
    }
  }
#undef EMIT
  int po = __shfl_xor(p, 1);
  if (!half) cnt8[qi * NSPLIT + split] = p | (po << 16);
}

// ---------------- final: lexicographic top-20 over segments + pool ----------------
// tie at equal d -> smaller j wins (matches jax.lax.top_k).
__global__ void k_final(const float* __restrict__ segs, const int* __restrict__ cnt8,
                        const float* __restrict__ pool, const int* __restrict__ gcnt,
                        int* __restrict__ idxk) {
  int qi = blockIdx.x * 256 + threadIdx.x;
  float tv[KK];
  int ti[KK];
#pragma unroll
  for (int s = 0; s < KK; ++s) { tv[s] = NEGINF; ti[s] = 0; }

#define INSERT(pr)                                                            \
  {                                                                           \
    float d = pr.x;                                                           \
    int j = __float_as_int(pr.y);                                             \
    bool acc = (d > tv[KK - 1]) || (d == tv[KK - 1] && j < ti[KK - 1]);       \
    if (acc) {                                                                \
      tv[KK - 1] = d;                                                         \
      ti[KK - 1] = j;                                                         \
      _Pragma("unroll")                                                       \
      for (int s = KK - 1; s > 0; --s) {                                      \
        bool gt_ = (tv[s] > tv[s - 1]) || (tv[s] == tv[s - 1] && ti[s] < ti[s - 1]); \
        float vh_ = gt_ ? tv[s] : tv[s - 1];                                  \
        float vl_ = gt_ ? tv[s - 1] : tv[s];                                  \
        int ih_ = gt_ ? ti[s] : ti[s - 1];                                    \
        int il_ = gt_ ? ti[s - 1] : ti[s];                                    \
        tv[s - 1] = vh_; tv[s] = vl_;                                         \
        ti[s - 1] = ih_; ti[s] = il_;                                         \
      }                                                                       \
    }                                                                         \
  }

#pragma unroll 1
  for (int sp = 0; sp < NSPLIT; ++sp) {
    int c = cnt8[qi * NSPLIT + sp];
    int ce = c & 0xffff;
    int co = c >> 16;
    if (ce > HCAP) ce = HCAP;
    if (co > HCAP) co = HCAP;
    const float* cp = segs + (((size_t)qi * NSPLIT) + sp) * CAPS * 2;
#pragma unroll 1
    for (int e = 0; e < ce; ++e) {
      float2 pr = *(const float2*)(cp + e * 2);
      INSERT(pr)
    }
#pragma unroll 1
    for (int e = 0; e < co; ++e) {
      float2 pr = *(const float2*)(cp + (HCAP + e) * 2);
      INSERT(pr)
    }
  }
  int g = gcnt[qi];
  if (g > GCAP) g = GCAP;
  const float* pp = pool + (size_t)qi * GCAP * 2;
#pragma unroll 1
  for (int e = 0; e < g; ++e) {
    float2 pr = *(const float2*)(pp + e * 2);
    INSERT(pr)
  }
#undef INSERT

  int* op = idxk + (size_t)qi * KK;
#pragma unroll
  for (int s = 0; s < KK; ++s) op[s] = ti[s];
}

// ---------------- K2: u = W1^T x, v = (W2-W1)^T x, stored (b, n, o) ----------------
__global__ void k_uv(const float* __restrict__ x, const float* __restrict__ W,
                     float* __restrict__ ut, float* __restrict__ vt) {
  __shared__ float w1[64 * 65];
  __shared__ float wd[64 * 65];
  __shared__ float xs[64 * 72];
  int t = threadIdx.x;
  int b = blockIdx.x >> 6;
  int nbase = (blockIdx.x & 63) * 64;

  for (int f = t; f < 4096; f += 256) {
    int o = f >> 6, c = f & 63;
    float a = W[o * 128 + c];
    float b2 = W[o * 128 + 64 + c];
    w1[c * 65 + o] = a;
    wd[c * 65 + o] = b2 - a;
  }
  for (int f = t; f < 1024; f += 256) {
    int c = f >> 4, q = f & 15;
    float4 v = *(const float4*)(x + ((size_t)b * CC + c) * NN + nbase + q * 4);
    *(float4*)(xs + c * 72 + q * 4) = v;
  }
  __syncthreads();

  int o = t & 63, w = t >> 6;
  float4 au[4], av[4];
#pragma unroll
  for (int nq = 0; nq < 4; ++nq) {
    au[nq] = make_float4(0.f, 0.f, 0.f, 0.f);
    av[nq] = make_float4(0.f, 0.f, 0.f, 0.f);
  }
#pragma unroll 4
  for (int c = 0; c < 64; ++c) {
    float w1v = w1[c * 65 + o];
    float wdv = wd[c * 65 + o];
#pragma unroll
    for (int nq = 0; nq < 4; ++nq) {
      float4 xv = *(const float4*)(xs + c * 72 + w * 16 + nq * 4);
      au[nq].x = fmaf(w1v, xv.x, au[nq].x);
      au[nq].y = fmaf(w1v, xv.y, au[nq].y);
      au[nq].z = fmaf(w1v, xv.z, au[nq].z);
      au[nq].w = fmaf(w1v, xv.w, au[nq].w);
      av[nq].x = fmaf(wdv, xv.x, av[nq].x);
      av[nq].y = fmaf(wdv, xv.y, av[nq].y);
      av[nq].z = fmaf(wdv, xv.z, av[nq].z);
      av[nq].w = fmaf(wdv, xv.w, av[nq].w);
    }
  }
#pragma unroll
  for (int nq = 0; nq < 4; ++nq) {
    int n = nbase + w * 16 + nq * 4;
    size_t base = ((size_t)b * NN + n) * OO + o;
    ut[base + 0 * OO] = au[nq].x;
    ut[base + 1 * OO] = au[nq].y;
    ut[base + 2 * OO] = au[nq].z;
    ut[base + 3 * OO] = au[nq].w;
    vt[base + 0 * OO] = av[nq].x;
    vt[base + 1 * OO] = av[nq].y;
    vt[base + 2 * OO] = av[nq].z;
    vt[base + 3 * OO] = av[nq].w;
  }
}

// ---------------- K3: BN sum / sumsq over all (b,n,k) per channel ----------------
__global__ void k_stats(const float* __restrict__ ut, const float* __restrict__ vt,
                        const int* __restrict__ idxk, float* __restrict__ gsum,
                        float* __restrict__ gsqs) {
  __shared__ float red[2][4][64];
  int t = threadIdx.x;
  int o = t & 63, w = t >> 6;
  int b = blockIdx.x >> 6;
  int nbase = (blockIdx.x & 63) * 64 + w * 16;
  const float* up = ut + (size_t)b * NN * OO;
  float s = 0.f, s2 = 0.f;
#pragma unroll 1
  for (int nn2 = 0; nn2 < 16; ++nn2) {
    int n = nbase + nn2;
    float vv = vt[((size_t)b * NN + n) * OO + o];
    const int* ip = idxk + ((size_t)b * NN + n) * KK;
    int4 q0 = *(const int4*)(ip + 0);
    int4 q1 = *(const int4*)(ip + 4);
    int4 q2 = *(const int4*)(ip + 8);
    int4 q3 = *(const int4*)(ip + 12);
    int4 q4 = *(const int4*)(ip + 16);
#define ACC(j)                                  \
    {                                           \
      float u = up[(size_t)(j) * OO + o];       \
      float yy = u + vv;                        \
      s += yy;                                  \
      s2 = fmaf(yy, yy, s2);                    \
    }
    ACC(q0.x) ACC(q0.y) ACC(q0.z) ACC(q0.w)
    ACC(q1.x) ACC(q1.y) ACC(q1.z) ACC(q1.w)
    ACC(q2.x) ACC(q2.y) ACC(q2.z) ACC(q2.w)
    ACC(q3.x) ACC(q3.y) ACC(q3.z) ACC(q3.w)
    ACC(q4.x) ACC(q4.y) ACC(q4.z) ACC(q4.w)
#undef ACC
  }
  red[0][w][o] = s;
  red[1][w][o] = s2;
  __syncthreads();
  if (w == 0) {
    float ts = red[0][0][o] + red[0][1][o] + red[0][2][o] + red[0][3][o];
    float t2 = red[1][0][o] + red[1][1][o] + red[1][2][o] + red[1][3][o];
    atomicAdd(&gsum[o], ts);
    atomicAdd(&gsqs[o], t2);
  }
}

// ---------------- K4: finalize BN affine ----------------
__global__ void k_bn(const float* __restrict__ gsum, const float* __restrict__ gsqs,
                     const float* __restrict__ gamma, const float* __restrict__ beta,
                     float* __restrict__ AB) {
  int o = threadIdx.x;
  float mean = gsum[o] * (1.f / M_TOTAL);
  float var = gsqs[o] * (1.f / M_TOTAL) - mean * mean;
  float A = gamma[o] / sqrtf(var + BN_EPS);
  AB[o] = A;
  AB[64 + o] = beta[o] - mean * A;
}

// ---------------- K5: normalized + leakyrelu + max over k, transposed store ----------------
__global__ void k_out(const float* __restrict__ ut, const float* __restrict__ vt,
                      const int* __restrict__ idxk, const float* __restrict__ AB,
                      float* __restrict__ outp) {
  __shared__ float lt[64 * 65];
  int t = threadIdx.x;
  int o = t & 63, w = t >> 6;
  int b = blockIdx.x >> 6;
  int nb = (blockIdx.x & 63) * 64;
  float A = AB[o], Bs = AB[64 + o];
  const float* up = ut + (size_t)b * NN * OO;
#pragma unroll 1
  for (int nn2 = 0; nn2 < 16; ++nn2) {
    int nl = w * 16 + nn2;
    int n = nb + nl;
    float vv = vt[((size_t)b * NN + n) * OO + o];
    const int* ip = idxk + ((size_t)b * NN + n) * KK;
    int4 q0 = *(const int4*)(ip + 0);
    int4 q1 = *(const int4*)(ip + 4);
    int4 q2 = *(const int4*)(ip + 8);
    int4 q3 = *(const int4*)(ip + 12);
    int4 q4 = *(const int4*)(ip + 16);
    float m = NEGINF;
#define STEP(j)                                   \
    {                                             \
      float u = up[(size_t)(j) * OO + o];         \
      float y = fmaf(A, u + vv, Bs);              \
      y = fmaxf(y, NEG * y);                      \
      m = fmaxf(m, y);                            \
    }
    STEP(q0.x) STEP(q0.y) STEP(q0.z) STEP(q0.w)
    STEP(q1.x) STEP(q1.y) STEP(q1.z) STEP(q1.w)
    STEP(q2.x) STEP(q2.y) STEP(q2.z) STEP(q2.w)
    STEP(q3.x) STEP(q3.y) STEP(q3.z) STEP(q3.w)
    STEP(q4.x) STEP(q4.y) STEP(q4.z) STEP(q4.w)
#undef STEP
    lt[nl * 65 + o] = m;
  }
  __syncthreads();
  int oo = t >> 2, part = t & 3;
#pragma unroll
  for (int mq = 0; mq < 4; ++mq) {
    int n0 = part * 16 + mq * 4;
    float4 vvv;
    vvv.x = lt[(n0 + 0) * 65 + oo];
    vvv.y = lt[(n0 + 1) * 65 + oo];
    vvv.z = lt[(n0 + 2) * 65 + oo];
    vvv.w = lt[(n0 + 3) * 65 + oo];
    *(float4*)(outp + ((size_t)b * OO + oo) * NN + nb + n0) = vvv;
  }
}

extern "C" void kernel_launch(void* const* d_in, const int* in_sizes, int n_in,
                              void* d_out, int out_size, void* d_ws, size_t ws_size,
                              hipStream_t stream) {
  const float* x = (const float*)d_in[0];
  const float* W = (const float*)d_in[1];
  const float* gamma = (const float*)d_in[2];
  const float* beta = (const float*)d_in[3];
  float* outp = (float*)d_out;
  char* ws = (char*)d_ws;

  const size_t NQ = (size_t)BB * NN;  // 32768 queries
  size_t off = 0;
  float* hg = (float*)(ws + off); off += NQ * 4;                      // 128 KB
  float* thr = (float*)(ws + off); off += NQ * 4;                     // 128 KB
  int* cnt8 = (int*)(ws + off); off += NQ * NSPLIT * 4;               // 1 MB
  int* gcnt = (int*)(ws + off); off += NQ * 4;                        // 128 KB
  int* idxk = (int*)(ws + off); off += NQ * KK * 4;                   // 2.6 MB
  float* gsum = (float*)(ws + off); off += 256;
  float* gsqs = (float*)(ws + off); off += 256;
  float* AB = (float*)(ws + off); off += 512;
  // overlapped region:
  //  phase 1 (knnA/thresh): candv                 = 20 MB
  //  phase 2 (collect/final): segs (20MB) + pool  = 25.2 MB
  //  phase 3 (uv/stats/out): ut (8MB) + vt (8MB)  = 16 MB
  char* region = ws + off;
  float* candv = (float*)region;                                      // 20 MB
  float* segs = (float*)region;                                       // 20 MB
  float* pool = (float*)(region + NQ * NSPLIT * CAPS * 2 * 4);        // 5.2 MB
  float* ut = (float*)region;                                         // 8 MB
  float* vt = (float*)(region + NQ * OO * 4);                         // 8 MB

  k_sq<<<BB * NN / 256, 256, 0, stream>>>(x, hg);
  k_knnA<<<BB * 32 * NSPLIT, 256, 0, stream>>>(x, hg, candv);
  k_thresh<<<BB * NN / 256, 256, 0, stream>>>(candv, thr);
  hipMemsetAsync(gcnt, 0, NQ * 4, stream);
  k_collect<<<BB * 32 * NSPLIT, 256, 0, stream>>>(x, hg, thr, cnt8, gcnt, segs, pool);
  k_final<<<BB * NN / 256, 256, 0, stream>>>(segs, cnt8, pool, gcnt, idxk);
  k_uv<<<BB * 64, 256, 0, stream>>>(x, W, ut, vt);
  hipMemsetAsync(gsum, 0, 512, stream);
  k_stats<<<BB * 64, 256, 0, stream>>>(ut, vt, idxk, gsum, gsqs);
  k_bn<<<1, 64, 0, stream>>>(gsum, gsqs, gamma, beta, AB);
  k_out<<<BB * 64, 256, 0, stream>>>(ut, vt, idxk, AB, outp);
}

// Round 8
// 1203.954 us; speedup vs baseline: 17.8883x; 1.2955x over previous
//
#include <hip/hip_runtime.h>
#include <cstdint>
#include <cstddef>

#define BB 8
#define CC 64
#define NN 4096
#define OO 64
#define KK 20
#define KC 58
#define HC 29             // channels per lane (lane-pair split: even 0-28, odd 29-57)
#define KSKIP 6
#define NSPLIT 8
#define JS 512            // j's per split
#define CAPS 10           // per-(query,split) segment slots: 5 even-lane + 5 odd-lane
#define HCAP 5
#define GCAP 20           // per-query overflow pool slots
#define BN_EPS 1e-5f
#define NEG 0.2f
#define NEGINF (-3.402823466e38f)
#define M_TOTAL 655360.0f   // B*N*K
// odd-half LDS tile offset: 29*64 words == 0 mod 32 banks -> collides with the
// even half's bank group (r7: SQ_LDS_BANK_CONFLICT 1.2e8 = 37% of cycles).
// Shift odd half by +4 words so even lanes use banks g..g+3, odd g+4..g+7.
#define HPAD 4

#define MED3F(a, b, c) __builtin_amdgcn_fmed3f((a), (b), (c))

// VGPR-CAP MODEL (measured r0-r5): hipcc cap = 256/waves_per_EU_bound.
//   no bounds -> flat-wg 1024 default -> cap 64; (256)->256; (256,2)->128;
//   (256,3)->84; (256,4)->64. Lane-pair split (r7) dropped live set to ~48
//   VGPR -> no spill at (256,2), occupancy 11->50%.
// SPILL TRIPWIRE: scan-kernel FETCH_SIZE must stay in MBs. GBs = spill.

// ---------------- K0: h = 0.5*||x_{6:}||^2 per point ----------------
__global__ void k_sq(const float* __restrict__ x, float* __restrict__ h) {
  int n = blockIdx.x * 256 + threadIdx.x;  // 0 .. BB*NN-1
  int b = n >> 12;
  int nn = n & (NN - 1);
  const float* xp = x + ((size_t)b * CC + KSKIP) * NN + nn;
  float s = 0.f;
#pragma unroll
  for (int c = 0; c < KC; ++c) {
    float v = xp[(size_t)c * NN];
    s = fmaf(v, v, s);
  }
  h[n] = 0.5f * s;
}

// med3 ripple: insert e into descending top-20 value list.
#define RIP(tv, e)                                   \
  do {                                               \
    float _e = (e);                                  \
    tv[19] = MED3F(tv[18], tv[19], _e);              \
    tv[18] = MED3F(tv[17], tv[18], _e);              \
    tv[17] = MED3F(tv[16], tv[17], _e);              \
    tv[16] = MED3F(tv[15], tv[16], _e);              \
    tv[15] = MED3F(tv[14], tv[15], _e);              \
    tv[14] = MED3F(tv[13], tv[14], _e);              \
    tv[13] = MED3F(tv[12], tv[13], _e);              \
    tv[12] = MED3F(tv[11], tv[12], _e);              \
    tv[11] = MED3F(tv[10], tv[11], _e);              \
    tv[10] = MED3F(tv[9],  tv[10], _e);              \
    tv[9]  = MED3F(tv[8],  tv[9],  _e);              \
    tv[8]  = MED3F(tv[7],  tv[8],  _e);              \
    tv[7]  = MED3F(tv[6],  tv[7],  _e);              \
    tv[6]  = MED3F(tv[5],  tv[6],  _e);              \
    tv[5]  = MED3F(tv[4],  tv[5],  _e);              \
    tv[4]  = MED3F(tv[3],  tv[4],  _e);              \
    tv[3]  = MED3F(tv[2],  tv[3],  _e);              \
    tv[2]  = MED3F(tv[1],  tv[2],  _e);              \
    tv[1]  = MED3F(tv[0],  tv[1],  _e);              \
    tv[0]  = fmaxf(tv[0], _e);                       \
  } while (0)

// Pair-split distance batch: 16 j's per pair-iteration. Each lane accumulates
// its 29-channel partial for all 16 j's; shfl_xor(1)+add completes the dot
// (commutative add -> bit-identical in both lanes). Even lane then owns
// d for j+0..7, odd lane j+8..15 (via half8 select).
// MUST be textually identical in pass A and B (bit-exact fp32 re-scan).
#define DIST16(jq)                                                    \
  float a0 = 0.f, a1 = 0.f, a2 = 0.f, a3 = 0.f;                       \
  float a4 = 0.f, a5 = 0.f, a6 = 0.f, a7 = 0.f;                       \
  float a8 = 0.f, a9 = 0.f, a10 = 0.f, a11 = 0.f;                     \
  float a12 = 0.f, a13 = 0.f, a14 = 0.f, a15 = 0.f;                   \
  _Pragma("unroll")                                                   \
  for (int cc = 0; cc < HC; ++cc) {                                   \
    float4 x0 = *(const float4*)(ltp + cc * 64 + (jq) * 16);          \
    float4 x1 = *(const float4*)(ltp + cc * 64 + (jq) * 16 + 4);      \
    float4 x2 = *(const float4*)(ltp + cc * 64 + (jq) * 16 + 8);      \
    float4 x3 = *(const float4*)(ltp + cc * 64 + (jq) * 16 + 12);     \
    float xic = xi[cc];                                               \
    a0  = fmaf(xic, x0.x, a0);  a1  = fmaf(xic, x0.y, a1);            \
    a2  = fmaf(xic, x0.z, a2);  a3  = fmaf(xic, x0.w, a3);            \
    a4  = fmaf(xic, x1.x, a4);  a5  = fmaf(xic, x1.y, a5);            \
    a6  = fmaf(xic, x1.z, a6);  a7  = fmaf(xic, x1.w, a7);            \
    a8  = fmaf(xic, x2.x, a8);  a9  = fmaf(xic, x2.y, a9);            \
    a10 = fmaf(xic, x2.z, a10); a11 = fmaf(xic, x2.w, a11);           \
    a12 = fmaf(xic, x3.x, a12); a13 = fmaf(xic, x3.y, a13);           \
    a14 = fmaf(xic, x3.z, a14); a15 = fmaf(xic, x3.w, a15);           \
  }                                                                   \
  a0  += __shfl_xor(a0, 1);  a1  += __shfl_xor(a1, 1);                \
  a2  += __shfl_xor(a2, 1);  a3  += __shfl_xor(a3, 1);                \
  a4  += __shfl_xor(a4, 1);  a5  += __shfl_xor(a5, 1);                \
  a6  += __shfl_xor(a6, 1);  a7  += __shfl_xor(a7, 1);                \
  a8  += __shfl_xor(a8, 1);  a9  += __shfl_xor(a9, 1);                \
  a10 += __shfl_xor(a10, 1); a11 += __shfl_xor(a11, 1);               \
  a12 += __shfl_xor(a12, 1); a13 += __shfl_xor(a13, 1);               \
  a14 += __shfl_xor(a14, 1); a15 += __shfl_xor(a15, 1);               \
  float4 hA = *(const float4*)(lh + (jq) * 16 + half8);               \
  float4 hB = *(const float4*)(lh + (jq) * 16 + half8 + 4);           \
  float d0 = (half8 ? a8  : a0)  - hA.x;                              \
  float d1 = (half8 ? a9  : a1)  - hA.y;                              \
  float d2 = (half8 ? a10 : a2)  - hA.z;                              \
  float d3 = (half8 ? a11 : a3)  - hA.w;                              \
  float d4 = (half8 ? a12 : a4)  - hB.x;                              \
  float d5 = (half8 ? a13 : a5)  - hB.y;                              \
  float d6 = (half8 ? a14 : a6)  - hB.z;                              \
  float d7 = (half8 ? a15 : a7)  - hB.w;

// rows >= HC (odd half) shifted by HPAD words to land on a disjoint bank group.
#define STAGE_TILE(jbase)                                             \
  __syncthreads();                                                    \
  for (int f = t; f < KC * 16; f += 256) {                            \
    int c = f >> 4, q = f & 15;                                       \
    float4 v = *(const float4*)(xb + c * NN + (jbase) + q * 4);       \
    *(float4*)(ltile + c * 64 + q * 4 + (c >= HC ? HPAD : 0)) = v;    \
  }                                                                   \
  if (t < 64) lh[t] = hg[b * NN + (jbase) + t];                       \
  __syncthreads();

// ---------------- Pass A: per-(query, split) top-20 VALUES only ----------------
// grid: BB(8) x itile(32) x split(8) = 2048 blocks of 256 threads.
// 128 queries per block (lane pairs), pair handles 16 j's per DIST16.
__global__ __launch_bounds__(256, 2) void k_knnA(const float* __restrict__ x,
                                                 const float* __restrict__ hg,
                                                 float* __restrict__ candv) {
  __shared__ float ltile[KC * 64 + HPAD];
  __shared__ float lh[64];
  int t = threadIdx.x;
  int l = t & 63;
  int w = t >> 6;
  int half = l & 1;
  int half8 = half * 8;
  int bidx = blockIdx.x;
  int b = bidx >> 8;
  int itile = (bidx >> 3) & 31;
  int split = bidx & 7;
  int i = itile * 128 + w * 32 + (l >> 1);
  const float* xb = x + ((size_t)b * CC + KSKIP) * NN;
  const float* ltp = ltile + half * (HC * 64 + HPAD);

  float xi[HC];
#pragma unroll
  for (int cc = 0; cc < HC; ++cc) xi[cc] = xb[(half * HC + cc) * NN + i];

  float tv[KK];
#pragma unroll
  for (int s = 0; s < KK; ++s) tv[s] = NEGINF;

#pragma unroll 1
  for (int jt = 0; jt < JS / 64; ++jt) {
    int jbase = split * JS + jt * 64;
    STAGE_TILE(jbase)
#pragma unroll 1
    for (int jq = 0; jq < 4; ++jq) {
      DIST16(jq)
      RIP(tv, d0); RIP(tv, d1); RIP(tv, d2); RIP(tv, d3);
      RIP(tv, d4); RIP(tv, d5); RIP(tv, d6); RIP(tv, d7);
    }
  }

  // merge partner lane's list (snapshot first: partner's tv mutates during merge)
  float ov[KK];
#pragma unroll
  for (int s = 0; s < KK; ++s) ov[s] = __shfl_xor(tv[s], 1);
#pragma unroll
  for (int s = 0; s < KK; ++s) { RIP(tv, ov[s]); }

  if (!half) {
    float* cv = candv + (((size_t)(b * NN + i)) * NSPLIT + split) * KK;
#pragma unroll
    for (int s = 0; s < KK; ++s) cv[s] = tv[s];
  }
}

// ---------------- merge split value-lists -> exact 20th-largest threshold ----------------
__global__ void k_thresh(const float* __restrict__ candv, float* __restrict__ thr) {
  int qi = blockIdx.x * 256 + threadIdx.x;  // 0..BB*NN-1
  const float* cv = candv + (size_t)qi * NSPLIT * KK;
  float tv[KK];
#pragma unroll
  for (int s = 0; s < KK; ++s) tv[s] = NEGINF;
#pragma unroll 1
  for (int s = 0; s < NSPLIT * KK; ++s) {
    RIP(tv, cv[s]);
  }
  thr[qi] = tv[19];
}

// ---------------- Pass B: re-scan, collect j with d >= thr ----------------
// Even lane emits j+0..7 into seg slots [0,5); odd lane j+8..15 into [5,10).
// Packed count: cnt8 = p_even | p_odd<<16. Overflow (>5 hits per lane-half,
// P~9e-4) -> per-query atomic pool.
__global__ __launch_bounds__(256, 2) void k_collect(const float* __restrict__ x,
                                                    const float* __restrict__ hg,
                                                    const float* __restrict__ thr,
                                                    int* __restrict__ cnt8,
                                                    int* __restrict__ gcnt,
                                                    float* __restrict__ segs,
                                                    float* __restrict__ pool) {
  __shared__ float ltile[KC * 64 + HPAD];
  __shared__ float lh[64];
  int t = threadIdx.x;
  int l = t & 63;
  int w = t >> 6;
  int half = l & 1;
  int half8 = half * 8;
  int bidx = blockIdx.x;
  int b = bidx >> 8;
  int itile = (bidx >> 3) & 31;
  int split = bidx & 7;
  int i = itile * 128 + w * 32 + (l >> 1);
  int qi = b * NN + i;
  const float* xb = x + ((size_t)b * CC + KSKIP) * NN;
  const float* ltp = ltile + half * (HC * 64 + HPAD);

  float xi[HC];
#pragma unroll
  for (int cc = 0; cc < HC; ++cc) xi[cc] = xb[(half * HC + cc) * NN + i];
  float ti_ = thr[qi];
  float* seg = segs + ((((size_t)qi * NSPLIT) + split) * CAPS + half * HCAP) * 2;
  int p = 0;

#define EMIT(dv, jj)                                                  \
  if ((dv) >= ti_) {                                                  \
    float2 pr;                                                        \
    pr.x = (dv);                                                      \
    pr.y = __int_as_float(jj);                                        \
    if (p < HCAP) {                                                   \
      *(float2*)(seg + p * 2) = pr;                                   \
    } else {                                                          \
      int g = atomicAdd(&gcnt[qi], 1);                                \
      if (g < GCAP) *(float2*)(pool + ((size_t)qi * GCAP + g) * 2) = pr; \
    }                                                                 \
    ++p;                                                              \
  }

#pragma unroll 1
  for (int jt = 0; jt < JS / 64; ++jt) {
    int jbase = split * JS + jt * 64;
    STAGE_TILE(jbase)
#pragma unroll 1
    for (int jq = 0; jq < 4; ++jq) {
      DIST16(jq)
      int j0 = jbase + jq * 16 + half8;
      EMIT(d0, j0 + 0) EMIT(d1, j0 + 1) EMIT(d2, j0 + 2) EMIT(d3, j0 + 3)
      EMIT(d4, j0 + 4) EMIT(d5, j0 + 5) EMIT(d6, j0 + 6) EMIT(d7, j0 + 7)
    }
  }
#undef EMIT
  int po = __shfl_xor(p, 1);
  if (!half) cnt8[qi * NSPLIT + split] = p | (po << 16);
}

// ---------------- final: lexicographic top-20 over segments + pool ----------------
// tie at equal d -> smaller j wins (matches jax.lax.top_k).
__global__ void k_final(const float* __restrict__ segs, const int* __restrict__ cnt8,
                        const float* __restrict__ pool, const int* __restrict__ gcnt,
                        int* __restrict__ idxk) {
  int qi = blockIdx.x * 256 + threadIdx.x;
  float tv[KK];
  int ti[KK];
#pragma unroll
  for (int s = 0; s < KK; ++s) { tv[s] = NEGINF; ti[s] = 0; }

#define INSERT(pr)                                                            \
  {                                                                           \
    float d = pr.x;                                                           \
    int j = __float_as_int(pr.y);                                             \
    bool acc = (d > tv[KK - 1]) || (d == tv[KK - 1] && j < ti[KK - 1]);       \
    if (acc) {                                                                \
      tv[KK - 1] = d;                                                         \
      ti[KK - 1] = j;                                                         \
      _Pragma("unroll")                                                       \
      for (int s = KK - 1; s > 0; --s) {                                      \
        bool gt_ = (tv[s] > tv[s - 1]) || (tv[s] == tv[s - 1] && ti[s] < ti[s - 1]); \
        float vh_ = gt_ ? tv[s] : tv[s - 1];                                  \
        float vl_ = gt_ ? tv[s - 1] : tv[s];                                  \
        int ih_ = gt_ ? ti[s] : ti[s - 1];                                    \
        int il_ = gt_ ? ti[s - 1] : ti[s];                                    \
        tv[s - 1] = vh_; tv[s] = vl_;                                         \
        ti[s - 1] = ih_; ti[s] = il_;                                         \
      }                                                                       \
    }                                                                         \
  }

#pragma unroll 1
  for (int sp = 0; sp < NSPLIT; ++sp) {
    int c = cnt8[qi * NSPLIT + sp];
    int ce = c & 0xffff;
    int co = c >> 16;
    if (ce > HCAP) ce = HCAP;
    if (co > HCAP) co = HCAP;
    const float* cp = segs + (((size_t)qi * NSPLIT) + sp) * CAPS * 2;
#pragma unroll 1
    for (int e = 0; e < ce; ++e) {
      float2 pr = *(const float2*)(cp + e * 2);
      INSERT(pr)
    }
#pragma unroll 1
    for (int e = 0; e < co; ++e) {
      float2 pr = *(const float2*)(cp + (HCAP + e) * 2);
      INSERT(pr)
    }
  }
  int g = gcnt[qi];
  if (g > GCAP) g = GCAP;
  const float* pp = pool + (size_t)qi * GCAP * 2;
#pragma unroll 1
  for (int e = 0; e < g; ++e) {
    float2 pr = *(const float2*)(pp + e * 2);
    INSERT(pr)
  }
#undef INSERT

  int* op = idxk + (size_t)qi * KK;
#pragma unroll
  for (int s = 0; s < KK; ++s) op[s] = ti[s];
}

// ---------------- K2: u = W1^T x, v = (W2-W1)^T x, stored (b, n, o) ----------------
__global__ void k_uv(const float* __restrict__ x, const float* __restrict__ W,
                     float* __restrict__ ut, float* __restrict__ vt) {
  __shared__ float w1[64 * 65];
  __shared__ float wd[64 * 65];
  __shared__ float xs[64 * 72];
  int t = threadIdx.x;
  int b = blockIdx.x >> 6;
  int nbase = (blockIdx.x & 63) * 64;

  for (int f = t; f < 4096; f += 256) {
    int o = f >> 6, c = f & 63;
    float a = W[o * 128 + c];
    float b2 = W[o * 128 + 64 + c];
    w1[c * 65 + o] = a;
    wd[c * 65 + o] = b2 - a;
  }
  for (int f = t; f < 1024; f += 256) {
    int c = f >> 4, q = f & 15;
    float4 v = *(const float4*)(x + ((size_t)b * CC + c) * NN + nbase + q * 4);
    *(float4*)(xs + c * 72 + q * 4) = v;
  }
  __syncthreads();

  int o = t & 63, w = t >> 6;
  float4 au[4], av[4];
#pragma unroll
  for (int nq = 0; nq < 4; ++nq) {
    au[nq] = make_float4(0.f, 0.f, 0.f, 0.f);
    av[nq] = make_float4(0.f, 0.f, 0.f, 0.f);
  }
#pragma unroll 4
  for (int c = 0; c < 64; ++c) {
    float w1v = w1[c * 65 + o];
    float wdv = wd[c * 65 + o];
#pragma unroll
    for (int nq = 0; nq < 4; ++nq) {
      float4 xv = *(const float4*)(xs + c * 72 + w * 16 + nq * 4);
      au[nq].x = fmaf(w1v, xv.x, au[nq].x);
      au[nq].y = fmaf(w1v, xv.y, au[nq].y);
      au[nq].z = fmaf(w1v, xv.z, au[nq].z);
      au[nq].w = fmaf(w1v, xv.w, au[nq].w);
      av[nq].x = fmaf(wdv, xv.x, av[nq].x);
      av[nq].y = fmaf(wdv, xv.y, av[nq].y);
      av[nq].z = fmaf(wdv, xv.z, av[nq].z);
      av[nq].w = fmaf(wdv, xv.w, av[nq].w);
    }
  }
#pragma unroll
  for (int nq = 0; nq < 4; ++nq) {
    int n = nbase + w * 16 + nq * 4;
    size_t base = ((size_t)b * NN + n) * OO + o;
    ut[base + 0 * OO] = au[nq].x;
    ut[base + 1 * OO] = au[nq].y;
    ut[base + 2 * OO] = au[nq].z;
    ut[base + 3 * OO] = au[nq].w;
    vt[base + 0 * OO] = av[nq].x;
    vt[base + 1 * OO] = av[nq].y;
    vt[base + 2 * OO] = av[nq].z;
    vt[base + 3 * OO] = av[nq].w;
  }
}

// ---------------- K3: BN sum / sumsq over all (b,n,k) per channel ----------------
__global__ void k_stats(const float* __restrict__ ut, const float* __restrict__ vt,
                        const int* __restrict__ idxk, float* __restrict__ gsum,
                        float* __restrict__ gsqs) {
  __shared__ float red[2][4][64];
  int t = threadIdx.x;
  int o = t & 63, w = t >> 6;
  int b = blockIdx.x >> 6;
  int nbase = (blockIdx.x & 63) * 64 + w * 16;
  const float* up = ut + (size_t)b * NN * OO;
  float s = 0.f, s2 = 0.f;
#pragma unroll 1
  for (int nn2 = 0; nn2 < 16; ++nn2) {
    int n = nbase + nn2;
    float vv = vt[((size_t)b * NN + n) * OO + o];
    const int* ip = idxk + ((size_t)b * NN + n) * KK;
    int4 q0 = *(const int4*)(ip + 0);
    int4 q1 = *(const int4*)(ip + 4);
    int4 q2 = *(const int4*)(ip + 8);
    int4 q3 = *(const int4*)(ip + 12);
    int4 q4 = *(const int4*)(ip + 16);
#define ACC(j)                                  \
    {                                           \
      float u = up[(size_t)(j) * OO + o];       \
      float yy = u + vv;                        \
      s += yy;                                  \
      s2 = fmaf(yy, yy, s2);                    \
    }
    ACC(q0.x) ACC(q0.y) ACC(q0.z) ACC(q0.w)
    ACC(q1.x) ACC(q1.y) ACC(q1.z) ACC(q1.w)
    ACC(q2.x) ACC(q2.y) ACC(q2.z) ACC(q2.w)
    ACC(q3.x) ACC(q3.y) ACC(q3.z) ACC(q3.w)
    ACC(q4.x) ACC(q4.y) ACC(q4.z) ACC(q4.w)
#undef ACC
  }
  red[0][w][o] = s;
  red[1][w][o] = s2;
  __syncthreads();
  if (w == 0) {
    float ts = red[0][0][o] + red[0][1][o] + red[0][2][o] + red[0][3][o];
    float t2 = red[1][0][o] + red[1][1][o] + red[1][2][o] + red[1][3][o];
    atomicAdd(&gsum[o], ts);
    atomicAdd(&gsqs[o], t2);
  }
}

// ---------------- K4: finalize BN affine ----------------
__global__ void k_bn(const float* __restrict__ gsum, const float* __restrict__ gsqs,
                     const float* __restrict__ gamma, const float* __restrict__ beta,
                     float* __restrict__ AB) {
  int o = threadIdx.x;
  float mean = gsum[o] * (1.f / M_TOTAL);
  float var = gsqs[o] * (1.f / M_TOTAL) - mean * mean;
  float A = gamma[o] / sqrtf(var + BN_EPS);
  AB[o] = A;
  AB[64 + o] = beta[o] - mean * A;
}

// ---------------- K5: normalized + leakyrelu + max over k, transposed store ----------------
__global__ void k_out(const float* __restrict__ ut, const float* __restrict__ vt,
                      const int* __restrict__ idxk, const float* __restrict__ AB,
                      float* __restrict__ outp) {
  __shared__ float lt[64 * 65];
  int t = threadIdx.x;
  int o = t & 63, w = t >> 6;
  int b = blockIdx.x >> 6;
  int nb = (blockIdx.x & 63) * 64;
  float A = AB[o], Bs = AB[64 + o];
  const float* up = ut + (size_t)b * NN * OO;
#pragma unroll 1
  for (int nn2 = 0; nn2 < 16; ++nn2) {
    int nl = w * 16 + nn2;
    int n = nb + nl;
    float vv = vt[((size_t)b * NN + n) * OO + o];
    const int* ip = idxk + ((size_t)b * NN + n) * KK;
    int4 q0 = *(const int4*)(ip + 0);
    int4 q1 = *(const int4*)(ip + 4);
    int4 q2 = *(const int4*)(ip + 8);
    int4 q3 = *(const int4*)(ip + 12);
    int4 q4 = *(const int4*)(ip + 16);
    float m = NEGINF;
#define STEP(j)                                   \
    {                                             \
      float u = up[(size_t)(j) * OO + o];         \
      float y = fmaf(A, u + vv, Bs);              \
      y = fmaxf(y, NEG * y);                      \
      m = fmaxf(m, y);                            \
    }
    STEP(q0.x) STEP(q0.y) STEP(q0.z) STEP(q0.w)
    STEP(q1.x) STEP(q1.y) STEP(q1.z) STEP(q1.w)
    STEP(q2.x) STEP(q2.y) STEP(q2.z) STEP(q2.w)
    STEP(q3.x) STEP(q3.y) STEP(q3.z) STEP(q3.w)
    STEP(q4.x) STEP(q4.y) STEP(q4.z) STEP(q4.w)
#undef STEP
    lt[nl * 65 + o] = m;
  }
  __syncthreads();
  int oo = t >> 2, part = t & 3;
#pragma unroll
  for (int mq = 0; mq < 4; ++mq) {
    int n0 = part * 16 + mq * 4;
    float4 vvv;
    vvv.x = lt[(n0 + 0) * 65 + oo];
    vvv.y = lt[(n0 + 1) * 65 + oo];
    vvv.z = lt[(n0 + 2) * 65 + oo];
    vvv.w = lt[(n0 + 3) * 65 + oo];
    *(float4*)(outp + ((size_t)b * OO + oo) * NN + nb + n0) = vvv;
  }
}

extern "C" void kernel_launch(void* const* d_in, const int* in_sizes, int n_in,
                              void* d_out, int out_size, void* d_ws, size_t ws_size,
                              hipStream_t stream) {
  const float* x = (const float*)d_in[0];
  const float* W = (const float*)d_in[1];
  const float* gamma = (const float*)d_in[2];
  const float* beta = (const float*)d_in[3];
  float* outp = (float*)d_out;
  char* ws = (char*)d_ws;

  const size_t NQ = (size_t)BB * NN;  // 32768 queries
  size_t off = 0;
  float* hg = (float*)(ws + off); off += NQ * 4;                      // 128 KB
  float* thr = (float*)(ws + off); off += NQ * 4;                     // 128 KB
  int* cnt8 = (int*)(ws + off); off += NQ * NSPLIT * 4;               // 1 MB
  int* gcnt = (int*)(ws + off); off += NQ * 4;                        // 128 KB
  int* idxk = (int*)(ws + off); off += NQ * KK * 4;                   // 2.6 MB
  float* gsum = (float*)(ws + off); off += 256;
  float* gsqs = (float*)(ws + off); off += 256;
  float* AB = (float*)(ws + off); off += 512;
  // overlapped region:
  //  phase 1 (knnA/thresh): candv                 = 20 MB
  //  phase 2 (collect/final): segs (20MB) + pool  = 25.2 MB
  //  phase 3 (uv/stats/out): ut (8MB) + vt (8MB)  = 16 MB
  char* region = ws + off;
  float* candv = (float*)region;                                      // 20 MB
  float* segs = (float*)region;                                       // 20 MB
  float* pool = (float*)(region + NQ * NSPLIT * CAPS * 2 * 4);        // 5.2 MB
  float* ut = (float*)region;                                         // 8 MB
  float* vt = (float*)(region + NQ * OO * 4);                         // 8 MB

  k_sq<<<BB * NN / 256, 256, 0, stream>>>(x, hg);
  k_knnA<<<BB * 32 * NSPLIT, 256, 0, stream>>>(x, hg, candv);
  k_thresh<<<BB * NN / 256, 256, 0, stream>>>(candv, thr);
  hipMemsetAsync(gcnt, 0, NQ * 4, stream);
  k_collect<<<BB * 32 * NSPLIT, 256, 0, stream>>>(x, hg, thr, cnt8, gcnt, segs, pool);
  k_final<<<BB * NN / 256, 256, 0, stream>>>(segs, cnt8, pool, gcnt, idxk);
  k_uv<<<BB * 64, 256, 0, stream>>>(x, W, ut, vt);
  hipMemsetAsync(gsum, 0, 512, stream);
  k_stats<<<BB * 64, 256, 0, stream>>>(ut, vt, idxk, gsum, gsqs);
  k_bn<<<1, 64, 0, stream>>>(gsum, gsqs, gamma, beta, AB);
  k_out<<<BB * 64, 256, 0, stream>>>(ut, vt, idxk, AB, outp);
}

// Round 9
// 772.884 us; speedup vs baseline: 27.8653x; 1.5577x over previous
//
#include <hip/hip_runtime.h>
#include <cstdint>
#include <cstddef>

#define BB 8
#define CC 64
#define NN 4096
#define OO 64
#define KK 20
#define KC 58
#define HC 29             // channels per lane (lane-pair split: even 0-28, odd 29-57)
#define KSKIP 6
#define NSPLIT 8
#define JS 512            // j's per split
#define CAPS 10           // per-(query,split) segment slots: 5 even-lane + 5 odd-lane
#define HCAP 5
#define GCAP 20           // per-query overflow pool slots
#define BN_EPS 1e-5f
#define NEG 0.2f
#define NEGINF (-3.402823466e38f)
#define M_TOTAL 655360.0f   // B*N*K
// odd-half LDS tile offset: 29*64 words == 0 mod 32 banks -> collides with the
// even half's bank group (r7: SQ_LDS_BANK_CONFLICT 1.2e8 = 37% of cycles).
// Shift odd half by +4 words so even lanes use banks g..g+3, odd g+4..g+7.
// (r8: conflicts -> 0, total 1559 -> 1204us)
#define HPAD 4

#define MED3F(a, b, c) __builtin_amdgcn_fmed3f((a), (b), (c))

// VGPR-CAP MODEL (measured r0-r5): hipcc cap = 256/waves_per_EU_bound.
//   no bounds -> flat-wg 1024 default -> cap 64; (256)->256; (256,2)->128;
//   (256,3)->84; (256,4)->64. Lane-pair split (r7) dropped live set to ~48
//   VGPR -> no spill at (256,2), occupancy 11->50%.
// SPILL TRIPWIRE: scan-kernel FETCH_SIZE must stay in MBs. GBs = spill.

// ---------------- K0: h = 0.5*||x_{6:}||^2 per point ----------------
__global__ void k_sq(const float* __restrict__ x, float* __restrict__ h) {
  int n = blockIdx.x * 256 + threadIdx.x;  // 0 .. BB*NN-1
  int b = n >> 12;
  int nn = n & (NN - 1);
  const float* xp = x + ((size_t)b * CC + KSKIP) * NN + nn;
  float s = 0.f;
#pragma unroll
  for (int c = 0; c < KC; ++c) {
    float v = xp[(size_t)c * NN];
    s = fmaf(v, v, s);
  }
  h[n] = 0.5f * s;
}

// med3 ripple: insert e into descending top-20 value list.
#define RIP(tv, e)                                   \
  do {                                               \
    float _e = (e);                                  \
    tv[19] = MED3F(tv[18], tv[19], _e);              \
    tv[18] = MED3F(tv[17], tv[18], _e);              \
    tv[17] = MED3F(tv[16], tv[17], _e);              \
    tv[16] = MED3F(tv[15], tv[16], _e);              \
    tv[15] = MED3F(tv[14], tv[15], _e);              \
    tv[14] = MED3F(tv[13], tv[14], _e);              \
    tv[13] = MED3F(tv[12], tv[13], _e);              \
    tv[12] = MED3F(tv[11], tv[12], _e);              \
    tv[11] = MED3F(tv[10], tv[11], _e);              \
    tv[10] = MED3F(tv[9],  tv[10], _e);              \
    tv[9]  = MED3F(tv[8],  tv[9],  _e);              \
    tv[8]  = MED3F(tv[7],  tv[8],  _e);              \
    tv[7]  = MED3F(tv[6],  tv[7],  _e);              \
    tv[6]  = MED3F(tv[5],  tv[6],  _e);              \
    tv[5]  = MED3F(tv[4],  tv[5],  _e);              \
    tv[4]  = MED3F(tv[3],  tv[4],  _e);              \
    tv[3]  = MED3F(tv[2],  tv[3],  _e);              \
    tv[2]  = MED3F(tv[1],  tv[2],  _e);              \
    tv[1]  = MED3F(tv[0],  tv[1],  _e);              \
    tv[0]  = fmaxf(tv[0], _e);                       \
  } while (0)

// Pair-split distance batch: 16 j's per pair-iteration. Each lane accumulates
// its 29-channel partial for all 16 j's; shfl_xor(1)+add completes the dot
// (commutative add -> bit-identical in both lanes). Even lane then owns
// d for j+0..7, odd lane j+8..15 (via half8 select).
// MUST be textually identical in pass A and B (bit-exact fp32 re-scan).
#define DIST16(jq)                                                    \
  float a0 = 0.f, a1 = 0.f, a2 = 0.f, a3 = 0.f;                       \
  float a4 = 0.f, a5 = 0.f, a6 = 0.f, a7 = 0.f;                       \
  float a8 = 0.f, a9 = 0.f, a10 = 0.f, a11 = 0.f;                     \
  float a12 = 0.f, a13 = 0.f, a14 = 0.f, a15 = 0.f;                   \
  _Pragma("unroll")                                                   \
  for (int cc = 0; cc < HC; ++cc) {                                   \
    float4 x0 = *(const float4*)(ltp + cc * 64 + (jq) * 16);          \
    float4 x1 = *(const float4*)(ltp + cc * 64 + (jq) * 16 + 4);      \
    float4 x2 = *(const float4*)(ltp + cc * 64 + (jq) * 16 + 8);      \
    float4 x3 = *(const float4*)(ltp + cc * 64 + (jq) * 16 + 12);     \
    float xic = xi[cc];                                               \
    a0  = fmaf(xic, x0.x, a0);  a1  = fmaf(xic, x0.y, a1);            \
    a2  = fmaf(xic, x0.z, a2);  a3  = fmaf(xic, x0.w, a3);            \
    a4  = fmaf(xic, x1.x, a4);  a5  = fmaf(xic, x1.y, a5);            \
    a6  = fmaf(xic, x1.z, a6);  a7  = fmaf(xic, x1.w, a7);            \
    a8  = fmaf(xic, x2.x, a8);  a9  = fmaf(xic, x2.y, a9);            \
    a10 = fmaf(xic, x2.z, a10); a11 = fmaf(xic, x2.w, a11);           \
    a12 = fmaf(xic, x3.x, a12); a13 = fmaf(xic, x3.y, a13);           \
    a14 = fmaf(xic, x3.z, a14); a15 = fmaf(xic, x3.w, a15);           \
  }                                                                   \
  a0  += __shfl_xor(a0, 1);  a1  += __shfl_xor(a1, 1);                \
  a2  += __shfl_xor(a2, 1);  a3  += __shfl_xor(a3, 1);                \
  a4  += __shfl_xor(a4, 1);  a5  += __shfl_xor(a5, 1);                \
  a6  += __shfl_xor(a6, 1);  a7  += __shfl_xor(a7, 1);                \
  a8  += __shfl_xor(a8, 1);  a9  += __shfl_xor(a9, 1);                \
  a10 += __shfl_xor(a10, 1); a11 += __shfl_xor(a11, 1);               \
  a12 += __shfl_xor(a12, 1); a13 += __shfl_xor(a13, 1);               \
  a14 += __shfl_xor(a14, 1); a15 += __shfl_xor(a15, 1);               \
  float4 hA = *(const float4*)(lh + (jq) * 16 + half8);               \
  float4 hB = *(const float4*)(lh + (jq) * 16 + half8 + 4);           \
  float d0 = (half8 ? a8  : a0)  - hA.x;                              \
  float d1 = (half8 ? a9  : a1)  - hA.y;                              \
  float d2 = (half8 ? a10 : a2)  - hA.z;                              \
  float d3 = (half8 ? a11 : a3)  - hA.w;                              \
  float d4 = (half8 ? a12 : a4)  - hB.x;                              \
  float d5 = (half8 ? a13 : a5)  - hB.y;                              \
  float d6 = (half8 ? a14 : a6)  - hB.z;                              \
  float d7 = (half8 ? a15 : a7)  - hB.w;

// rows >= HC (odd half) shifted by HPAD words to land on a disjoint bank group.
#define STAGE_TILE(jbase)                                             \
  __syncthreads();                                                    \
  for (int f = t; f < KC * 16; f += 256) {                            \
    int c = f >> 4, q = f & 15;                                       \
    float4 v = *(const float4*)(xb + c * NN + (jbase) + q * 4);       \
    *(float4*)(ltile + c * 64 + q * 4 + (c >= HC ? HPAD : 0)) = v;    \
  }                                                                   \
  if (t < 64) lh[t] = hg[b * NN + (jbase) + t];                       \
  __syncthreads();

// ---------------- Pass A: per-(query, split) top-20 VALUES only ----------------
// grid: BB(8) x itile(32) x split(8) = 2048 blocks of 256 threads.
// 128 queries per block (lane pairs), pair handles 16 j's per DIST16.
__global__ __launch_bounds__(256, 2) void k_knnA(const float* __restrict__ x,
                                                 const float* __restrict__ hg,
                                                 float* __restrict__ candv) {
  __shared__ float ltile[KC * 64 + HPAD];
  __shared__ float lh[64];
  int t = threadIdx.x;
  int l = t & 63;
  int w = t >> 6;
  int half = l & 1;
  int half8 = half * 8;
  int bidx = blockIdx.x;
  int b = bidx >> 8;
  int itile = (bidx >> 3) & 31;
  int split = bidx & 7;
  int i = itile * 128 + w * 32 + (l >> 1);
  const float* xb = x + ((size_t)b * CC + KSKIP) * NN;
  const float* ltp = ltile + half * (HC * 64 + HPAD);

  float xi[HC];
#pragma unroll
  for (int cc = 0; cc < HC; ++cc) xi[cc] = xb[(half * HC + cc) * NN + i];

  float tv[KK];
#pragma unroll
  for (int s = 0; s < KK; ++s) tv[s] = NEGINF;

#pragma unroll 1
  for (int jt = 0; jt < JS / 64; ++jt) {
    int jbase = split * JS + jt * 64;
    STAGE_TILE(jbase)
#pragma unroll 1
    for (int jq = 0; jq < 4; ++jq) {
      DIST16(jq)
      RIP(tv, d0); RIP(tv, d1); RIP(tv, d2); RIP(tv, d3);
      RIP(tv, d4); RIP(tv, d5); RIP(tv, d6); RIP(tv, d7);
    }
  }

  // merge partner lane's list (snapshot first: partner's tv mutates during merge)
  float ov[KK];
#pragma unroll
  for (int s = 0; s < KK; ++s) ov[s] = __shfl_xor(tv[s], 1);
#pragma unroll
  for (int s = 0; s < KK; ++s) { RIP(tv, ov[s]); }

  if (!half) {
    float* cv = candv + (((size_t)(b * NN + i)) * NSPLIT + split) * KK;
#pragma unroll
    for (int s = 0; s < KK; ++s) cv[s] = tv[s];
  }
}

// ---------------- merge split value-lists -> exact 20th-largest threshold ----------------
__global__ void k_thresh(const float* __restrict__ candv, float* __restrict__ thr) {
  int qi = blockIdx.x * 256 + threadIdx.x;  // 0..BB*NN-1
  const float* cv = candv + (size_t)qi * NSPLIT * KK;
  float tv[KK];
#pragma unroll
  for (int s = 0; s < KK; ++s) tv[s] = NEGINF;
#pragma unroll 1
  for (int s = 0; s < NSPLIT * KK; ++s) {
    RIP(tv, cv[s]);
  }
  thr[qi] = tv[19];
}

// ---------------- Pass B: re-scan, collect j with d >= thr ----------------
// Even lane emits j+0..7 into seg slots [0,5); odd lane j+8..15 into [5,10).
// Packed count: cnt8 = p_even | p_odd<<16. Overflow (>5 hits per lane-half,
// P~9e-4) -> per-query atomic pool.
__global__ __launch_bounds__(256, 2) void k_collect(const float* __restrict__ x,
                                                    const float* __restrict__ hg,
                                                    const float* __restrict__ thr,
                                                    int* __restrict__ cnt8,
                                                    int* __restrict__ gcnt,
                                                    float* __restrict__ segs,
                                                    float* __restrict__ pool) {
  __shared__ float ltile[KC * 64 + HPAD];
  __shared__ float lh[64];
  int t = threadIdx.x;
  int l = t & 63;
  int w = t >> 6;
  int half = l & 1;
  int half8 = half * 8;
  int bidx = blockIdx.x;
  int b = bidx >> 8;
  int itile = (bidx >> 3) & 31;
  int split = bidx & 7;
  int i = itile * 128 + w * 32 + (l >> 1);
  int qi = b * NN + i;
  const float* xb = x + ((size_t)b * CC + KSKIP) * NN;
  const float* ltp = ltile + half * (HC * 64 + HPAD);

  float xi[HC];
#pragma unroll
  for (int cc = 0; cc < HC; ++cc) xi[cc] = xb[(half * HC + cc) * NN + i];
  float ti_ = thr[qi];
  float* seg = segs + ((((size_t)qi * NSPLIT) + split) * CAPS + half * HCAP) * 2;
  int p = 0;

#define EMIT(dv, jj)                                                  \
  if ((dv) >= ti_) {                                                  \
    float2 pr;                                                        \
    pr.x = (dv);                                                      \
    pr.y = __int_as_float(jj);                                        \
    if (p < HCAP) {                                                   \
      *(float2*)(seg + p * 2) = pr;                                   \
    } else {                                                          \
      int g = atomicAdd(&gcnt[qi], 1);                                \
      if (g < GCAP) *(float2*)(pool + ((size_t)qi * GCAP + g) * 2) = pr; \
    }                                                                 \
    ++p;                                                              \
  }

#pragma unroll 1
  for (int jt = 0; jt < JS / 64; ++jt) {
    int jbase = split * JS + jt * 64;
    STAGE_TILE(jbase)
#pragma unroll 1
    for (int jq = 0; jq < 4; ++jq) {
      DIST16(jq)
      int j0 = jbase + jq * 16 + half8;
      EMIT(d0, j0 + 0) EMIT(d1, j0 + 1) EMIT(d2, j0 + 2) EMIT(d3, j0 + 3)
      EMIT(d4, j0 + 4) EMIT(d5, j0 + 5) EMIT(d6, j0 + 6) EMIT(d7, j0 + 7)
    }
  }
#undef EMIT
  int po = __shfl_xor(p, 1);
  if (!half) cnt8[qi * NSPLIT + split] = p | (po << 16);
}

// ---------------- final: top-20 via threshold classification ----------------
// Every candidate has d >= thr (EMIT guarantees), thr = exact 20th largest.
// Lexicographic top-20 = all {d > thr} (m <= 19) + the (20-m) smallest-j ties
// {d == thr}. Common case: m + nt == 20 and nt <= 2 -> direct writes, no
// selection, no serial insert chain (r8: old INSERT bubble = 480us, 40% of
// wall). Rare tie-overflow -> repeated min-scan over L2-hot candidates.
// Output order irrelevant downstream (sum/max over k).
__global__ void k_final(const float* __restrict__ segs, const int* __restrict__ cnt8,
                        const float* __restrict__ pool, const int* __restrict__ gcnt,
                        const float* __restrict__ thr, int* __restrict__ idxk) {
  int qi = blockIdx.x * 256 + threadIdx.x;
  float ti_ = thr[qi];
  int* op = idxk + (size_t)qi * KK;
  int g = gcnt[qi];
  if (g > GCAP) g = GCAP;
  const float* pp = pool + (size_t)qi * GCAP * 2;

  int m = 0, nt = 0;
  int tj0 = 0, tj1 = 0;

#define PASS1(pr)                                                     \
  {                                                                   \
    float d = (pr).x;                                                 \
    int j = __float_as_int((pr).y);                                   \
    if (d > ti_) {                                                    \
      if (m < KK) op[m] = j;                                          \
      ++m;                                                            \
    } else {                                                          \
      if (nt == 0) tj0 = j; else if (nt == 1) tj1 = j;                \
      ++nt;                                                           \
    }                                                                 \
  }

#pragma unroll 1
  for (int sp = 0; sp < NSPLIT; ++sp) {
    int c = cnt8[qi * NSPLIT + sp];
    int ce = c & 0xffff;
    int co = c >> 16;
    if (ce > HCAP) ce = HCAP;
    if (co > HCAP) co = HCAP;
    const float* cp = segs + (((size_t)qi * NSPLIT) + sp) * CAPS * 2;
#pragma unroll 1
    for (int e = 0; e < ce; ++e) { float2 pr = *(const float2*)(cp + e * 2); PASS1(pr) }
#pragma unroll 1
    for (int e = 0; e < co; ++e) { float2 pr = *(const float2*)(cp + (HCAP + e) * 2); PASS1(pr) }
  }
#pragma unroll 1
  for (int e = 0; e < g; ++e) { float2 pr = *(const float2*)(pp + e * 2); PASS1(pr) }
#undef PASS1

  if (m + nt == KK && nt <= 2) {
    if (nt >= 1) op[m] = tj0;
    if (nt == 2) op[m + 1] = tj1;
    return;
  }

  // rare path: >2 ties or tie-overflow past the top-20 boundary.
  // select the (KK-m) smallest tie j's by repeated min-scan (candidates L2-hot).
  int need = KK - m;
  int last = -1;
#pragma unroll 1
  for (int r = 0; r < need; ++r) {
    int best = 0x7fffffff;
#pragma unroll 1
    for (int sp = 0; sp < NSPLIT; ++sp) {
      int c = cnt8[qi * NSPLIT + sp];
      int ce = c & 0xffff;
      int co = c >> 16;
      if (ce > HCAP) ce = HCAP;
      if (co > HCAP) co = HCAP;
      const float* cp = segs + (((size_t)qi * NSPLIT) + sp) * CAPS * 2;
#pragma unroll 1
      for (int e = 0; e < ce; ++e) {
        float2 pr = *(const float2*)(cp + e * 2);
        int j = __float_as_int(pr.y);
        if (pr.x == ti_ && j > last && j < best) best = j;
      }
#pragma unroll 1
      for (int e = 0; e < co; ++e) {
        float2 pr = *(const float2*)(cp + (HCAP + e) * 2);
        int j = __float_as_int(pr.y);
        if (pr.x == ti_ && j > last && j < best) best = j;
      }
    }
#pragma unroll 1
    for (int e = 0; e < g; ++e) {
      float2 pr = *(const float2*)(pp + e * 2);
      int j = __float_as_int(pr.y);
      if (pr.x == ti_ && j > last && j < best) best = j;
    }
    op[m + r] = best;
    last = best;
  }
}

// ---------------- K2: u = W1^T x, v = (W2-W1)^T x, stored (b, n, o) ----------------
__global__ void k_uv(const float* __restrict__ x, const float* __restrict__ W,
                     float* __restrict__ ut, float* __restrict__ vt) {
  __shared__ float w1[64 * 65];
  __shared__ float wd[64 * 65];
  __shared__ float xs[64 * 72];
  int t = threadIdx.x;
  int b = blockIdx.x >> 6;
  int nbase = (blockIdx.x & 63) * 64;

  for (int f = t; f < 4096; f += 256) {
    int o = f >> 6, c = f & 63;
    float a = W[o * 128 + c];
    float b2 = W[o * 128 + 64 + c];
    w1[c * 65 + o] = a;
    wd[c * 65 + o] = b2 - a;
  }
  for (int f = t; f < 1024; f += 256) {
    int c = f >> 4, q = f & 15;
    float4 v = *(const float4*)(x + ((size_t)b * CC + c) * NN + nbase + q * 4);
    *(float4*)(xs + c * 72 + q * 4) = v;
  }
  __syncthreads();

  int o = t & 63, w = t >> 6;
  float4 au[4], av[4];
#pragma unroll
  for (int nq = 0; nq < 4; ++nq) {
    au[nq] = make_float4(0.f, 0.f, 0.f, 0.f);
    av[nq] = make_float4(0.f, 0.f, 0.f, 0.f);
  }
#pragma unroll 4
  for (int c = 0; c < 64; ++c) {
    float w1v = w1[c * 65 + o];
    float wdv = wd[c * 65 + o];
#pragma unroll
    for (int nq = 0; nq < 4; ++nq) {
      float4 xv = *(const float4*)(xs + c * 72 + w * 16 + nq * 4);
      au[nq].x = fmaf(w1v, xv.x, au[nq].x);
      au[nq].y = fmaf(w1v, xv.y, au[nq].y);
      au[nq].z = fmaf(w1v, xv.z, au[nq].z);
      au[nq].w = fmaf(w1v, xv.w, au[nq].w);
      av[nq].x = fmaf(wdv, xv.x, av[nq].x);
      av[nq].y = fmaf(wdv, xv.y, av[nq].y);
      av[nq].z = fmaf(wdv, xv.z, av[nq].z);
      av[nq].w = fmaf(wdv, xv.w, av[nq].w);
    }
  }
#pragma unroll
  for (int nq = 0; nq < 4; ++nq) {
    int n = nbase + w * 16 + nq * 4;
    size_t base = ((size_t)b * NN + n) * OO + o;
    ut[base + 0 * OO] = au[nq].x;
    ut[base + 1 * OO] = au[nq].y;
    ut[base + 2 * OO] = au[nq].z;
    ut[base + 3 * OO] = au[nq].w;
    vt[base + 0 * OO] = av[nq].x;
    vt[base + 1 * OO] = av[nq].y;
    vt[base + 2 * OO] = av[nq].z;
    vt[base + 3 * OO] = av[nq].w;
  }
}

// ---------------- K3: BN sum / sumsq over all (b,n,k) per channel ----------------
__global__ void k_stats(const float* __restrict__ ut, const float* __restrict__ vt,
                        const int* __restrict__ idxk, float* __restrict__ gsum,
                        float* __restrict__ gsqs) {
  __shared__ float red[2][4][64];
  int t = threadIdx.x;
  int o = t & 63, w = t >> 6;
  int b = blockIdx.x >> 6;
  int nbase = (blockIdx.x & 63) * 64 + w * 16;
  const float* up = ut + (size_t)b * NN * OO;
  float s = 0.f, s2 = 0.f;
#pragma unroll 1
  for (int nn2 = 0; nn2 < 16; ++nn2) {
    int n = nbase + nn2;
    float vv = vt[((size_t)b * NN + n) * OO + o];
    const int* ip = idxk + ((size_t)b * NN + n) * KK;
    int4 q0 = *(const int4*)(ip + 0);
    int4 q1 = *(const int4*)(ip + 4);
    int4 q2 = *(const int4*)(ip + 8);
    int4 q3 = *(const int4*)(ip + 12);
    int4 q4 = *(const int4*)(ip + 16);
#define ACC(j)                                  \
    {                                           \
      float u = up[(size_t)(j) * OO + o];       \
      float yy = u + vv;                        \
      s += yy;                                  \
      s2 = fmaf(yy, yy, s2);                    \
    }
    ACC(q0.x) ACC(q0.y) ACC(q0.z) ACC(q0.w)
    ACC(q1.x) ACC(q1.y) ACC(q1.z) ACC(q1.w)
    ACC(q2.x) ACC(q2.y) ACC(q2.z) ACC(q2.w)
    ACC(q3.x) ACC(q3.y) ACC(q3.z) ACC(q3.w)
    ACC(q4.x) ACC(q4.y) ACC(q4.z) ACC(q4.w)
#undef ACC
  }
  red[0][w][o] = s;
  red[1][w][o] = s2;
  __syncthreads();
  if (w == 0) {
    float ts = red[0][0][o] + red[0][1][o] + red[0][2][o] + red[0][3][o];
    float t2 = red[1][0][o] + red[1][1][o] + red[1][2][o] + red[1][3][o];
    atomicAdd(&gsum[o], ts);
    atomicAdd(&gsqs[o], t2);
  }
}

// ---------------- K4: finalize BN affine ----------------
__global__ void k_bn(const float* __restrict__ gsum, const float* __restrict__ gsqs,
                     const float* __restrict__ gamma, const float* __restrict__ beta,
                     float* __restrict__ AB) {
  int o = threadIdx.x;
  float mean = gsum[o] * (1.f / M_TOTAL);
  float var = gsqs[o] * (1.f / M_TOTAL) - mean * mean;
  float A = gamma[o] / sqrtf(var + BN_EPS);
  AB[o] = A;
  AB[64 + o] = beta[o] - mean * A;
}

// ---------------- K5: normalized + leakyrelu + max over k, transposed store ----------------
__global__ void k_out(const float* __restrict__ ut, const float* __restrict__ vt,
                      const int* __restrict__ idxk, const float* __restrict__ AB,
                      float* __restrict__ outp) {
  __shared__ float lt[64 * 65];
  int t = threadIdx.x;
  int o = t & 63, w = t >> 6;
  int b = blockIdx.x >> 6;
  int nb = (blockIdx.x & 63) * 64;
  float A = AB[o], Bs = AB[64 + o];
  const float* up = ut + (size_t)b * NN * OO;
#pragma unroll 1
  for (int nn2 = 0; nn2 < 16; ++nn2) {
    int nl = w * 16 + nn2;
    int n = nb + nl;
    float vv = vt[((size_t)b * NN + n) * OO + o];
    const int* ip = idxk + ((size_t)b * NN + n) * KK;
    int4 q0 = *(const int4*)(ip + 0);
    int4 q1 = *(const int4*)(ip + 4);
    int4 q2 = *(const int4*)(ip + 8);
    int4 q3 = *(const int4*)(ip + 12);
    int4 q4 = *(const int4*)(ip + 16);
    float m = NEGINF;
#define STEP(j)                                   \
    {                                             \
      float u = up[(size_t)(j) * OO + o];         \
      float y = fmaf(A, u + vv, Bs);              \
      y = fmaxf(y, NEG * y);                      \
      m = fmaxf(m, y);                            \
    }
    STEP(q0.x) STEP(q0.y) STEP(q0.z) STEP(q0.w)
    STEP(q1.x) STEP(q1.y) STEP(q1.z) STEP(q1.w)
    STEP(q2.x) STEP(q2.y) STEP(q2.z) STEP(q2.w)
    STEP(q3.x) STEP(q3.y) STEP(q3.z) STEP(q3.w)
    STEP(q4.x) STEP(q4.y) STEP(q4.z) STEP(q4.w)
#undef STEP
    lt[nl * 65 + o] = m;
  }
  __syncthreads();
  int oo = t >> 2, part = t & 3;
#pragma unroll
  for (int mq = 0; mq < 4; ++mq) {
    int n0 = part * 16 + mq * 4;
    float4 vvv;
    vvv.x = lt[(n0 + 0) * 65 + oo];
    vvv.y = lt[(n0 + 1) * 65 + oo];
    vvv.z = lt[(n0 + 2) * 65 + oo];
    vvv.w = lt[(n0 + 3) * 65 + oo];
    *(float4*)(outp + ((size_t)b * OO + oo) * NN + nb + n0) = vvv;
  }
}

extern "C" void kernel_launch(void* const* d_in, const int* in_sizes, int n_in,
                              void* d_out, int out_size, void* d_ws, size_t ws_size,
                              hipStream_t stream) {
  const float* x = (const float*)d_in[0];
  const float* W = (const float*)d_in[1];
  const float* gamma = (const float*)d_in[2];
  const float* beta = (const float*)d_in[3];
  float* outp = (float*)d_out;
  char* ws = (char*)d_ws;

  const size_t NQ = (size_t)BB * NN;  // 32768 queries
  size_t off = 0;
  float* hg = (float*)(ws + off); off += NQ * 4;                      // 128 KB
  float* thr = (float*)(ws + off); off += NQ * 4;                     // 128 KB
  int* cnt8 = (int*)(ws + off); off += NQ * NSPLIT * 4;               // 1 MB
  int* gcnt = (int*)(ws + off); off += NQ * 4;                        // 128 KB
  int* idxk = (int*)(ws + off); off += NQ * KK * 4;                   // 2.6 MB
  float* gsum = (float*)(ws + off); off += 256;
  float* gsqs = (float*)(ws + off); off += 256;
  float* AB = (float*)(ws + off); off += 512;
  // overlapped region:
  //  phase 1 (knnA/thresh): candv                 = 20 MB
  //  phase 2 (collect/final): segs (20MB) + pool  = 25.2 MB
  //  phase 3 (uv/stats/out): ut (8MB) + vt (8MB)  = 16 MB
  char* region = ws + off;
  float* candv = (float*)region;                                      // 20 MB
  float* segs = (float*)region;                                       // 20 MB
  float* pool = (float*)(region + NQ * NSPLIT * CAPS * 2 * 4);        // 5.2 MB
  float* ut = (float*)region;                                         // 8 MB
  float* vt = (float*)(region + NQ * OO * 4);                         // 8 MB

  k_sq<<<BB * NN / 256, 256, 0, stream>>>(x, hg);
  k_knnA<<<BB * 32 * NSPLIT, 256, 0, stream>>>(x, hg, candv);
  k_thresh<<<BB * NN / 256, 256, 0, stream>>>(candv, thr);
  hipMemsetAsync(gcnt, 0, NQ * 4, stream);
  k_collect<<<BB * 32 * NSPLIT, 256, 0, stream>>>(x, hg, thr, cnt8, gcnt, segs, pool);
  k_final<<<BB * NN / 256, 256, 0, stream>>>(segs, cnt8, pool, gcnt, thr, idxk);
  k_uv<<<BB * 64, 256, 0, stream>>>(x, W, ut, vt);
  hipMemsetAsync(gsum, 0, 512, stream);
  k_stats<<<BB * 64, 256, 0, stream>>>(ut, vt, idxk, gsum, gsqs);
  k_bn<<<1, 64, 0, stream>>>(gsum, gsqs, gamma, beta, AB);
  k_out<<<BB * 64, 256, 0, stream>>>(ut, vt, idxk, AB, outp);
}

// Round 10
// 701.165 us; speedup vs baseline: 30.7156x; 1.1023x over previous
//
#include <hip/hip_runtime.h>
#include <cstdint>
#include <cstddef>

#define BB 8
#define CC 64
#define NN 4096
#define OO 64
#define KK 20
#define KC 58
#define HC 29             // channels per lane (lane-pair split: even 0-28, odd 29-57)
#define KSKIP 6
#define NSPLIT 8
#define JS 512            // j's per split
#define TIDX 8            // tracked-index depth per split list
#define REC 28            // candvx record: 20 values + 8 indices (words)
#define BN_EPS 1e-5f
#define NEG 0.2f
#define NEGINF (-3.402823466e38f)
#define M_TOTAL 655360.0f   // B*N*K
// odd-half LDS tile offset: 29*64 words == 0 mod 32 banks -> collides with the
// even half's bank group (r7: SQ_LDS_BANK_CONFLICT 1.2e8 = 37% of cycles).
// Shift odd half by +4 words (r8: conflicts -> 0, total 1559 -> 1204us).
#define HPAD 4

#define MED3F(a, b, c) __builtin_amdgcn_fmed3f((a), (b), (c))

// SINGLE-PASS DESIGN (r10): pass B (k_collect) recomputed all 7.8e9 distance
// FMAs only to recover indices. But every global top-20 element satisfies
// d >= thr_global >= thr_split, so it sits in its split's top-20 -- which
// pass A holds in registers. Track indices for the top-TIDX positions only
// (+22 VALU ops/elem vs +63 for full tracking); a split needing an index
// past position TIDX-1 implies v[TIDX] >= thr -> exactly detectable ->
// per-query fallback rescan (P ~ 2e-3; bit-identical summation chain).
//
// VGPR-CAP MODEL (r0-r5): hipcc cap = 256/waves_per_EU_bound; no bounds ->
// flat-wg 1024 default -> cap 64 (SPILLS for scan kernels). (256,2) -> 128.
// SPILL TRIPWIRE: scan-kernel FETCH_SIZE must stay in MBs. GBs = spill.

// ---------------- K0: h = 0.5*||x_{6:}||^2 per point ----------------
__global__ void k_sq(const float* __restrict__ x, float* __restrict__ h) {
  int n = blockIdx.x * 256 + threadIdx.x;  // 0 .. BB*NN-1
  int b = n >> 12;
  int nn = n & (NN - 1);
  const float* xp = x + ((size_t)b * CC + KSKIP) * NN + nn;
  float s = 0.f;
#pragma unroll
  for (int c = 0; c < KC; ++c) {
    float v = xp[(size_t)c * NN];
    s = fmaf(v, v, s);
  }
  h[n] = 0.5f * s;
}

// med3 ripple: insert e into descending top-20 value list (values only).
#define RIP(tv, e)                                   \
  do {                                               \
    float _e = (e);                                  \
    tv[19] = MED3F(tv[18], tv[19], _e);              \
    tv[18] = MED3F(tv[17], tv[18], _e);              \
    tv[17] = MED3F(tv[16], tv[17], _e);              \
    tv[16] = MED3F(tv[15], tv[16], _e);              \
    tv[15] = MED3F(tv[14], tv[15], _e);              \
    tv[14] = MED3F(tv[13], tv[14], _e);              \
    tv[13] = MED3F(tv[12], tv[13], _e);              \
    tv[12] = MED3F(tv[11], tv[12], _e);              \
    tv[11] = MED3F(tv[10], tv[11], _e);              \
    tv[10] = MED3F(tv[9],  tv[10], _e);              \
    tv[9]  = MED3F(tv[8],  tv[9],  _e);              \
    tv[8]  = MED3F(tv[7],  tv[8],  _e);              \
    tv[7]  = MED3F(tv[6],  tv[7],  _e);              \
    tv[6]  = MED3F(tv[5],  tv[6],  _e);              \
    tv[5]  = MED3F(tv[4],  tv[5],  _e);              \
    tv[4]  = MED3F(tv[3],  tv[4],  _e);              \
    tv[3]  = MED3F(tv[2],  tv[3],  _e);              \
    tv[2]  = MED3F(tv[1],  tv[2],  _e);              \
    tv[1]  = MED3F(tv[0],  tv[1],  _e);              \
    tv[0]  = fmaxf(tv[0], _e);                       \
  } while (0)

// Value+index ripple, indices tracked for positions 0..7 only.
// Strict-greater insert + ascending-j insertion order = equal values keep
// the earlier (smaller-j) element above -> matches lax.top_k tie behavior.
// cmps read OLD tv values (computed up front); tv/ti updated bottom-up so
// every tv[s-1]/ti[s-1] read is pre-update. ~43 VALU ops.
#define RIPX(tv, ti, e, jj)                                                   \
  do {                                                                        \
    float _e = (e);                                                           \
    int _j = (jj);                                                            \
    bool c0 = _e > tv[0], c1 = _e > tv[1], c2 = _e > tv[2], c3 = _e > tv[3];  \
    bool c4 = _e > tv[4], c5 = _e > tv[5], c6 = _e > tv[6], c7 = _e > tv[7];  \
    tv[19] = MED3F(tv[18], tv[19], _e);                                       \
    tv[18] = MED3F(tv[17], tv[18], _e);                                       \
    tv[17] = MED3F(tv[16], tv[17], _e);                                       \
    tv[16] = MED3F(tv[15], tv[16], _e);                                       \
    tv[15] = MED3F(tv[14], tv[15], _e);                                       \
    tv[14] = MED3F(tv[13], tv[14], _e);                                       \
    tv[13] = MED3F(tv[12], tv[13], _e);                                       \
    tv[12] = MED3F(tv[11], tv[12], _e);                                       \
    tv[11] = MED3F(tv[10], tv[11], _e);                                       \
    tv[10] = MED3F(tv[9],  tv[10], _e);                                       \
    tv[9]  = MED3F(tv[8],  tv[9],  _e);                                       \
    tv[8]  = MED3F(tv[7],  tv[8],  _e);                                       \
    tv[7]  = MED3F(tv[6],  tv[7],  _e); ti[7] = c6 ? ti[6] : (c7 ? _j : ti[7]); \
    tv[6]  = MED3F(tv[5],  tv[6],  _e); ti[6] = c5 ? ti[5] : (c6 ? _j : ti[6]); \
    tv[5]  = MED3F(tv[4],  tv[5],  _e); ti[5] = c4 ? ti[4] : (c5 ? _j : ti[5]); \
    tv[4]  = MED3F(tv[3],  tv[4],  _e); ti[4] = c3 ? ti[3] : (c4 ? _j : ti[4]); \
    tv[3]  = MED3F(tv[2],  tv[3],  _e); ti[3] = c2 ? ti[2] : (c3 ? _j : ti[3]); \
    tv[2]  = MED3F(tv[1],  tv[2],  _e); ti[2] = c1 ? ti[1] : (c2 ? _j : ti[2]); \
    tv[1]  = MED3F(tv[0],  tv[1],  _e); ti[1] = c0 ? ti[0] : (c1 ? _j : ti[1]); \
    tv[0]  = fmaxf(tv[0], _e);          ti[0] = c0 ? _j : ti[0];              \
  } while (0)

// Pair-split distance batch: 16 j's per pair-iteration. Each lane accumulates
// its 29-channel partial for all 16 j's; shfl_xor(1)+add completes the dot
// (commutative add -> bit-identical in both lanes). Even lane owns j+0..7,
// odd lane j+8..15 (via half8 select). k_fb replicates this summation order
// exactly: s1 = chain(c 0..28), s2 = chain(c 29..57), d = (s1+s2) - h.
#define DIST16(jq)                                                    \
  float a0 = 0.f, a1 = 0.f, a2 = 0.f, a3 = 0.f;                       \
  float a4 = 0.f, a5 = 0.f, a6 = 0.f, a7 = 0.f;                       \
  float a8 = 0.f, a9 = 0.f, a10 = 0.f, a11 = 0.f;                     \
  float a12 = 0.f, a13 = 0.f, a14 = 0.f, a15 = 0.f;                   \
  _Pragma("unroll")                                                   \
  for (int cc = 0; cc < HC; ++cc) {                                   \
    float4 x0 = *(const float4*)(ltp + cc * 64 + (jq) * 16);          \
    float4 x1 = *(const float4*)(ltp + cc * 64 + (jq) * 16 + 4);      \
    float4 x2 = *(const float4*)(ltp + cc * 64 + (jq) * 16 + 8);      \
    float4 x3 = *(const float4*)(ltp + cc * 64 + (jq) * 16 + 12);     \
    float xic = xi[cc];                                               \
    a0  = fmaf(xic, x0.x, a0);  a1  = fmaf(xic, x0.y, a1);            \
    a2  = fmaf(xic, x0.z, a2);  a3  = fmaf(xic, x0.w, a3);            \
    a4  = fmaf(xic, x1.x, a4);  a5  = fmaf(xic, x1.y, a5);            \
    a6  = fmaf(xic, x1.z, a6);  a7  = fmaf(xic, x1.w, a7);            \
    a8  = fmaf(xic, x2.x, a8);  a9  = fmaf(xic, x2.y, a9);            \
    a10 = fmaf(xic, x2.z, a10); a11 = fmaf(xic, x2.w, a11);           \
    a12 = fmaf(xic, x3.x, a12); a13 = fmaf(xic, x3.y, a13);           \
    a14 = fmaf(xic, x3.z, a14); a15 = fmaf(xic, x3.w, a15);           \
  }                                                                   \
  a0  += __shfl_xor(a0, 1);  a1  += __shfl_xor(a1, 1);                \
  a2  += __shfl_xor(a2, 1);  a3  += __shfl_xor(a3, 1);                \
  a4  += __shfl_xor(a4, 1);  a5  += __shfl_xor(a5, 1);                \
  a6  += __shfl_xor(a6, 1);  a7  += __shfl_xor(a7, 1);                \
  a8  += __shfl_xor(a8, 1);  a9  += __shfl_xor(a9, 1);                \
  a10 += __shfl_xor(a10, 1); a11 += __shfl_xor(a11, 1);               \
  a12 += __shfl_xor(a12, 1); a13 += __shfl_xor(a13, 1);               \
  a14 += __shfl_xor(a14, 1); a15 += __shfl_xor(a15, 1);               \
  float4 hA = *(const float4*)(lh + (jq) * 16 + half8);               \
  float4 hB = *(const float4*)(lh + (jq) * 16 + half8 + 4);           \
  float d0 = (half8 ? a8  : a0)  - hA.x;                              \
  float d1 = (half8 ? a9  : a1)  - hA.y;                              \
  float d2 = (half8 ? a10 : a2)  - hA.z;                              \
  float d3 = (half8 ? a11 : a3)  - hA.w;                              \
  float d4 = (half8 ? a12 : a4)  - hB.x;                              \
  float d5 = (half8 ? a13 : a5)  - hB.y;                              \
  float d6 = (half8 ? a14 : a6)  - hB.z;                              \
  float d7 = (half8 ? a15 : a7)  - hB.w;

// rows >= HC (odd half) shifted by HPAD words to land on a disjoint bank group.
#define STAGE_TILE(jbase)                                             \
  __syncthreads();                                                    \
  for (int f = t; f < KC * 16; f += 256) {                            \
    int c = f >> 4, q = f & 15;                                       \
    float4 v = *(const float4*)(xb + c * NN + (jbase) + q * 4);       \
    *(float4*)(ltile + c * 64 + q * 4 + (c >= HC ? HPAD : 0)) = v;    \
  }                                                                   \
  if (t < 64) lh[t] = hg[b * NN + (jbase) + t];                       \
  __syncthreads();

// ---------------- single pass: per-(query,split) top-20 values + top-8 indices ----
// grid: BB(8) x itile(32) x split(8) = 2048 blocks of 256 threads.
// 128 queries per block (lane pairs), pair handles 16 j's per DIST16.
__global__ __launch_bounds__(256, 2) void k_knnA(const float* __restrict__ x,
                                                 const float* __restrict__ hg,
                                                 float* __restrict__ candvx) {
  __shared__ float ltile[KC * 64 + HPAD];
  __shared__ float lh[64];
  int t = threadIdx.x;
  int l = t & 63;
  int w = t >> 6;
  int half = l & 1;
  int half8 = half * 8;
  int bidx = blockIdx.x;
  int b = bidx >> 8;
  int itile = (bidx >> 3) & 31;
  int split = bidx & 7;
  int i = itile * 128 + w * 32 + (l >> 1);
  const float* xb = x + ((size_t)b * CC + KSKIP) * NN;
  const float* ltp = ltile + half * (HC * 64 + HPAD);

  float xi[HC];
#pragma unroll
  for (int cc = 0; cc < HC; ++cc) xi[cc] = xb[(half * HC + cc) * NN + i];

  float tv[KK];
  int ti[TIDX];
#pragma unroll
  for (int s = 0; s < KK; ++s) tv[s] = NEGINF;
#pragma unroll
  for (int s = 0; s < TIDX; ++s) ti[s] = -1;

#pragma unroll 1
  for (int jt = 0; jt < JS / 64; ++jt) {
    int jbase = split * JS + jt * 64;
    STAGE_TILE(jbase)
#pragma unroll 1
    for (int jq = 0; jq < 4; ++jq) {
      DIST16(jq)
      int j0 = jbase + jq * 16 + half8;
      RIPX(tv, ti, d0, j0 + 0); RIPX(tv, ti, d1, j0 + 1);
      RIPX(tv, ti, d2, j0 + 2); RIPX(tv, ti, d3, j0 + 3);
      RIPX(tv, ti, d4, j0 + 4); RIPX(tv, ti, d5, j0 + 5);
      RIPX(tv, ti, d6, j0 + 6); RIPX(tv, ti, d7, j0 + 7);
    }
  }

  // merge partner lane's list (snapshot first: partner's mutates during merge).
  // Partner positions 0..7 carry indices; 8..19 insert with -1 poison —
  // a needed poison implies split >= 9 qualifiers -> caught by v[8]>=thr fb check.
  float ov[KK];
  int oi[TIDX];
#pragma unroll
  for (int s = 0; s < KK; ++s) ov[s] = __shfl_xor(tv[s], 1);
#pragma unroll
  for (int s = 0; s < TIDX; ++s) oi[s] = __shfl_xor(ti[s], 1);
#pragma unroll
  for (int s = 0; s < TIDX; ++s) { RIPX(tv, ti, ov[s], oi[s]); }
#pragma unroll
  for (int s = TIDX; s < KK; ++s) { RIPX(tv, ti, ov[s], -1); }

  if (!half) {
    float* cv = candvx + (((size_t)(b * NN + i)) * NSPLIT + split) * REC;
    *(float4*)(cv + 0)  = make_float4(tv[0], tv[1], tv[2], tv[3]);
    *(float4*)(cv + 4)  = make_float4(tv[4], tv[5], tv[6], tv[7]);
    *(float4*)(cv + 8)  = make_float4(tv[8], tv[9], tv[10], tv[11]);
    *(float4*)(cv + 12) = make_float4(tv[12], tv[13], tv[14], tv[15]);
    *(float4*)(cv + 16) = make_float4(tv[16], tv[17], tv[18], tv[19]);
    int* cvi = (int*)(cv + KK);
    *(int4*)(cvi + 0) = make_int4(ti[0], ti[1], ti[2], ti[3]);
    *(int4*)(cvi + 4) = make_int4(ti[4], ti[5], ti[6], ti[7]);
  }
}

// ---------------- merge split value-lists -> exact 20th-largest threshold ----------------
__global__ void k_thresh(const float* __restrict__ candvx, float* __restrict__ thr) {
  int qi = blockIdx.x * 256 + threadIdx.x;  // 0..BB*NN-1
  const float* cv = candvx + (size_t)qi * NSPLIT * REC;
  float tv[KK];
#pragma unroll
  for (int s = 0; s < KK; ++s) tv[s] = NEGINF;
#pragma unroll 1
  for (int sp = 0; sp < NSPLIT; ++sp) {
#pragma unroll
    for (int s = 0; s < KK; ++s) {
      RIP(tv, cv[sp * REC + s]);
    }
  }
  thr[qi] = tv[19];
}

// ---------------- final: classify tracked entries vs thr ----------------
// top-20 = all {v > thr} (their indices are tracked, else fb) + the (20-m)
// smallest-j ties {v == thr}. fb whenever any split's 9th value >= thr or a
// needed index is poison -> k_fb rescans that query exactly.
__global__ void k_final(const float* __restrict__ candvx, const float* __restrict__ thr,
                        int* __restrict__ idxk, int* __restrict__ fbl,
                        int* __restrict__ fbcnt) {
  int qi = blockIdx.x * 256 + threadIdx.x;
  float ti_ = thr[qi];
  const float* cv = candvx + (size_t)qi * NSPLIT * REC;
  int* op = idxk + (size_t)qi * KK;
  bool fb = false;
  int m = 0;
#pragma unroll 1
  for (int sp = 0; sp < NSPLIT; ++sp) {
    const float* r = cv + sp * REC;
    if (r[TIDX] >= ti_) fb = true;   // qualifier (or tie) beyond tracked depth
    const int* ri = (const int*)(r + KK);
#pragma unroll
    for (int s = 0; s < TIDX; ++s) {
      float v = r[s];
      if (v >= ti_ && ri[s] < 0) fb = true;   // poison on a needed entry
      if (v > ti_) {
        if (m < KK) op[m] = ri[s];
        ++m;
      }
    }
  }
  if (m >= KK) fb = true;  // paranoia; strict-greater count is mathematically <= 19
  if (fb) {
    int p = atomicAdd(fbcnt, 1);
    fbl[p] = qi;
    return;
  }
  // fill (KK-m) smallest-j ties at v == thr from tracked entries
  int need = KK - m;
  int last = -1;
#pragma unroll 1
  for (int r2 = 0; r2 < need; ++r2) {
    int best = 0x7fffffff;
#pragma unroll 1
    for (int sp = 0; sp < NSPLIT; ++sp) {
      const float* r = cv + sp * REC;
      const int* ri = (const int*)(r + KK);
#pragma unroll
      for (int s = 0; s < TIDX; ++s) {
        if (r[s] == ti_) {
          int jx = ri[s];
          if (jx > last && jx < best) best = jx;
        }
      }
    }
    op[m + r2] = best;
    last = best;
  }
}

// ---------------- fallback: exact rescan for flagged queries ----------------
// One query per block iteration; summation order matches DIST16's even lane
// bit-exactly: s1 = fmaf chain c=0..28, s2 = chain c=29..57, d = (s1+s2)-h.
__global__ __launch_bounds__(256) void k_fb(const float* __restrict__ x,
                                            const float* __restrict__ hg,
                                            const float* __restrict__ thr,
                                            const int* __restrict__ fbl,
                                            const int* __restrict__ fbcnt,
                                            int* __restrict__ idxk) {
  __shared__ float xiA[HC];
  __shared__ float xiB[HC];
  __shared__ float db[64 * 2];
  __shared__ int cnt;
  int t = threadIdx.x;
  int nfb = *fbcnt;
  if (nfb > BB * NN) nfb = BB * NN;
#pragma unroll 1
  for (int q = blockIdx.x; q < nfb; q += gridDim.x) {
    int qi = fbl[q];
    int b = qi >> 12;
    int i = qi & (NN - 1);
    const float* xb = x + ((size_t)b * CC + KSKIP) * NN;
    if (t < HC) xiA[t] = xb[t * NN + i];
    else if (t < 2 * HC) xiB[t - HC] = xb[(size_t)t * NN + i];
    if (t == 0) cnt = 0;
    __syncthreads();
    float ti_ = thr[qi];
#pragma unroll 1
    for (int j = t; j < NN; j += 256) {
      float s1 = 0.f, s2 = 0.f;
#pragma unroll
      for (int cc = 0; cc < HC; ++cc) s1 = fmaf(xiA[cc], xb[cc * NN + j], s1);
#pragma unroll
      for (int cc = 0; cc < HC; ++cc) s2 = fmaf(xiB[cc], xb[(HC + cc) * NN + j], s2);
      float d = (s1 + s2) - hg[b * NN + j];
      if (d >= ti_) {
        int p = atomicAdd(&cnt, 1);
        if (p < 64) { db[p * 2] = d; db[p * 2 + 1] = __int_as_float(j); }
      }
    }
    __syncthreads();
    if (t == 0) {
      int n = cnt;
      if (n > 64) n = 64;
      int* op = idxk + (size_t)qi * KK;
      int m = 0;
      for (int e = 0; e < n; ++e) {
        if (db[e * 2] > ti_) {
          if (m < KK) op[m] = __float_as_int(db[e * 2 + 1]);
          ++m;
        }
      }
      int need = KK - m;
      int last = -1;
      for (int r = 0; r < need; ++r) {
        int best = 0x7fffffff;
        for (int e = 0; e < n; ++e) {
          if (db[e * 2] == ti_) {
            int jx = __float_as_int(db[e * 2 + 1]);
            if (jx > last && jx < best) best = jx;
          }
        }
        op[m + r] = best;
        last = best;
      }
    }
    __syncthreads();
  }
}

// ---------------- K2: u = W1^T x, v = (W2-W1)^T x, stored (b, n, o) ----------------
__global__ void k_uv(const float* __restrict__ x, const float* __restrict__ W,
                     float* __restrict__ ut, float* __restrict__ vt) {
  __shared__ float w1[64 * 65];
  __shared__ float wd[64 * 65];
  __shared__ float xs[64 * 72];
  int t = threadIdx.x;
  int b = blockIdx.x >> 6;
  int nbase = (blockIdx.x & 63) * 64;

  for (int f = t; f < 4096; f += 256) {
    int o = f >> 6, c = f & 63;
    float a = W[o * 128 + c];
    float b2 = W[o * 128 + 64 + c];
    w1[c * 65 + o] = a;
    wd[c * 65 + o] = b2 - a;
  }
  for (int f = t; f < 1024; f += 256) {
    int c = f >> 4, q = f & 15;
    float4 v = *(const float4*)(x + ((size_t)b * CC + c) * NN + nbase + q * 4);
    *(float4*)(xs + c * 72 + q * 4) = v;
  }
  __syncthreads();

  int o = t & 63, w = t >> 6;
  float4 au[4], av[4];
#pragma unroll
  for (int nq = 0; nq < 4; ++nq) {
    au[nq] = make_float4(0.f, 0.f, 0.f, 0.f);
    av[nq] = make_float4(0.f, 0.f, 0.f, 0.f);
  }
#pragma unroll 4
  for (int c = 0; c < 64; ++c) {
    float w1v = w1[c * 65 + o];
    float wdv = wd[c * 65 + o];
#pragma unroll
    for (int nq = 0; nq < 4; ++nq) {
      float4 xv = *(const float4*)(xs + c * 72 + w * 16 + nq * 4);
      au[nq].x = fmaf(w1v, xv.x, au[nq].x);
      au[nq].y = fmaf(w1v, xv.y, au[nq].y);
      au[nq].z = fmaf(w1v, xv.z, au[nq].z);
      au[nq].w = fmaf(w1v, xv.w, au[nq].w);
      av[nq].x = fmaf(wdv, xv.x, av[nq].x);
      av[nq].y = fmaf(wdv, xv.y, av[nq].y);
      av[nq].z = fmaf(wdv, xv.z, av[nq].z);
      av[nq].w = fmaf(wdv, xv.w, av[nq].w);
    }
  }
#pragma unroll
  for (int nq = 0; nq < 4; ++nq) {
    int n = nbase + w * 16 + nq * 4;
    size_t base = ((size_t)b * NN + n) * OO + o;
    ut[base + 0 * OO] = au[nq].x;
    ut[base + 1 * OO] = au[nq].y;
    ut[base + 2 * OO] = au[nq].z;
    ut[base + 3 * OO] = au[nq].w;
    vt[base + 0 * OO] = av[nq].x;
    vt[base + 1 * OO] = av[nq].y;
    vt[base + 2 * OO] = av[nq].z;
    vt[base + 3 * OO] = av[nq].w;
  }
}

// ---------------- K3: BN sum / sumsq over all (b,n,k) per channel ----------------
__global__ void k_stats(const float* __restrict__ ut, const float* __restrict__ vt,
                        const int* __restrict__ idxk, float* __restrict__ gsum,
                        float* __restrict__ gsqs) {
  __shared__ float red[2][4][64];
  int t = threadIdx.x;
  int o = t & 63, w = t >> 6;
  int b = blockIdx.x >> 6;
  int nbase = (blockIdx.x & 63) * 64 + w * 16;
  const float* up = ut + (size_t)b * NN * OO;
  float s = 0.f, s2 = 0.f;
#pragma unroll 1
  for (int nn2 = 0; nn2 < 16; ++nn2) {
    int n = nbase + nn2;
    float vv = vt[((size_t)b * NN + n) * OO + o];
    const int* ip = idxk + ((size_t)b * NN + n) * KK;
    int4 q0 = *(const int4*)(ip + 0);
    int4 q1 = *(const int4*)(ip + 4);
    int4 q2 = *(const int4*)(ip + 8);
    int4 q3 = *(const int4*)(ip + 12);
    int4 q4 = *(const int4*)(ip + 16);
#define ACC(j)                                  \
    {                                           \
      float u = up[(size_t)(j) * OO + o];       \
      float yy = u + vv;                        \
      s += yy;                                  \
      s2 = fmaf(yy, yy, s2);                    \
    }
    ACC(q0.x) ACC(q0.y) ACC(q0.z) ACC(q0.w)
    ACC(q1.x) ACC(q1.y) ACC(q1.z) ACC(q1.w)
    ACC(q2.x) ACC(q2.y) ACC(q2.z) ACC(q2.w)
    ACC(q3.x) ACC(q3.y) ACC(q3.z) ACC(q3.w)
    ACC(q4.x) ACC(q4.y) ACC(q4.z) ACC(q4.w)
#undef ACC
  }
  red[0][w][o] = s;
  red[1][w][o] = s2;
  __syncthreads();
  if (w == 0) {
    float ts = red[0][0][o] + red[0][1][o] + red[0][2][o] + red[0][3][o];
    float t2 = red[1][0][o] + red[1][1][o] + red[1][2][o] + red[1][3][o];
    atomicAdd(&gsum[o], ts);
    atomicAdd(&gsqs[o], t2);
  }
}

// ---------------- K4: finalize BN affine ----------------
__global__ void k_bn(const float* __restrict__ gsum, const float* __restrict__ gsqs,
                     const float* __restrict__ gamma, const float* __restrict__ beta,
                     float* __restrict__ AB) {
  int o = threadIdx.x;
  float mean = gsum[o] * (1.f / M_TOTAL);
  float var = gsqs[o] * (1.f / M_TOTAL) - mean * mean;
  float A = gamma[o] / sqrtf(var + BN_EPS);
  AB[o] = A;
  AB[64 + o] = beta[o] - mean * A;
}

// ---------------- K5: normalized + leakyrelu + max over k, transposed store ----------------
__global__ void k_out(const float* __restrict__ ut, const float* __restrict__ vt,
                      const int* __restrict__ idxk, const float* __restrict__ AB,
                      float* __restrict__ outp) {
  __shared__ float lt[64 * 65];
  int t = threadIdx.x;
  int o = t & 63, w = t >> 6;
  int b = blockIdx.x >> 6;
  int nb = (blockIdx.x & 63) * 64;
  float A = AB[o], Bs = AB[64 + o];
  const float* up = ut + (size_t)b * NN * OO;
#pragma unroll 1
  for (int nn2 = 0; nn2 < 16; ++nn2) {
    int nl = w * 16 + nn2;
    int n = nb + nl;
    float vv = vt[((size_t)b * NN + n) * OO + o];
    const int* ip = idxk + ((size_t)b * NN + n) * KK;
    int4 q0 = *(const int4*)(ip + 0);
    int4 q1 = *(const int4*)(ip + 4);
    int4 q2 = *(const int4*)(ip + 8);
    int4 q3 = *(const int4*)(ip + 12);
    int4 q4 = *(const int4*)(ip + 16);
    float m = NEGINF;
#define STEP(j)                                   \
    {                                             \
      float u = up[(size_t)(j) * OO + o];         \
      float y = fmaf(A, u + vv, Bs);              \
      y = fmaxf(y, NEG * y);                      \
      m = fmaxf(m, y);                            \
    }
    STEP(q0.x) STEP(q0.y) STEP(q0.z) STEP(q0.w)
    STEP(q1.x) STEP(q1.y) STEP(q1.z) STEP(q1.w)
    STEP(q2.x) STEP(q2.y) STEP(q2.z) STEP(q2.w)
    STEP(q3.x) STEP(q3.y) STEP(q3.z) STEP(q3.w)
    STEP(q4.x) STEP(q4.y) STEP(q4.z) STEP(q4.w)
#undef STEP
    lt[nl * 65 + o] = m;
  }
  __syncthreads();
  int oo = t >> 2, part = t & 3;
#pragma unroll
  for (int mq = 0; mq < 4; ++mq) {
    int n0 = part * 16 + mq * 4;
    float4 vvv;
    vvv.x = lt[(n0 + 0) * 65 + oo];
    vvv.y = lt[(n0 + 1) * 65 + oo];
    vvv.z = lt[(n0 + 2) * 65 + oo];
    vvv.w = lt[(n0 + 3) * 65 + oo];
    *(float4*)(outp + ((size_t)b * OO + oo) * NN + nb + n0) = vvv;
  }
}

extern "C" void kernel_launch(void* const* d_in, const int* in_sizes, int n_in,
                              void* d_out, int out_size, void* d_ws, size_t ws_size,
                              hipStream_t stream) {
  const float* x = (const float*)d_in[0];
  const float* W = (const float*)d_in[1];
  const float* gamma = (const float*)d_in[2];
  const float* beta = (const float*)d_in[3];
  float* outp = (float*)d_out;
  char* ws = (char*)d_ws;

  const size_t NQ = (size_t)BB * NN;  // 32768 queries
  size_t off = 0;
  float* hg = (float*)(ws + off); off += NQ * 4;                      // 128 KB
  float* thr = (float*)(ws + off); off += NQ * 4;                     // 128 KB
  int* idxk = (int*)(ws + off); off += NQ * KK * 4;                   // 2.6 MB
  int* fbcnt = (int*)(ws + off); off += 256;
  int* fbl = (int*)(ws + off); off += NQ * 4;                         // 128 KB
  float* gsum = (float*)(ws + off); off += 256;
  float* gsqs = (float*)(ws + off); off += 256;
  float* AB = (float*)(ws + off); off += 512;
  // overlapped region:
  //  phase 1 (knnA/thresh/final/fb): candvx = NQ*8*28*4 = 29.4 MB
  //  phase 2 (uv/stats/out): ut (8MB) + vt (8MB) = 16 MB
  char* region = ws + off;
  float* candvx = (float*)region;                                     // 29.4 MB
  float* ut = (float*)region;                                         // 8 MB
  float* vt = (float*)(region + NQ * OO * 4);                         // 8 MB

  k_sq<<<BB * NN / 256, 256, 0, stream>>>(x, hg);
  k_knnA<<<BB * 32 * NSPLIT, 256, 0, stream>>>(x, hg, candvx);
  k_thresh<<<BB * NN / 256, 256, 0, stream>>>(candvx, thr);
  hipMemsetAsync(fbcnt, 0, 4, stream);
  k_final<<<BB * NN / 256, 256, 0, stream>>>(candvx, thr, idxk, fbl, fbcnt);
  k_fb<<<256, 256, 0, stream>>>(x, hg, thr, fbl, fbcnt, idxk);
  k_uv<<<BB * 64, 256, 0, stream>>>(x, W, ut, vt);
  hipMemsetAsync(gsum, 0, 512, stream);
  k_stats<<<BB * 64, 256, 0, stream>>>(ut, vt, idxk, gsum, gsqs);
  k_bn<<<1, 64, 0, stream>>>(gsum, gsqs, gamma, beta, AB);
  k_out<<<BB * 64, 256, 0, stream>>>(ut, vt, idxk, AB, outp);
}

// Round 11
// 691.790 us; speedup vs baseline: 31.1318x; 1.0136x over previous
//
#include <hip/hip_runtime.h>
#include <cstdint>
#include <cstddef>

#define BB 8
#define CC 64
#define NN 4096
#define OO 64
#define KK 20
#define KC 58
#define HC 29             // channels per lane (lane-pair split: even 0-28, odd 29-57)
#define KSKIP 6
#define NSPLIT 8
#define JS 512            // j's per split
#define TIDX 8            // tracked-index depth per split list
#define REC 28            // candvx record: 20 values + 8 indices (words)
#define BN_EPS 1e-5f
#define NEG 0.2f
#define NEGINF (-3.402823466e38f)
#define M_TOTAL 655360.0f   // B*N*K
// odd-half LDS tile offset: 29*64 words == 0 mod 32 banks -> collides with the
// even half's bank group (r7: SQ_LDS_BANK_CONFLICT 1.2e8 = 37% of cycles).
// Shift odd half by +4 words (r8: conflicts -> 0).
#define HPAD 4

#define MED3F(a, b, c) __builtin_amdgcn_fmed3f((a), (b), (c))

// SINGLE-PASS DESIGN (r10, proven): track per-split top-20 values + top-8
// indices in one scan; every global top-20 element is inside its split's
// top-8-by-construction with P~0.999 per split; detectable exceptions
// (split's 9th value >= thr, or poison index) -> exact per-query fallback.
//
// r11: DIST16 -> DIST8P. r10's 16 accumulators + 4 staged float4 pushed
// VGPR to 72, crossing the 64-VGPR residency cliff (m69: waves/SIMD halve
// at alloc {64,128,256}) -> occupancy 47->31%, VALUBusy 92->73%. 8-j pair
// batches halve acc+staging regs; launch_bounds(256,4) pins cap at 64.
// SPILL TRIPWIRE: k_knnA FETCH_SIZE must stay ~30 MB. GBs = spill -> revert
// to (256,2).

// ---------------- K0: h = 0.5*||x_{6:}||^2 per point ----------------
__global__ void k_sq(const float* __restrict__ x, float* __restrict__ h) {
  int n = blockIdx.x * 256 + threadIdx.x;  // 0 .. BB*NN-1
  int b = n >> 12;
  int nn = n & (NN - 1);
  const float* xp = x + ((size_t)b * CC + KSKIP) * NN + nn;
  float s = 0.f;
#pragma unroll
  for (int c = 0; c < KC; ++c) {
    float v = xp[(size_t)c * NN];
    s = fmaf(v, v, s);
  }
  h[n] = 0.5f * s;
}

// med3 ripple: insert e into descending top-20 value list (values only).
#define RIP(tv, e)                                   \
  do {                                               \
    float _e = (e);                                  \
    tv[19] = MED3F(tv[18], tv[19], _e);              \
    tv[18] = MED3F(tv[17], tv[18], _e);              \
    tv[17] = MED3F(tv[16], tv[17], _e);              \
    tv[16] = MED3F(tv[15], tv[16], _e);              \
    tv[15] = MED3F(tv[14], tv[15], _e);              \
    tv[14] = MED3F(tv[13], tv[14], _e);              \
    tv[13] = MED3F(tv[12], tv[13], _e);              \
    tv[12] = MED3F(tv[11], tv[12], _e);              \
    tv[11] = MED3F(tv[10], tv[11], _e);              \
    tv[10] = MED3F(tv[9],  tv[10], _e);              \
    tv[9]  = MED3F(tv[8],  tv[9],  _e);              \
    tv[8]  = MED3F(tv[7],  tv[8],  _e);              \
    tv[7]  = MED3F(tv[6],  tv[7],  _e);              \
    tv[6]  = MED3F(tv[5],  tv[6],  _e);              \
    tv[5]  = MED3F(tv[4],  tv[5],  _e);              \
    tv[4]  = MED3F(tv[3],  tv[4],  _e);              \
    tv[3]  = MED3F(tv[2],  tv[3],  _e);              \
    tv[2]  = MED3F(tv[1],  tv[2],  _e);              \
    tv[1]  = MED3F(tv[0],  tv[1],  _e);              \
    tv[0]  = fmaxf(tv[0], _e);                       \
  } while (0)

// Value+index ripple, indices tracked for positions 0..7 only.
// Strict-greater insert + ascending-j insertion order = equal values keep
// the earlier (smaller-j) element above -> matches lax.top_k tie behavior.
// cmps read OLD tv values; tv/ti updated bottom-up. ~43 VALU ops.
#define RIPX(tv, ti, e, jj)                                                   \
  do {                                                                        \
    float _e = (e);                                                           \
    int _j = (jj);                                                            \
    bool c0 = _e > tv[0], c1 = _e > tv[1], c2 = _e > tv[2], c3 = _e > tv[3];  \
    bool c4 = _e > tv[4], c5 = _e > tv[5], c6 = _e > tv[6], c7 = _e > tv[7];  \
    tv[19] = MED3F(tv[18], tv[19], _e);                                       \
    tv[18] = MED3F(tv[17], tv[18], _e);                                       \
    tv[17] = MED3F(tv[16], tv[17], _e);                                       \
    tv[16] = MED3F(tv[15], tv[16], _e);                                       \
    tv[15] = MED3F(tv[14], tv[15], _e);                                       \
    tv[14] = MED3F(tv[13], tv[14], _e);                                       \
    tv[13] = MED3F(tv[12], tv[13], _e);                                       \
    tv[12] = MED3F(tv[11], tv[12], _e);                                       \
    tv[11] = MED3F(tv[10], tv[11], _e);                                       \
    tv[10] = MED3F(tv[9],  tv[10], _e);                                       \
    tv[9]  = MED3F(tv[8],  tv[9],  _e);                                       \
    tv[8]  = MED3F(tv[7],  tv[8],  _e);                                       \
    tv[7]  = MED3F(tv[6],  tv[7],  _e); ti[7] = c6 ? ti[6] : (c7 ? _j : ti[7]); \
    tv[6]  = MED3F(tv[5],  tv[6],  _e); ti[6] = c5 ? ti[5] : (c6 ? _j : ti[6]); \
    tv[5]  = MED3F(tv[4],  tv[5],  _e); ti[5] = c4 ? ti[4] : (c5 ? _j : ti[5]); \
    tv[4]  = MED3F(tv[3],  tv[4],  _e); ti[4] = c3 ? ti[3] : (c4 ? _j : ti[4]); \
    tv[3]  = MED3F(tv[2],  tv[3],  _e); ti[3] = c2 ? ti[2] : (c3 ? _j : ti[3]); \
    tv[2]  = MED3F(tv[1],  tv[2],  _e); ti[2] = c1 ? ti[1] : (c2 ? _j : ti[2]); \
    tv[1]  = MED3F(tv[0],  tv[1],  _e); ti[1] = c0 ? ti[0] : (c1 ? _j : ti[1]); \
    tv[0]  = fmaxf(tv[0], _e);          ti[0] = c0 ? _j : ti[0];              \
  } while (0)

// Pair-split distance batch, 8 j's per pair-iteration (r11: halves live
// accumulators+staging vs DIST16 -> VGPR back under the 64 cliff).
// Each lane accumulates its 29-channel partial for all 8 j's; shfl_xor(1)+add
// completes the dot (commutative fp add -> bit-identical in both lanes).
// Even lane owns j+0..3, odd lane j+4..7 (half4 select). k_fb replicates the
// even-lane summation order exactly: s1 = chain(c 0..28), s2 = chain(c 29..57),
// d = (s1+s2) - h.
#define DIST8P(jq)                                                    \
  float a0 = 0.f, a1 = 0.f, a2 = 0.f, a3 = 0.f;                       \
  float a4 = 0.f, a5 = 0.f, a6 = 0.f, a7 = 0.f;                       \
  _Pragma("unroll")                                                   \
  for (int cc = 0; cc < HC; ++cc) {                                   \
    float4 x0 = *(const float4*)(ltp + cc * 64 + (jq) * 8);           \
    float4 x1 = *(const float4*)(ltp + cc * 64 + (jq) * 8 + 4);       \
    float xic = xi[cc];                                               \
    a0 = fmaf(xic, x0.x, a0); a1 = fmaf(xic, x0.y, a1);               \
    a2 = fmaf(xic, x0.z, a2); a3 = fmaf(xic, x0.w, a3);               \
    a4 = fmaf(xic, x1.x, a4); a5 = fmaf(xic, x1.y, a5);               \
    a6 = fmaf(xic, x1.z, a6); a7 = fmaf(xic, x1.w, a7);               \
  }                                                                   \
  a0 += __shfl_xor(a0, 1); a1 += __shfl_xor(a1, 1);                   \
  a2 += __shfl_xor(a2, 1); a3 += __shfl_xor(a3, 1);                   \
  a4 += __shfl_xor(a4, 1); a5 += __shfl_xor(a5, 1);                   \
  a6 += __shfl_xor(a6, 1); a7 += __shfl_xor(a7, 1);                   \
  float4 hA = *(const float4*)(lh + (jq) * 8 + half4);                \
  float d0 = (half4 ? a4 : a0) - hA.x;                                \
  float d1 = (half4 ? a5 : a1) - hA.y;                                \
  float d2 = (half4 ? a6 : a2) - hA.z;                                \
  float d3 = (half4 ? a7 : a3) - hA.w;

// rows >= HC (odd half) shifted by HPAD words to land on a disjoint bank group.
#define STAGE_TILE(jbase)                                             \
  __syncthreads();                                                    \
  for (int f = t; f < KC * 16; f += 256) {                            \
    int c = f >> 4, q = f & 15;                                       \
    float4 v = *(const float4*)(xb + c * NN + (jbase) + q * 4);       \
    *(float4*)(ltile + c * 64 + q * 4 + (c >= HC ? HPAD : 0)) = v;    \
  }                                                                   \
  if (t < 64) lh[t] = hg[b * NN + (jbase) + t];                       \
  __syncthreads();

// ---------------- single pass: per-(query,split) top-20 values + top-8 indices ----
// grid: BB(8) x itile(32) x split(8) = 2048 blocks of 256 threads.
// 128 queries per block (lane pairs), pair handles 8 j's per DIST8P.
__global__ __launch_bounds__(256, 4) void k_knnA(const float* __restrict__ x,
                                                 const float* __restrict__ hg,
                                                 float* __restrict__ candvx) {
  __shared__ float ltile[KC * 64 + HPAD];
  __shared__ float lh[64];
  int t = threadIdx.x;
  int l = t & 63;
  int w = t >> 6;
  int half = l & 1;
  int half4 = half * 4;
  int bidx = blockIdx.x;
  int b = bidx >> 8;
  int itile = (bidx >> 3) & 31;
  int split = bidx & 7;
  int i = itile * 128 + w * 32 + (l >> 1);
  const float* xb = x + ((size_t)b * CC + KSKIP) * NN;
  const float* ltp = ltile + half * (HC * 64 + HPAD);

  float xi[HC];
#pragma unroll
  for (int cc = 0; cc < HC; ++cc) xi[cc] = xb[(half * HC + cc) * NN + i];

  float tv[KK];
  int ti[TIDX];
#pragma unroll
  for (int s = 0; s < KK; ++s) tv[s] = NEGINF;
#pragma unroll
  for (int s = 0; s < TIDX; ++s) ti[s] = -1;

#pragma unroll 1
  for (int jt = 0; jt < JS / 64; ++jt) {
    int jbase = split * JS + jt * 64;
    STAGE_TILE(jbase)
#pragma unroll 1
    for (int jq = 0; jq < 8; ++jq) {
      DIST8P(jq)
      int j0 = jbase + jq * 8 + half4;
      RIPX(tv, ti, d0, j0 + 0); RIPX(tv, ti, d1, j0 + 1);
      RIPX(tv, ti, d2, j0 + 2); RIPX(tv, ti, d3, j0 + 3);
    }
  }

  // merge partner lane's list (snapshot first: partner's mutates during merge).
  // Partner positions 0..7 carry indices; 8..19 insert with -1 poison —
  // a needed poison implies split >= 9 qualifiers -> caught by v[8]>=thr fb check.
  float ov[KK];
  int oi[TIDX];
#pragma unroll
  for (int s = 0; s < KK; ++s) ov[s] = __shfl_xor(tv[s], 1);
#pragma unroll
  for (int s = 0; s < TIDX; ++s) oi[s] = __shfl_xor(ti[s], 1);
#pragma unroll
  for (int s = 0; s < TIDX; ++s) { RIPX(tv, ti, ov[s], oi[s]); }
#pragma unroll
  for (int s = TIDX; s < KK; ++s) { RIPX(tv, ti, ov[s], -1); }

  if (!half) {
    float* cv = candvx + (((size_t)(b * NN + i)) * NSPLIT + split) * REC;
    *(float4*)(cv + 0)  = make_float4(tv[0], tv[1], tv[2], tv[3]);
    *(float4*)(cv + 4)  = make_float4(tv[4], tv[5], tv[6], tv[7]);
    *(float4*)(cv + 8)  = make_float4(tv[8], tv[9], tv[10], tv[11]);
    *(float4*)(cv + 12) = make_float4(tv[12], tv[13], tv[14], tv[15]);
    *(float4*)(cv + 16) = make_float4(tv[16], tv[17], tv[18], tv[19]);
    int* cvi = (int*)(cv + KK);
    *(int4*)(cvi + 0) = make_int4(ti[0], ti[1], ti[2], ti[3]);
    *(int4*)(cvi + 4) = make_int4(ti[4], ti[5], ti[6], ti[7]);
  }
}

// ---------------- merge split value-lists -> exact 20th-largest threshold ----------------
__global__ void k_thresh(const float* __restrict__ candvx, float* __restrict__ thr) {
  int qi = blockIdx.x * 256 + threadIdx.x;  // 0..BB*NN-1
  const float* cv = candvx + (size_t)qi * NSPLIT * REC;
  float tv[KK];
#pragma unroll
  for (int s = 0; s < KK; ++s) tv[s] = NEGINF;
#pragma unroll 1
  for (int sp = 0; sp < NSPLIT; ++sp) {
#pragma unroll
    for (int s = 0; s < KK; ++s) {
      RIP(tv, cv[sp * REC + s]);
    }
  }
  thr[qi] = tv[19];
}

// ---------------- final: classify tracked entries vs thr ----------------
// top-20 = all {v > thr} (their indices are tracked, else fb) + the (20-m)
// smallest-j ties {v == thr}. fb whenever any split's 9th value >= thr or a
// needed index is poison -> k_fb rescans that query exactly.
__global__ void k_final(const float* __restrict__ candvx, const float* __restrict__ thr,
                        int* __restrict__ idxk, int* __restrict__ fbl,
                        int* __restrict__ fbcnt) {
  int qi = blockIdx.x * 256 + threadIdx.x;
  float ti_ = thr[qi];
  const float* cv = candvx + (size_t)qi * NSPLIT * REC;
  int* op = idxk + (size_t)qi * KK;
  bool fb = false;
  int m = 0;
#pragma unroll 1
  for (int sp = 0; sp < NSPLIT; ++sp) {
    const float* r = cv + sp * REC;
    if (r[TIDX] >= ti_) fb = true;   // qualifier (or tie) beyond tracked depth
    const int* ri = (const int*)(r + KK);
#pragma unroll
    for (int s = 0; s < TIDX; ++s) {
      float v = r[s];
      if (v >= ti_ && ri[s] < 0) fb = true;   // poison on a needed entry
      if (v > ti_) {
        if (m < KK) op[m] = ri[s];
        ++m;
      }
    }
  }
  if (m >= KK) fb = true;  // paranoia; strict-greater count is mathematically <= 19
  if (fb) {
    int p = atomicAdd(fbcnt, 1);
    fbl[p] = qi;
    return;
  }
  // fill (KK-m) smallest-j ties at v == thr from tracked entries
  int need = KK - m;
  int last = -1;
#pragma unroll 1
  for (int r2 = 0; r2 < need; ++r2) {
    int best = 0x7fffffff;
#pragma unroll 1
    for (int sp = 0; sp < NSPLIT; ++sp) {
      const float* r = cv + sp * REC;
      const int* ri = (const int*)(r + KK);
#pragma unroll
      for (int s = 0; s < TIDX; ++s) {
        if (r[s] == ti_) {
          int jx = ri[s];
          if (jx > last && jx < best) best = jx;
        }
      }
    }
    op[m + r2] = best;
    last = best;
  }
}

// ---------------- fallback: exact rescan for flagged queries ----------------
// One query per block iteration; summation order matches DIST8P's even lane
// bit-exactly: s1 = fmaf chain c=0..28, s2 = chain c=29..57, d = (s1+s2)-h.
__global__ __launch_bounds__(256) void k_fb(const float* __restrict__ x,
                                            const float* __restrict__ hg,
                                            const float* __restrict__ thr,
                                            const int* __restrict__ fbl,
                                            const int* __restrict__ fbcnt,
                                            int* __restrict__ idxk) {
  __shared__ float xiA[HC];
  __shared__ float xiB[HC];
  __shared__ float db[64 * 2];
  __shared__ int cnt;
  int t = threadIdx.x;
  int nfb = *fbcnt;
  if (nfb > BB * NN) nfb = BB * NN;
#pragma unroll 1
  for (int q = blockIdx.x; q < nfb; q += gridDim.x) {
    int qi = fbl[q];
    int b = qi >> 12;
    int i = qi & (NN - 1);
    const float* xb = x + ((size_t)b * CC + KSKIP) * NN;
    if (t < HC) xiA[t] = xb[t * NN + i];
    else if (t < 2 * HC) xiB[t - HC] = xb[(size_t)t * NN + i];
    if (t == 0) cnt = 0;
    __syncthreads();
    float ti_ = thr[qi];
#pragma unroll 1
    for (int j = t; j < NN; j += 256) {
      float s1 = 0.f, s2 = 0.f;
#pragma unroll
      for (int cc = 0; cc < HC; ++cc) s1 = fmaf(xiA[cc], xb[cc * NN + j], s1);
#pragma unroll
      for (int cc = 0; cc < HC; ++cc) s2 = fmaf(xiB[cc], xb[(HC + cc) * NN + j], s2);
      float d = (s1 + s2) - hg[b * NN + j];
      if (d >= ti_) {
        int p = atomicAdd(&cnt, 1);
        if (p < 64) { db[p * 2] = d; db[p * 2 + 1] = __int_as_float(j); }
      }
    }
    __syncthreads();
    if (t == 0) {
      int n = cnt;
      if (n > 64) n = 64;
      int* op = idxk + (size_t)qi * KK;
      int m = 0;
      for (int e = 0; e < n; ++e) {
        if (db[e * 2] > ti_) {
          if (m < KK) op[m] = __float_as_int(db[e * 2 + 1]);
          ++m;
        }
      }
      int need = KK - m;
      int last = -1;
      for (int r = 0; r < need; ++r) {
        int best = 0x7fffffff;
        for (int e = 0; e < n; ++e) {
          if (db[e * 2] == ti_) {
            int jx = __float_as_int(db[e * 2 + 1]);
            if (jx > last && jx < best) best = jx;
          }
        }
        op[m + r] = best;
        last = best;
      }
    }
    __syncthreads();
  }
}

// ---------------- K2: u = W1^T x, v = (W2-W1)^T x, stored (b, n, o) ----------------
__global__ void k_uv(const float* __restrict__ x, const float* __restrict__ W,
                     float* __restrict__ ut, float* __restrict__ vt) {
  __shared__ float w1[64 * 65];
  __shared__ float wd[64 * 65];
  __shared__ float xs[64 * 72];
  int t = threadIdx.x;
  int b = blockIdx.x >> 6;
  int nbase = (blockIdx.x & 63) * 64;

  for (int f = t; f < 4096; f += 256) {
    int o = f >> 6, c = f & 63;
    float a = W[o * 128 + c];
    float b2 = W[o * 128 + 64 + c];
    w1[c * 65 + o] = a;
    wd[c * 65 + o] = b2 - a;
  }
  for (int f = t; f < 1024; f += 256) {
    int c = f >> 4, q = f & 15;
    float4 v = *(const float4*)(x + ((size_t)b * CC + c) * NN + nbase + q * 4);
    *(float4*)(xs + c * 72 + q * 4) = v;
  }
  __syncthreads();

  int o = t & 63, w = t >> 6;
  float4 au[4], av[4];
#pragma unroll
  for (int nq = 0; nq < 4; ++nq) {
    au[nq] = make_float4(0.f, 0.f, 0.f, 0.f);
    av[nq] = make_float4(0.f, 0.f, 0.f, 0.f);
  }
#pragma unroll 4
  for (int c = 0; c < 64; ++c) {
    float w1v = w1[c * 65 + o];
    float wdv = wd[c * 65 + o];
#pragma unroll
    for (int nq = 0; nq < 4; ++nq) {
      float4 xv = *(const float4*)(xs + c * 72 + w * 16 + nq * 4);
      au[nq].x = fmaf(w1v, xv.x, au[nq].x);
      au[nq].y = fmaf(w1v, xv.y, au[nq].y);
      au[nq].z = fmaf(w1v, xv.z, au[nq].z);
      au[nq].w = fmaf(w1v, xv.w, au[nq].w);
      av[nq].x = fmaf(wdv, xv.x, av[nq].x);
      av[nq].y = fmaf(wdv, xv.y, av[nq].y);
      av[nq].z = fmaf(wdv, xv.z, av[nq].z);
      av[nq].w = fmaf(wdv, xv.w, av[nq].w);
    }
  }
#pragma unroll
  for (int nq = 0; nq < 4; ++nq) {
    int n = nbase + w * 16 + nq * 4;
    size_t base = ((size_t)b * NN + n) * OO + o;
    ut[base + 0 * OO] = au[nq].x;
    ut[base + 1 * OO] = au[nq].y;
    ut[base + 2 * OO] = au[nq].z;
    ut[base + 3 * OO] = au[nq].w;
    vt[base + 0 * OO] = av[nq].x;
    vt[base + 1 * OO] = av[nq].y;
    vt[base + 2 * OO] = av[nq].z;
    vt[base + 3 * OO] = av[nq].w;
  }
}

// ---------------- K3: BN sum / sumsq over all (b,n,k) per channel ----------------
__global__ void k_stats(const float* __restrict__ ut, const float* __restrict__ vt,
                        const int* __restrict__ idxk, float* __restrict__ gsum,
                        float* __restrict__ gsqs) {
  __shared__ float red[2][4][64];
  int t = threadIdx.x;
  int o = t & 63, w = t >> 6;
  int b = blockIdx.x >> 6;
  int nbase = (blockIdx.x & 63) * 64 + w * 16;
  const float* up = ut + (size_t)b * NN * OO;
  float s = 0.f, s2 = 0.f;
#pragma unroll 1
  for (int nn2 = 0; nn2 < 16; ++nn2) {
    int n = nbase + nn2;
    float vv = vt[((size_t)b * NN + n) * OO + o];
    const int* ip = idxk + ((size_t)b * NN + n) * KK;
    int4 q0 = *(const int4*)(ip + 0);
    int4 q1 = *(const int4*)(ip + 4);
    int4 q2 = *(const int4*)(ip + 8);
    int4 q3 = *(const int4*)(ip + 12);
    int4 q4 = *(const int4*)(ip + 16);
#define ACC(j)                                  \
    {                                           \
      float u = up[(size_t)(j) * OO + o];       \
      float yy = u + vv;                        \
      s += yy;                                  \
      s2 = fmaf(yy, yy, s2);                    \
    }
    ACC(q0.x) ACC(q0.y) ACC(q0.z) ACC(q0.w)
    ACC(q1.x) ACC(q1.y) ACC(q1.z) ACC(q1.w)
    ACC(q2.x) ACC(q2.y) ACC(q2.z) ACC(q2.w)
    ACC(q3.x) ACC(q3.y) ACC(q3.z) ACC(q3.w)
    ACC(q4.x) ACC(q4.y) ACC(q4.z) ACC(q4.w)
#undef ACC
  }
  red[0][w][o] = s;
  red[1][w][o] = s2;
  __syncthreads();
  if (w == 0) {
    float ts = red[0][0][o] + red[0][1][o] + red[0][2][o] + red[0][3][o];
    float t2 = red[1][0][o] + red[1][1][o] + red[1][2][o] + red[1][3][o];
    atomicAdd(&gsum[o], ts);
    atomicAdd(&gsqs[o], t2);
  }
}

// ---------------- K4: finalize BN affine ----------------
__global__ void k_bn(const float* __restrict__ gsum, const float* __restrict__ gsqs,
                     const float* __restrict__ gamma, const float* __restrict__ beta,
                     float* __restrict__ AB) {
  int o = threadIdx.x;
  float mean = gsum[o] * (1.f / M_TOTAL);
  float var = gsqs[o] * (1.f / M_TOTAL) - mean * mean;
  float A = gamma[o] / sqrtf(var + BN_EPS);
  AB[o] = A;
  AB[64 + o] = beta[o] - mean * A;
}

// ---------------- K5: normalized + leakyrelu + max over k, transposed store ----------------
__global__ void k_out(const float* __restrict__ ut, const float* __restrict__ vt,
                      const int* __restrict__ idxk, const float* __restrict__ AB,
                      float* __restrict__ outp) {
  __shared__ float lt[64 * 65];
  int t = threadIdx.x;
  int o = t & 63, w = t >> 6;
  int b = blockIdx.x >> 6;
  int nb = (blockIdx.x & 63) * 64;
  float A = AB[o], Bs = AB[64 + o];
  const float* up = ut + (size_t)b * NN * OO;
#pragma unroll 1
  for (int nn2 = 0; nn2 < 16; ++nn2) {
    int nl = w * 16 + nn2;
    int n = nb + nl;
    float vv = vt[((size_t)b * NN + n) * OO + o];
    const int* ip = idxk + ((size_t)b * NN + n) * KK;
    int4 q0 = *(const int4*)(ip + 0);
    int4 q1 = *(const int4*)(ip + 4);
    int4 q2 = *(const int4*)(ip + 8);
    int4 q3 = *(const int4*)(ip + 12);
    int4 q4 = *(const int4*)(ip + 16);
    float m = NEGINF;
#define STEP(j)                                   \
    {                                             \
      float u = up[(size_t)(j) * OO + o];         \
      float y = fmaf(A, u + vv, Bs);              \
      y = fmaxf(y, NEG * y);                      \
      m = fmaxf(m, y);                            \
    }
    STEP(q0.x) STEP(q0.y) STEP(q0.z) STEP(q0.w)
    STEP(q1.x) STEP(q1.y) STEP(q1.z) STEP(q1.w)
    STEP(q2.x) STEP(q2.y) STEP(q2.z) STEP(q2.w)
    STEP(q3.x) STEP(q3.y) STEP(q3.z) STEP(q3.w)
    STEP(q4.x) STEP(q4.y) STEP(q4.z) STEP(q4.w)
#undef STEP
    lt[nl * 65 + o] = m;
  }
  __syncthreads();
  int oo = t >> 2, part = t & 3;
#pragma unroll
  for (int mq = 0; mq < 4; ++mq) {
    int n0 = part * 16 + mq * 4;
    float4 vvv;
    vvv.x = lt[(n0 + 0) * 65 + oo];
    vvv.y = lt[(n0 + 1) * 65 + oo];
    vvv.z = lt[(n0 + 2) * 65 + oo];
    vvv.w = lt[(n0 + 3) * 65 + oo];
    *(float4*)(outp + ((size_t)b * OO + oo) * NN + nb + n0) = vvv;
  }
}

extern "C" void kernel_launch(void* const* d_in, const int* in_sizes, int n_in,
                              void* d_out, int out_size, void* d_ws, size_t ws_size,
                              hipStream_t stream) {
  const float* x = (const float*)d_in[0];
  const float* W = (const float*)d_in[1];
  const float* gamma = (const float*)d_in[2];
  const float* beta = (const float*)d_in[3];
  float* outp = (float*)d_out;
  char* ws = (char*)d_ws;

  const size_t NQ = (size_t)BB * NN;  // 32768 queries
  size_t off = 0;
  float* hg = (float*)(ws + off); off += NQ * 4;                      // 128 KB
  float* thr = (float*)(ws + off); off += NQ * 4;                     // 128 KB
  int* idxk = (int*)(ws + off); off += NQ * KK * 4;                   // 2.6 MB
  int* fbcnt = (int*)(ws + off); off += 256;
  int* fbl = (int*)(ws + off); off += NQ * 4;                         // 128 KB
  float* gsum = (float*)(ws + off); off += 256;
  float* gsqs = (float*)(ws + off); off += 256;
  float* AB = (float*)(ws + off); off += 512;
  // overlapped region:
  //  phase 1 (knnA/thresh/final/fb): candvx = NQ*8*28*4 = 29.4 MB
  //  phase 2 (uv/stats/out): ut (8MB) + vt (8MB) = 16 MB
  char* region = ws + off;
  float* candvx = (float*)region;                                     // 29.4 MB
  float* ut = (float*)region;                                         // 8 MB
  float* vt = (float*)(region + NQ * OO * 4);                         // 8 MB

  k_sq<<<BB * NN / 256, 256, 0, stream>>>(x, hg);
  k_knnA<<<BB * 32 * NSPLIT, 256, 0, stream>>>(x, hg, candvx);
  k_thresh<<<BB * NN / 256, 256, 0, stream>>>(candvx, thr);
  hipMemsetAsync(fbcnt, 0, 4, stream);
  k_final<<<BB * NN / 256, 256, 0, stream>>>(candvx, thr, idxk, fbl, fbcnt);
  k_fb<<<256, 256, 0, stream>>>(x, hg, thr, fbl, fbcnt, idxk);
  k_uv<<<BB * 64, 256, 0, stream>>>(x, W, ut, vt);
  hipMemsetAsync(gsum, 0, 512, stream);
  k_stats<<<BB * 64, 256, 0, stream>>>(ut, vt, idxk, gsum, gsqs);
  k_bn<<<1, 64, 0, stream>>>(gsum, gsqs, gamma, beta, AB);
  k_out<<<BB * 64, 256, 0, stream>>>(ut, vt, idxk, AB, outp);
}